// Round 6
// baseline (579.126 us; speedup 1.0000x reference)
//
#include <hip/hip_runtime.h>
#include <hip/hip_bf16.h>

// GAT 3-layer: N=50000 nodes, E=800000 edges, H=6 heads.
// R1-R17: MFMA split-bf16 GEMMs + CSR fused softmax/aggregate ladder (545us).
// R18/R19: degree-sort reverted (aggregate invariant under schedule changes).
// R20: L3 aggregate wave-per-node: 103->95.6us. Aggregates pin at FETCH ~312MB
//      (8 XCDs x full h array); wall = bytes through the L2-miss path.
// R21: L3 h -> fp8 e4m3 (halved aggregate bytes; absmax still 0) + L2 wpn agg.
// R22: packed-store epilogue (4x4 xor-shuffle transpose): NO CHANGE (82us,
//      MfmaUtil 10.2% identical). Lesson: L3 GEMM was ~82us all along (hidden
//      below aggregates in top-5); store path was never the constraint.
//      22.1 GFLOP / 82us = 270 TF = pre-global_load_lds ladder level; fetch
//      0.7 TB/s (not BW-bound). Bottleneck: VGPR-roundtrip staging.
// R23: staging -> __builtin_amdgcn_global_load_lds width=16 (8 calls/thread/kt;
//      LDS dst already wave-uniform-base + lane*16, global src per-lane
//      contiguous). The documented 517->874 TF step; no numerics change.

#define HHEADS 6

typedef __attribute__((ext_vector_type(8))) short bf16x8;   // 8 bf16 = 4 VGPR
typedef __attribute__((ext_vector_type(4))) float f32x4;    // mfma C/D
typedef __attribute__((ext_vector_type(2))) float f32x2;

typedef __attribute__((address_space(3))) unsigned int lds_uint;
typedef const __attribute__((address_space(1))) unsigned int glb_uint;

__device__ __forceinline__ float bfl(unsigned u) { return __uint_as_float(u << 16); }
__device__ __forceinline__ float bfh(unsigned u) { return __uint_as_float(u & 0xffff0000u); }
__device__ __forceinline__ unsigned short f2bf(float v) {  // RNE f32->bf16
    unsigned u = __float_as_uint(v);
    return (unsigned short)((u + 0x7fffu + ((u >> 16) & 1u)) >> 16);
}
__device__ __forceinline__ float bf2f(unsigned short h) {
    return __uint_as_float((unsigned)h << 16);
}
// monotone float<->uint for atomicMax on floats (memset-0 = -inf identity)
__device__ __forceinline__ unsigned fkey(float f) {
    unsigned u = __float_as_uint(f);
    return (u >> 31) ? ~u : (u | 0x80000000u);
}
__device__ __forceinline__ float funkey(unsigned k) {
    return (k >> 31) ? __uint_as_float(k & 0x7fffffffu) : __uint_as_float(~k);
}

// 4x4 transpose across a 4-lane group (lanes share lane>>2). In: v0..v3 =
// rows 0..3 at this lane's column. Out: v0..v3 = cols 0..3 at row (lane&3).
__device__ __forceinline__ void xpose4(float& v0, float& v1, float& v2, float& v3, int b) {
    bool hi = (b & 2) != 0;
    float s0 = hi ? v0 : v2;
    float s1 = hi ? v1 : v3;
    s0 = __shfl_xor(s0, 2, 64);
    s1 = __shfl_xor(s1, 2, 64);
    v0 = hi ? s0 : v0;
    v1 = hi ? s1 : v1;
    v2 = hi ? v2 : s0;
    v3 = hi ? v3 : s1;
    bool od = (b & 1) != 0;
    float t0 = od ? v0 : v1;
    t0 = __shfl_xor(t0, 1, 64);
    v0 = od ? t0 : v0;
    v1 = od ? v1 : t0;
    float t1 = od ? v2 : v3;
    t1 = __shfl_xor(t1, 1, 64);
    v2 = od ? t1 : v2;
    v3 = od ? v3 : t1;
}

// ---------------- one-shot zero of all small scratch ----------------
__global__ void zero_misc(int* __restrict__ count, int* __restrict__ cursor,
                          float* __restrict__ g, unsigned* __restrict__ gmax,
                          unsigned short* __restrict__ apH, unsigned short* __restrict__ apL,
                          long pad3_off, long pad3_cnt, long pad6_off, long pad6_cnt, int n) {
    long i = (long)blockIdx.x * blockDim.x + threadIdx.x;
    long stride = (long)gridDim.x * blockDim.x;
    for (long j = i; j < n; j += stride) {
        count[j] = 0;
        cursor[j] = 0;
    }
    if (i < 384) g[i] = 0.f;
    if (i < 12) gmax[i] = 0u;  // slots 0-5: L3, 6-11: L2
    for (long j = i; j < pad3_cnt; j += stride) {
        apH[pad3_off + j] = 0;
        apL[pad3_off + j] = 0;
    }
    for (long j = i; j < pad6_cnt; j += stride) {
        apH[pad6_off + j] = 0;
        apL[pad6_off + j] = 0;
    }
}

// ---------------- CSR build ----------------
__global__ void hist_kernel(const int* __restrict__ dst, int* __restrict__ count, int E) {
    int e = blockIdx.x * blockDim.x + threadIdx.x;
    if (e >= E) return;
    atomicAdd(&count[dst[e]], 1);
}

__global__ void scan_block(const int* __restrict__ count, int* __restrict__ offsets,
                           int* __restrict__ bsum, int n) {
    __shared__ int s[1024];
    int i = blockIdx.x * 1024 + threadIdx.x;
    int v = (i < n) ? count[i] : 0;
    s[threadIdx.x] = v;
    __syncthreads();
    for (int off = 1; off < 1024; off <<= 1) {
        int t = (threadIdx.x >= (unsigned)off) ? s[threadIdx.x - off] : 0;
        __syncthreads();
        s[threadIdx.x] += t;
        __syncthreads();
    }
    if (i < n) offsets[i] = s[threadIdx.x] - v;
    if (threadIdx.x == 1023) bsum[blockIdx.x] = s[1023];
}

__global__ void scan_tops(int* __restrict__ bsum, int nb) {
    __shared__ int s[64];
    int t = threadIdx.x;
    int v = (t < nb) ? bsum[t] : 0;
    s[t] = v;
    __syncthreads();
    for (int off = 1; off < 64; off <<= 1) {
        int tmp = (t >= off) ? s[t - off] : 0;
        __syncthreads();
        s[t] += tmp;
        __syncthreads();
    }
    if (t < nb) bsum[t] = s[t] - v;
}

__global__ void scan_add(int* __restrict__ offsets, const int* __restrict__ bsum, int n,
                         int total) {
    int i = blockIdx.x * 1024 + threadIdx.x;
    if (i < n) offsets[i] += bsum[blockIdx.x];
    if (i == 0) offsets[n] = total;
}

__global__ void scatter_kernel(const int* __restrict__ src, const int* __restrict__ dst,
                               const int* __restrict__ offsets, int* __restrict__ cursor,
                               int* __restrict__ ssrc, int E) {
    int e = blockIdx.x * blockDim.x + threadIdx.x;
    if (e >= E) return;
    int d = dst[e];
    int pos = offsets[d] + atomicAdd(&cursor[d], 1);
    ssrc[pos] = src[e];
}

// ---------------- weight repacks ----------------
__global__ void repack_w(const float* __restrict__ W, float* __restrict__ Wp, int FIN, int F) {
    int HF = HHEADS * F;
    int i = blockIdx.x * blockDim.x + threadIdx.x;
    if (i >= FIN * HF) return;
    int k = i / HF, c = i % HF;
    int hd = c / F, f = c % F;
    Wp[i] = W[(hd * FIN + k) * F + f];
}

// split-bf16 pack in MFMA B-fragment layout (B^T: lane n=..&15, k contiguous)
__global__ void repack_w_mfma(const float* __restrict__ W, unsigned short* __restrict__ bh,
                              unsigned short* __restrict__ bl, int FIN, int F, int NPAD) {
    int i = blockIdx.x * blockDim.x + threadIdx.x;
    if (i >= FIN * NPAD) return;
    int k = i / NPAD, n = i % NPAD;
    int NKT = FIN / 32;
    int HF = HHEADS * F;
    float w = 0.f;
    if (n < HF) {
        int hd = n / F, f = n % F;
        w = W[(hd * FIN + k) * F + f];
    }
    unsigned short h = f2bf(w);
    unsigned short l = f2bf(w - bf2f(h));
    size_t e = ((size_t)((n >> 4) * NKT + (k >> 5)) * 64 + ((n & 15) | (((k >> 3) & 3) << 4))) * 8 +
               (k & 7);
    bh[e] = h;
    bl[e] = l;
}

// ---------------- small GEMM + fused attn (layer 1, K=11, F=16) ----------------
template <int BM, int BN, int BK>
__global__ __launch_bounds__(256) void gemm_small_attn(const float* __restrict__ A,
                                                       const float* __restrict__ B,
                                                       __hip_bfloat16* __restrict__ C,
                                                       const float* __restrict__ as_,
                                                       const float* __restrict__ ad_,
                                                       float* __restrict__ es,
                                                       float* __restrict__ ed, int M, int K,
                                                       int N) {
    __shared__ float As[BK][BM + 4];
    __shared__ float Bs[BK][BN];
    int tid = threadIdx.x;
    int tx = tid % 16, ty = tid / 16;
    int m0 = blockIdx.y * BM, n0 = blockIdx.x * BN;
    float acc[4][4] = {};
    for (int kk0 = 0; kk0 < K; kk0 += BK) {
#pragma unroll
        for (int i = 0; i < (BM * BK) / 256; ++i) {
            int idx = tid + i * 256;
            int m = idx / BK, k = idx % BK;
            float v = 0.f;
            if (m0 + m < M && kk0 + k < K) v = A[(size_t)(m0 + m) * K + kk0 + k];
            As[k][m] = v;
        }
#pragma unroll
        for (int i = 0; i < (BK * BN) / 1024; ++i) {
            int idx = tid + i * 256;
            int k = idx / (BN / 4), n4 = idx % (BN / 4);
            float4 v = make_float4(0.f, 0.f, 0.f, 0.f);
            if (kk0 + k < K && n0 + n4 * 4 < N)
                v = *(const float4*)&B[(size_t)(kk0 + k) * N + n0 + n4 * 4];
            *(float4*)&Bs[k][n4 * 4] = v;
        }
        __syncthreads();
#pragma unroll
        for (int k = 0; k < BK; ++k) {
            float4 av = *(const float4*)&As[k][ty * 4];
            float4 bv = *(const float4*)&Bs[k][tx * 4];
            float a[4] = {av.x, av.y, av.z, av.w};
            float b[4] = {bv.x, bv.y, bv.z, bv.w};
#pragma unroll
            for (int i = 0; i < 4; ++i)
#pragma unroll
                for (int j = 0; j < 4; ++j) acc[i][j] += a[i] * b[j];
        }
        __syncthreads();
    }
    bool colok = (n0 + tx * 4) < N;
    float asv[4], adv[4];
#pragma unroll
    for (int j = 0; j < 4; ++j) {
        int col = n0 + tx * 4 + j;
        asv[j] = (col < N) ? as_[col] : 0.f;
        adv[j] = (col < N) ? ad_[col] : 0.f;
    }
#pragma unroll
    for (int i = 0; i < 4; ++i) {
        int m = m0 + ty * 4 + i;
        bool mok = m < M;
        if (mok && colok) {
            __hip_bfloat16 tmp[4];
#pragma unroll
            for (int j = 0; j < 4; ++j) tmp[j] = __float2bfloat16(acc[i][j]);
            *(uint2*)&C[(size_t)m * N + n0 + tx * 4] = *(uint2*)tmp;
        }
        float ps = 0.f, pd = 0.f;
#pragma unroll
        for (int j = 0; j < 4; ++j) {
            ps += acc[i][j] * asv[j];
            pd += acc[i][j] * adv[j];
        }
        ps += __shfl_down(ps, 2, 4);
        ps += __shfl_down(ps, 1, 4);
        pd += __shfl_down(pd, 2, 4);
        pd += __shfl_down(pd, 1, 4);
        if (mok && colok && (tx & 3) == 0) {
            int hd = (n0 + tx * 4) >> 4;  // F=16
            es[(size_t)m * HHEADS + hd] = ps;
            ed[(size_t)m * HHEADS + hd] = pd;
        }
    }
}

// ---------------- MFMA split-bf16 GEMM + fused attn (layers 2/3) ----------------
// Staging via global_load_lds width=16 (R23): LDS dst = wave-uniform base +
// lane*16B, global src per-lane contiguous 16B - direct HW DMA, no VGPR trip.
// F==64: C written fp8 e4m3; gmax slots 0-5. F==32: C bf16; gmax slots 6-11.
template <int K, int NREAL, int NPAD, int F>
__global__ __launch_bounds__(256) void gemm_attn_mfma(
    const unsigned short* __restrict__ Ah, const unsigned short* __restrict__ Al,
    const unsigned short* __restrict__ Bh, const unsigned short* __restrict__ Bl,
    __hip_bfloat16* __restrict__ C, unsigned char* __restrict__ C8,
    const float* __restrict__ as_, const float* __restrict__ ad_, float* __restrict__ es,
    float* __restrict__ ed, unsigned* __restrict__ gmax, int M) {
    constexpr int NKT = K / 32;
    __shared__ unsigned short sAh[4096], sAl[4096], sBh[4096], sBl[4096];
    int tid = threadIdx.x;
    int lane = tid & 63, wave = tid >> 6;
    int wrow = wave >> 1, wcol = wave & 1;
    int quad = lane >> 4, c16 = lane & 15;
    int m0 = blockIdx.y * 128, n0 = blockIdx.x * 128;
    int bt16 = m0 >> 4, bn16 = n0 >> 4;

    f32x4 acc[4][4] = {};
    for (int kt = 0; kt < NKT; ++kt) {
#pragma unroll
        for (int rep = 0; rep < 2; ++rep) {
            int chunk = tid + rep * 256;
            int tile = chunk >> 6, e8 = chunk & 63;
            size_t aoff = ((size_t)((bt16 + tile) * NKT + kt) * 64 + e8) * 8;
            size_t boff = ((size_t)((bn16 + tile) * NKT + kt) * 64 + e8) * 8;
            __builtin_amdgcn_global_load_lds((glb_uint*)&Ah[aoff], (lds_uint*)&sAh[chunk * 8],
                                             16, 0, 0);
            __builtin_amdgcn_global_load_lds((glb_uint*)&Al[aoff], (lds_uint*)&sAl[chunk * 8],
                                             16, 0, 0);
            __builtin_amdgcn_global_load_lds((glb_uint*)&Bh[boff], (lds_uint*)&sBh[chunk * 8],
                                             16, 0, 0);
            __builtin_amdgcn_global_load_lds((glb_uint*)&Bl[boff], (lds_uint*)&sBl[chunk * 8],
                                             16, 0, 0);
        }
        __syncthreads();
        bf16x8 fah[4], fal[4], fbh[4], fbl[4];
#pragma unroll
        for (int i = 0; i < 4; ++i) {
            fah[i] = *(const bf16x8*)&sAh[(wrow * 4 + i) * 512 + lane * 8];
            fal[i] = *(const bf16x8*)&sAl[(wrow * 4 + i) * 512 + lane * 8];
            fbh[i] = *(const bf16x8*)&sBh[(wcol * 4 + i) * 512 + lane * 8];
            fbl[i] = *(const bf16x8*)&sBl[(wcol * 4 + i) * 512 + lane * 8];
        }
#pragma unroll
        for (int i = 0; i < 4; ++i)
#pragma unroll
            for (int j = 0; j < 4; ++j) {
                acc[i][j] = __builtin_amdgcn_mfma_f32_16x16x32_bf16(fah[i], fbh[j], acc[i][j],
                                                                    0, 0, 0);
                acc[i][j] = __builtin_amdgcn_mfma_f32_16x16x32_bf16(fal[i], fbh[j], acc[i][j],
                                                                    0, 0, 0);
                acc[i][j] = __builtin_amdgcn_mfma_f32_16x16x32_bf16(fah[i], fbl[j], acc[i][j],
                                                                    0, 0, 0);
            }
        __syncthreads();
    }

    float asv[4], adv[4];
#pragma unroll
    for (int j = 0; j < 4; ++j) {
        int col = n0 + wcol * 64 + j * 16 + c16;
        bool ok = col < NREAL;
        asv[j] = ok ? as_[col] : 0.f;
        adv[j] = ok ? ad_[col] : 0.f;
    }
    float mx = -1e30f;                 // F==64 per-wave head max
    float mxA = -1e30f, mxB = -1e30f;  // F==32 per-wave 2-head max
    bool colvalid = (n0 + wcol * 64) < NREAL;

    // ---- es/ed + gmax (uses fragment layout; no C writes here) ----
#pragma unroll
    for (int i = 0; i < 4; ++i) {
#pragma unroll
        for (int r = 0; r < 4; ++r) {
            int m = m0 + wrow * 64 + i * 16 + quad * 4 + r;
            bool mok = m < M;
            if (F == 64) {
                float ps = acc[i][0][r] * asv[0] + acc[i][1][r] * asv[1] +
                           acc[i][2][r] * asv[2] + acc[i][3][r] * asv[3];
                float pd = acc[i][0][r] * adv[0] + acc[i][1][r] * adv[1] +
                           acc[i][2][r] * adv[2] + acc[i][3][r] * adv[3];
#pragma unroll
                for (int off = 8; off > 0; off >>= 1) {
                    ps += __shfl_down(ps, off, 16);
                    pd += __shfl_down(pd, off, 16);
                }
                if (mok && c16 == 0) {
                    int hd = (n0 + wcol * 64) / 64;
                    es[(size_t)m * HHEADS + hd] = ps;
                    ed[(size_t)m * HHEADS + hd] = pd;
                    mx = fmaxf(mx, ps);
                }
            } else {  // F == 32: two heads per wave-column
                float psA = acc[i][0][r] * asv[0] + acc[i][1][r] * asv[1];
                float pdA = acc[i][0][r] * adv[0] + acc[i][1][r] * adv[1];
                float psB = acc[i][2][r] * asv[2] + acc[i][3][r] * asv[3];
                float pdB = acc[i][2][r] * adv[2] + acc[i][3][r] * adv[3];
#pragma unroll
                for (int off = 8; off > 0; off >>= 1) {
                    psA += __shfl_down(psA, off, 16);
                    pdA += __shfl_down(pdA, off, 16);
                    psB += __shfl_down(psB, off, 16);
                    pdB += __shfl_down(pdB, off, 16);
                }
                if (mok && c16 == 0 && colvalid) {
                    int colbase = n0 + wcol * 64;
                    int hd = colbase / 32;
                    es[(size_t)m * HHEADS + hd] = psA;
                    ed[(size_t)m * HHEADS + hd] = pdA;
                    es[(size_t)m * HHEADS + hd + 1] = psB;
                    ed[(size_t)m * HHEADS + hd + 1] = pdB;
                    mxA = fmaxf(mxA, psA);
                    mxB = fmaxf(mxB, psB);
                }
            }
        }
    }
    if (F == 64) {  // per-head global es max, one atomic per wave (slots 0-5)
#pragma unroll
        for (int off = 32; off > 0; off >>= 1) mx = fmaxf(mx, __shfl_xor(mx, off));
        if (lane == 0) atomicMax(&gmax[(n0 + wcol * 64) / 64], fkey(mx));
    } else {  // slots 6-11
        mxA = fmaxf(mxA, __shfl_xor(mxA, 16));
        mxA = fmaxf(mxA, __shfl_xor(mxA, 32));
        mxB = fmaxf(mxB, __shfl_xor(mxB, 16));
        mxB = fmaxf(mxB, __shfl_xor(mxB, 32));
        if (lane == 0 && colvalid) {
            int hd = (n0 + wcol * 64) / 32;
            atomicMax(&gmax[6 + hd], fkey(mxA));
            atomicMax(&gmax[6 + hd + 1], fkey(mxB));
        }
    }

    // ---- C store: transpose each 16x16 block, packed wide stores ----
    int b4 = lane & 3;
#pragma unroll
    for (int i = 0; i < 4; ++i) {
        int m = m0 + wrow * 64 + i * 16 + quad * 4 + b4;  // row after transpose
        bool mok = m < M;
#pragma unroll
        for (int j = 0; j < 4; ++j) {
            float v0 = acc[i][j][0], v1 = acc[i][j][1], v2 = acc[i][j][2], v3 = acc[i][j][3];
            xpose4(v0, v1, v2, v3, b4);  // all lanes participate
            int colb = n0 + wcol * 64 + j * 16 + (c16 & 12);
            if (F == 64) {
                if (mok) {
                    int pk = __builtin_amdgcn_cvt_pk_fp8_f32(v0, v1, 0, false);
                    pk = __builtin_amdgcn_cvt_pk_fp8_f32(v2, v3, pk, true);
                    *(unsigned*)&C8[(size_t)m * NREAL + colb] = (unsigned)pk;
                }
            } else {
                if (mok && colvalid) {
                    unsigned lo = (unsigned)f2bf(v0) | ((unsigned)f2bf(v1) << 16);
                    unsigned hi = (unsigned)f2bf(v2) | ((unsigned)f2bf(v3) << 16);
                    uint2 pk2;
                    pk2.x = lo;
                    pk2.y = hi;
                    *(uint2*)&C[(size_t)m * NREAL + colb] = pk2;
                }
            }
        }
    }
}

// ---------------- online-rescale softmax-aggregate (layer 1) ----------------
template <int F>
__global__ __launch_bounds__(256) void aggregate_fused(
    const __hip_bfloat16* __restrict__ h, const float* __restrict__ es,
    const float* __restrict__ ed, const int* __restrict__ offsets,
    const int* __restrict__ ssrc, unsigned short* __restrict__ oh,
    unsigned short* __restrict__ ol, int n) {
    constexpr int HF = HHEADS * F;
    constexpr int C8 = HF / 8;
    int tid = blockIdx.x * blockDim.x + threadIdx.x;
    if (tid >= n * C8) return;
    int node = tid / C8, q = tid % C8;
    int c = q * 8, hd = c / F;
    int a = offsets[node], b = offsets[node + 1];
    float edv = ed[node * HHEADS + hd];
    float m = -1e30f, l = 0.f;
    float acc[8] = {};
    for (int j = a; j < b; ++j) {
        int s = ssrc[j];
        float v = es[s * HHEADS + hd] + edv;
        v = v > 0.f ? v : 0.2f * v;  // leaky relu 0.2
        float mn = fmaxf(m, v);
        float r = __expf(m - mn);
        float wgt = __expf(v - mn);
        uint4 hv = *(const uint4*)&h[(size_t)s * HF + c];
        l = l * r + wgt;
        acc[0] = acc[0] * r + wgt * bfl(hv.x);
        acc[1] = acc[1] * r + wgt * bfh(hv.x);
        acc[2] = acc[2] * r + wgt * bfl(hv.y);
        acc[3] = acc[3] * r + wgt * bfh(hv.y);
        acc[4] = acc[4] * r + wgt * bfl(hv.z);
        acc[5] = acc[5] * r + wgt * bfh(hv.z);
        acc[6] = acc[6] * r + wgt * bfl(hv.w);
        acc[7] = acc[7] * r + wgt * bfh(hv.w);
        m = mn;
    }
    float invd = 1.0f / (l + 1e-16f);
    float res[8];
#pragma unroll
    for (int k = 0; k < 8; ++k) {
        float v = acc[k] * invd;
        res[k] = v > 0.f ? v : (__expf(v) - 1.0f);  // elu
    }
    constexpr int NKT = HF / 32;
    unsigned short th[8], tl[8];
#pragma unroll
    for (int k = 0; k < 8; ++k) {
        unsigned short hh = f2bf(res[k]);
        th[k] = hh;
        tl[k] = f2bf(res[k] - bf2f(hh));
    }
    int lq = (node & 15) | (((c >> 3) & 3) << 4);
    size_t base = ((size_t)((node >> 4) * NKT + (c >> 5)) * 64 + lq) * 8;
    *(uint4*)&oh[base] = *(uint4*)th;
    *(uint4*)&ol[base] = *(uint4*)tl;
}

// ---------------- wave-per-node single-pass aggregate (layer 2) ----------------
__global__ __launch_bounds__(256) void aggregate_wpn2(
    const __hip_bfloat16* __restrict__ h, const float* __restrict__ es,
    const float* __restrict__ ed, const unsigned* __restrict__ gmax,
    const int* __restrict__ offsets, const int* __restrict__ ssrc,
    unsigned short* __restrict__ oh, unsigned short* __restrict__ ol, int n) {
    constexpr int HF = 192;
    int wid = (int)((blockIdx.x * (unsigned)blockDim.x + threadIdx.x) >> 6);
    int lane = threadIdx.x & 63;
    if (wid >= n || lane >= 48) return;
    int node = wid;
    int hd = lane >> 3;  // F=32: 8 lanes (32ch) per head
    int c = lane * 4;
    int a = offsets[node], b = offsets[node + 1];
    float edv = ed[node * HHEADS + hd];
    float mv = funkey(gmax[6 + hd]) + edv;
    float m = mv > 0.f ? mv : 0.2f * mv;
    float l = 0.f;
    float acc[4] = {};
    const unsigned short* hbase = (const unsigned short*)h + c;
    int j = a;
    for (; j + 1 < b; j += 2) {
        int s0 = ssrc[j], s1 = ssrc[j + 1];
        float ev0 = es[(size_t)s0 * HHEADS + hd];
        float ev1 = es[(size_t)s1 * HHEADS + hd];
        uint2 h0 = *(const uint2*)(hbase + (size_t)s0 * HF);
        uint2 h1 = *(const uint2*)(hbase + (size_t)s1 * HF);
        float v0 = ev0 + edv;
        v0 = v0 > 0.f ? v0 : 0.2f * v0;
        float v1 = ev1 + edv;
        v1 = v1 > 0.f ? v1 : 0.2f * v1;
        float w0 = __expf(v0 - m);
        float w1 = __expf(v1 - m);
        l += w0;
        acc[0] += w0 * bfl(h0.x);
        acc[1] += w0 * bfh(h0.x);
        acc[2] += w0 * bfl(h0.y);
        acc[3] += w0 * bfh(h0.y);
        l += w1;
        acc[0] += w1 * bfl(h1.x);
        acc[1] += w1 * bfh(h1.x);
        acc[2] += w1 * bfl(h1.y);
        acc[3] += w1 * bfh(h1.y);
    }
    if (j < b) {
        int s0 = ssrc[j];
        float ev0 = es[(size_t)s0 * HHEADS + hd];
        uint2 h0 = *(const uint2*)(hbase + (size_t)s0 * HF);
        float v0 = ev0 + edv;
        v0 = v0 > 0.f ? v0 : 0.2f * v0;
        float w0 = __expf(v0 - m);
        l += w0;
        acc[0] += w0 * bfl(h0.x);
        acc[1] += w0 * bfh(h0.x);
        acc[2] += w0 * bfl(h0.y);
        acc[3] += w0 * bfh(h0.y);
    }
    float invd = 1.0f / (l + 1e-16f);
    unsigned short th[4], tl[4];
#pragma unroll
    for (int k = 0; k < 4; ++k) {
        float v = acc[k] * invd;
        v = v > 0.f ? v : (__expf(v) - 1.0f);  // elu
        unsigned short hh = f2bf(v);
        th[k] = hh;
        tl[k] = f2bf(v - bf2f(hh));
    }
    int lq = (node & 15) | (((c >> 3) & 3) << 4);
    size_t base = ((size_t)((node >> 4) * (HF / 32) + (c >> 5)) * 64 + lq) * 8 + (c & 7);
    *(uint2*)&oh[base] = *(uint2*)th;
    *(uint2*)&ol[base] = *(uint2*)tl;
}

// ---------------- wave-per-node single-pass aggregate (layer 3, fp8 h) --------
__global__ __launch_bounds__(256) void aggregate_wpn3(
    const unsigned char* __restrict__ h8, const float* __restrict__ es,
    const float* __restrict__ ed, const unsigned* __restrict__ gmax,
    const int* __restrict__ offsets, const int* __restrict__ ssrc,
    __hip_bfloat16* __restrict__ outb, int n) {
    constexpr int HF = 384;
    int wid = (int)((blockIdx.x * (unsigned)blockDim.x + threadIdx.x) >> 6);
    int lane = threadIdx.x & 63;
    if (wid >= n || lane >= 48) return;
    int node = wid;
    int hd = lane >> 3;  // 8 lanes (64ch) per head
    int c = lane * 8;
    int a = offsets[node], b = offsets[node + 1];
    float edv = ed[node * HHEADS + hd];
    float mv = funkey(gmax[hd]) + edv;
    float m = mv > 0.f ? mv : 0.2f * mv;
    float l = 0.f;
    float acc[8] = {};
    const unsigned char* hbase = h8 + c;
    int j = a;
    for (; j + 1 < b; j += 2) {
        int s0 = ssrc[j], s1 = ssrc[j + 1];
        float ev0 = es[(size_t)s0 * HHEADS + hd];
        float ev1 = es[(size_t)s1 * HHEADS + hd];
        uint2 h0 = *(const uint2*)(hbase + (size_t)s0 * HF);
        uint2 h1 = *(const uint2*)(hbase + (size_t)s1 * HF);
        float v0 = ev0 + edv;
        v0 = v0 > 0.f ? v0 : 0.2f * v0;
        float v1 = ev1 + edv;
        v1 = v1 > 0.f ? v1 : 0.2f * v1;
        float w0 = __expf(v0 - m);
        float w1 = __expf(v1 - m);
        {
            f32x2 p0 = __builtin_amdgcn_cvt_pk_f32_fp8((int)h0.x, false);
            f32x2 p1 = __builtin_amdgcn_cvt_pk_f32_fp8((int)h0.x, true);
            f32x2 p2 = __builtin_amdgcn_cvt_pk_f32_fp8((int)h0.y, false);
            f32x2 p3 = __builtin_amdgcn_cvt_pk_f32_fp8((int)h0.y, true);
            l += w0;
            acc[0] += w0 * p0[0];
            acc[1] += w0 * p0[1];
            acc[2] += w0 * p1[0];
            acc[3] += w0 * p1[1];
            acc[4] += w0 * p2[0];
            acc[5] += w0 * p2[1];
            acc[6] += w0 * p3[0];
            acc[7] += w0 * p3[1];
        }
        {
            f32x2 p0 = __builtin_amdgcn_cvt_pk_f32_fp8((int)h1.x, false);
            f32x2 p1 = __builtin_amdgcn_cvt_pk_f32_fp8((int)h1.x, true);
            f32x2 p2 = __builtin_amdgcn_cvt_pk_f32_fp8((int)h1.y, false);
            f32x2 p3 = __builtin_amdgcn_cvt_pk_f32_fp8((int)h1.y, true);
            l += w1;
            acc[0] += w1 * p0[0];
            acc[1] += w1 * p0[1];
            acc[2] += w1 * p1[0];
            acc[3] += w1 * p1[1];
            acc[4] += w1 * p2[0];
            acc[5] += w1 * p2[1];
            acc[6] += w1 * p3[0];
            acc[7] += w1 * p3[1];
        }
    }
    if (j < b) {
        int s0 = ssrc[j];
        float ev0 = es[(size_t)s0 * HHEADS + hd];
        uint2 h0 = *(const uint2*)(hbase + (size_t)s0 * HF);
        float v0 = ev0 + edv;
        v0 = v0 > 0.f ? v0 : 0.2f * v0;
        float w0 = __expf(v0 - m);
        f32x2 p0 = __builtin_amdgcn_cvt_pk_f32_fp8((int)h0.x, false);
        f32x2 p1 = __builtin_amdgcn_cvt_pk_f32_fp8((int)h0.x, true);
        f32x2 p2 = __builtin_amdgcn_cvt_pk_f32_fp8((int)h0.y, false);
        f32x2 p3 = __builtin_amdgcn_cvt_pk_f32_fp8((int)h0.y, true);
        l += w0;
        acc[0] += w0 * p0[0];
        acc[1] += w0 * p0[1];
        acc[2] += w0 * p1[0];
        acc[3] += w0 * p1[1];
        acc[4] += w0 * p2[0];
        acc[5] += w0 * p2[1];
        acc[6] += w0 * p3[0];
        acc[7] += w0 * p3[1];
    }
    float invd = 1.0f / (l + 1e-16f);
    __hip_bfloat16 tb[8];
#pragma unroll
    for (int k = 0; k < 8; ++k) {
        float v = acc[k] * invd;
        v = v > 0.f ? v : (__expf(v) - 1.0f);  // elu
        tb[k] = __float2bfloat16(v);
    }
    *(uint4*)&outb[(size_t)node * HF + c] = *(uint4*)tb;
}

// ---------------- pooling (bf16 input) + head ----------------
__global__ void pool_kernel(const __hip_bfloat16* __restrict__ out3, float* __restrict__ g,
                            int n) {
    int b = blockIdx.x, t = threadIdx.x;  // blockDim = 192
    int chunk = (n + gridDim.x - 1) / gridDim.x;
    int n0 = b * chunk, n1 = min(n, n0 + chunk);
    float a0 = 0.f, a1 = 0.f;
    const unsigned* p = (const unsigned*)out3;
    for (int node = n0; node < n1; ++node) {
        unsigned u = p[(size_t)node * 192 + t];
        a0 += bfl(u);
        a1 += bfh(u);
    }
    atomicAdd(&g[2 * t], a0);
    atomicAdd(&g[2 * t + 1], a1);
}

__global__ void final_kernel(const float* __restrict__ g, const float* __restrict__ Wd,
                             const float* __restrict__ bd, float* __restrict__ outp) {
    __shared__ float red[384];
    int t = threadIdx.x;  // blockDim = 384
    float v = g[t];
    red[t] = v * v;
    __syncthreads();
    for (int s = 192; s >= 3; s >>= 1) {
        if (t < s) red[t] += red[t + s];
        __syncthreads();
    }
    __shared__ float scale_s;
    if (t == 0) {
        float norm = sqrtf(red[0] + red[1] + red[2]);
        scale_s = 1.0f / fmaxf(norm, 1e-12f);
    }
    __syncthreads();
    float scale = scale_s;
    red[t] = v * scale * Wd[t];
    __syncthreads();
    for (int s = 192; s >= 3; s >>= 1) {
        if (t < s) red[t] += red[t + s];
        __syncthreads();
    }
    if (t == 0) outp[0] = red[0] + red[1] + red[2] + bd[0];
}

// ---------------- host side ----------------
extern "C" void kernel_launch(void* const* d_in, const int* in_sizes, int n_in, void* d_out,
                              int out_size, void* d_ws, size_t ws_size, hipStream_t stream) {
    const float* x = (const float*)d_in[0];
    const int* ei = (const int*)d_in[1];
    const float* W1 = (const float*)d_in[2];
    const float* a1s = (const float*)d_in[3];
    const float* a1d = (const float*)d_in[4];
    const float* W2 = (const float*)d_in[5];
    const float* a2s = (const float*)d_in[6];
    const float* a2d = (const float*)d_in[7];
    const float* W3 = (const float*)d_in[8];
    const float* a3s = (const float*)d_in[9];
    const float* a3d = (const float*)d_in[10];
    const float* Wd = (const float*)d_in[11];
    const float* bd = (const float*)d_in[12];
    float* outp = (float*)d_out;

    const int N = in_sizes[0] / 11;
    const int E = in_sizes[1] / 2;
    const int* src = ei;
    const int* dst = ei + E;

    const int NT16 = ((N + 127) / 128) * 8;  // padded 16-row tiles

    char* w = (char*)d_ws;
    size_t off = 0;
    auto A = [&](size_t bytes) {
        size_t o = off;
        off += (bytes + 255) & ~(size_t)255;
        return o;
    };
    __hip_bfloat16* bufH = (__hip_bfloat16*)(w + A((size_t)N * 384 * 2));  // h (bf16 / fp8@L3)
    __hip_bfloat16* bufO = (__hip_bfloat16*)(w + A((size_t)N * 384 * 2));  // layer3 out (bf16)
    unsigned short* apH = (unsigned short*)(w + A((size_t)NT16 * 6 * 512 * 2));  // A-pack hi
    unsigned short* apL = (unsigned short*)(w + A((size_t)NT16 * 6 * 512 * 2));  // A-pack lo
    unsigned short* b2H = (unsigned short*)(w + A((size_t)16 * 3 * 512 * 2));    // W2 pack
    unsigned short* b2L = (unsigned short*)(w + A((size_t)16 * 3 * 512 * 2));
    unsigned short* b3H = (unsigned short*)(w + A((size_t)24 * 6 * 512 * 2));    // W3 pack
    unsigned short* b3L = (unsigned short*)(w + A((size_t)24 * 6 * 512 * 2));
    float* es = (float*)(w + A((size_t)N * HHEADS * 4));
    float* ed = (float*)(w + A((size_t)N * HHEADS * 4));
    unsigned* gmax = (unsigned*)(w + A(256));
    float* wp = (float*)(w + A((size_t)11 * 96 * 4));  // layer-1 f32 repack
    int* count = (int*)(w + A((size_t)(N + 1) * 4));
    int* cursor = (int*)(w + A((size_t)(N + 1) * 4));
    int* offsets = (int*)(w + A((size_t)(N + 1) * 4));
    int* bsum = (int*)(w + A(64 * 4));
    int* ssrc = (int*)(w + A((size_t)E * 4));
    float* g = (float*)(w + A(384 * 4));

    // one-shot zero of all small scratch (count, cursor, g, gmax, A-pack pads)
    const long t16v = N / 16;
    const long padT = NT16 - t16v;
    zero_misc<<<(N + 255) / 256, 256, 0, stream>>>(count, cursor, g, gmax, apH, apL,
                                                   t16v * 3 * 512, padT * 3 * 512,
                                                   t16v * 6 * 512, padT * 6 * 512, N);

    // CSR build (by dst)
    hist_kernel<<<(E + 255) / 256, 256, 0, stream>>>(dst, count, E);
    int nb = (N + 1023) / 1024;
    scan_block<<<nb, 1024, 0, stream>>>(count, offsets, bsum, N);
    scan_tops<<<1, 64, 0, stream>>>(bsum, nb);
    scan_add<<<nb, 1024, 0, stream>>>(offsets, bsum, N, E);
    scatter_kernel<<<(E + 255) / 256, 256, 0, stream>>>(src, dst, offsets, cursor, ssrc, E);

    // weight packs
    repack_w<<<(11 * 96 + 255) / 256, 256, 0, stream>>>(W1, wp, 11, 16);
    repack_w_mfma<<<(96 * 256 + 255) / 256, 256, 0, stream>>>(W2, b2H, b2L, 96, 32, 256);
    repack_w_mfma<<<(192 * 384 + 255) / 256, 256, 0, stream>>>(W3, b3H, b3L, 192, 64, 384);

    // ---- layer 1 (FIN=11, F=16): gemm + fused attn terms ----
    {
        dim3 grid((96 + 63) / 64, (N + 63) / 64);
        gemm_small_attn<64, 64, 32><<<grid, 256, 0, stream>>>(x, wp, bufH, a1s, a1d, es, ed, N,
                                                              11, 96);
    }
    {
        long total = (long)N * (96 / 8);
        aggregate_fused<16><<<(total + 255) / 256, 256, 0, stream>>>(bufH, es, ed, offsets,
                                                                     ssrc, apH, apL, N);
    }

    // ---- layer 2 (K=96, N=192 pad 256, F=32): bf16 C + fused gmax(6-11) ----
    {
        dim3 grid(256 / 128, (N + 127) / 128);
        gemm_attn_mfma<96, 192, 256, 32><<<grid, 256, 0, stream>>>(
            apH, apL, b2H, b2L, bufH, (unsigned char*)nullptr, a2s, a2d, es, ed, gmax, N);
    }
    {
        int grid = (N + 3) / 4;  // 4 waves/block, wave-per-node
        aggregate_wpn2<<<grid, 256, 0, stream>>>(bufH, es, ed, gmax, offsets, ssrc, apH, apL,
                                                 N);
    }

    // ---- layer 3 (K=192, N=384, F=64): fp8 C + fused gmax(0-5) ----
    {
        dim3 grid(384 / 128, (N + 127) / 128);
        gemm_attn_mfma<192, 384, 384, 64><<<grid, 256, 0, stream>>>(
            apH, apL, b3H, b3L, bufH, (unsigned char*)bufH, a3s, a3d, es, ed, gmax, N);
    }
    {
        int grid = (N + 3) / 4;
        aggregate_wpn3<<<grid, 256, 0, stream>>>((const unsigned char*)bufH, es, ed, gmax,
                                                 offsets, ssrc, bufO, N);
    }

    // sum-pool (bf16 in) -> normalize -> dense
    pool_kernel<<<256, 192, 0, stream>>>(bufO, g, N);
    final_kernel<<<1, 384, 0, stream>>>(g, Wd, bd, outp);
}

// Round 7
// 576.891 us; speedup vs baseline: 1.0039x; 1.0039x over previous
//
#include <hip/hip_runtime.h>
#include <hip/hip_bf16.h>

// GAT 3-layer: N=50000 nodes, E=800000 edges, H=6 heads.
// R1-R17: MFMA split-bf16 GEMMs + CSR fused softmax/aggregate ladder (545us).
// R20: L3 aggregate wave-per-node; aggregates pin at bytes-through-L2-miss.
// R21: L3 h -> fp8 e4m3 (halved aggregate bytes; absmax 0) + L2 wpn agg.
// R22/R23: packed stores, global_load_lds: BOTH NULL (83us, MfmaUtil 10%,
//      counters identical). Lesson: cost is STRUCTURAL - per kt the kernel
//      does stage -> full-drain syncthreads -> MFMA, exposing all memory
//      latency; skinny K (NKT=6) + ~3 blocks/CU gives no TLP to hide it.
// R24: 2-phase software pipeline (guide T3/T4-lite, m230/m248-verified):
//      double-buffered LDS (64KB), per kt: STAGE(kt+1,buf^1) FIRST, ds_read
//      buf, lgkmcnt(0)+sched_barrier, MFMA, vmcnt(0)+raw s_barrier. Latency
//      of kt+1 hides under kt's compute. + bijective XCD swizzle (m204):
//      3 x-siblings sharing an A-tile land on one XCD -> A fetched once/XCD.

#define HHEADS 6

typedef __attribute__((ext_vector_type(8))) short bf16x8;   // 8 bf16 = 4 VGPR
typedef __attribute__((ext_vector_type(4))) float f32x4;    // mfma C/D
typedef __attribute__((ext_vector_type(2))) float f32x2;

typedef __attribute__((address_space(3))) unsigned int lds_uint;
typedef const __attribute__((address_space(1))) unsigned int glb_uint;

__device__ __forceinline__ float bfl(unsigned u) { return __uint_as_float(u << 16); }
__device__ __forceinline__ float bfh(unsigned u) { return __uint_as_float(u & 0xffff0000u); }
__device__ __forceinline__ unsigned short f2bf(float v) {  // RNE f32->bf16
    unsigned u = __float_as_uint(v);
    return (unsigned short)((u + 0x7fffu + ((u >> 16) & 1u)) >> 16);
}
__device__ __forceinline__ float bf2f(unsigned short h) {
    return __uint_as_float((unsigned)h << 16);
}
// monotone float<->uint for atomicMax on floats (memset-0 = -inf identity)
__device__ __forceinline__ unsigned fkey(float f) {
    unsigned u = __float_as_uint(f);
    return (u >> 31) ? ~u : (u | 0x80000000u);
}
__device__ __forceinline__ float funkey(unsigned k) {
    return (k >> 31) ? __uint_as_float(k & 0x7fffffffu) : __uint_as_float(~k);
}

// 4x4 transpose across a 4-lane group (lanes share lane>>2). In: v0..v3 =
// rows 0..3 at this lane's column. Out: v0..v3 = cols 0..3 at row (lane&3).
__device__ __forceinline__ void xpose4(float& v0, float& v1, float& v2, float& v3, int b) {
    bool hi = (b & 2) != 0;
    float s0 = hi ? v0 : v2;
    float s1 = hi ? v1 : v3;
    s0 = __shfl_xor(s0, 2, 64);
    s1 = __shfl_xor(s1, 2, 64);
    v0 = hi ? s0 : v0;
    v1 = hi ? s1 : v1;
    v2 = hi ? v2 : s0;
    v3 = hi ? v3 : s1;
    bool od = (b & 1) != 0;
    float t0 = od ? v0 : v1;
    t0 = __shfl_xor(t0, 1, 64);
    v0 = od ? t0 : v0;
    v1 = od ? v1 : t0;
    float t1 = od ? v2 : v3;
    t1 = __shfl_xor(t1, 1, 64);
    v2 = od ? t1 : v2;
    v3 = od ? v3 : t1;
}

// ---------------- one-shot zero of all small scratch ----------------
__global__ void zero_misc(int* __restrict__ count, int* __restrict__ cursor,
                          float* __restrict__ g, unsigned* __restrict__ gmax,
                          unsigned short* __restrict__ apH, unsigned short* __restrict__ apL,
                          long pad3_off, long pad3_cnt, long pad6_off, long pad6_cnt, int n) {
    long i = (long)blockIdx.x * blockDim.x + threadIdx.x;
    long stride = (long)gridDim.x * blockDim.x;
    for (long j = i; j < n; j += stride) {
        count[j] = 0;
        cursor[j] = 0;
    }
    if (i < 384) g[i] = 0.f;
    if (i < 12) gmax[i] = 0u;  // slots 0-5: L3, 6-11: L2
    for (long j = i; j < pad3_cnt; j += stride) {
        apH[pad3_off + j] = 0;
        apL[pad3_off + j] = 0;
    }
    for (long j = i; j < pad6_cnt; j += stride) {
        apH[pad6_off + j] = 0;
        apL[pad6_off + j] = 0;
    }
}

// ---------------- CSR build ----------------
__global__ void hist_kernel(const int* __restrict__ dst, int* __restrict__ count, int E) {
    int e = blockIdx.x * blockDim.x + threadIdx.x;
    if (e >= E) return;
    atomicAdd(&count[dst[e]], 1);
}

__global__ void scan_block(const int* __restrict__ count, int* __restrict__ offsets,
                           int* __restrict__ bsum, int n) {
    __shared__ int s[1024];
    int i = blockIdx.x * 1024 + threadIdx.x;
    int v = (i < n) ? count[i] : 0;
    s[threadIdx.x] = v;
    __syncthreads();
    for (int off = 1; off < 1024; off <<= 1) {
        int t = (threadIdx.x >= (unsigned)off) ? s[threadIdx.x - off] : 0;
        __syncthreads();
        s[threadIdx.x] += t;
        __syncthreads();
    }
    if (i < n) offsets[i] = s[threadIdx.x] - v;
    if (threadIdx.x == 1023) bsum[blockIdx.x] = s[1023];
}

__global__ void scan_tops(int* __restrict__ bsum, int nb) {
    __shared__ int s[64];
    int t = threadIdx.x;
    int v = (t < nb) ? bsum[t] : 0;
    s[t] = v;
    __syncthreads();
    for (int off = 1; off < 64; off <<= 1) {
        int tmp = (t >= off) ? s[t - off] : 0;
        __syncthreads();
        s[t] += tmp;
        __syncthreads();
    }
    if (t < nb) bsum[t] = s[t] - v;
}

__global__ void scan_add(int* __restrict__ offsets, const int* __restrict__ bsum, int n,
                         int total) {
    int i = blockIdx.x * 1024 + threadIdx.x;
    if (i < n) offsets[i] += bsum[blockIdx.x];
    if (i == 0) offsets[n] = total;
}

__global__ void scatter_kernel(const int* __restrict__ src, const int* __restrict__ dst,
                               const int* __restrict__ offsets, int* __restrict__ cursor,
                               int* __restrict__ ssrc, int E) {
    int e = blockIdx.x * blockDim.x + threadIdx.x;
    if (e >= E) return;
    int d = dst[e];
    int pos = offsets[d] + atomicAdd(&cursor[d], 1);
    ssrc[pos] = src[e];
}

// ---------------- weight repacks ----------------
__global__ void repack_w(const float* __restrict__ W, float* __restrict__ Wp, int FIN, int F) {
    int HF = HHEADS * F;
    int i = blockIdx.x * blockDim.x + threadIdx.x;
    if (i >= FIN * HF) return;
    int k = i / HF, c = i % HF;
    int hd = c / F, f = c % F;
    Wp[i] = W[(hd * FIN + k) * F + f];
}

// split-bf16 pack in MFMA B-fragment layout (B^T: lane n=..&15, k contiguous)
__global__ void repack_w_mfma(const float* __restrict__ W, unsigned short* __restrict__ bh,
                              unsigned short* __restrict__ bl, int FIN, int F, int NPAD) {
    int i = blockIdx.x * blockDim.x + threadIdx.x;
    if (i >= FIN * NPAD) return;
    int k = i / NPAD, n = i % NPAD;
    int NKT = FIN / 32;
    int HF = HHEADS * F;
    float w = 0.f;
    if (n < HF) {
        int hd = n / F, f = n % F;
        w = W[(hd * FIN + k) * F + f];
    }
    unsigned short h = f2bf(w);
    unsigned short l = f2bf(w - bf2f(h));
    size_t e = ((size_t)((n >> 4) * NKT + (k >> 5)) * 64 + ((n & 15) | (((k >> 3) & 3) << 4))) * 8 +
               (k & 7);
    bh[e] = h;
    bl[e] = l;
}

// ---------------- small GEMM + fused attn (layer 1, K=11, F=16) ----------------
template <int BM, int BN, int BK>
__global__ __launch_bounds__(256) void gemm_small_attn(const float* __restrict__ A,
                                                       const float* __restrict__ B,
                                                       __hip_bfloat16* __restrict__ C,
                                                       const float* __restrict__ as_,
                                                       const float* __restrict__ ad_,
                                                       float* __restrict__ es,
                                                       float* __restrict__ ed, int M, int K,
                                                       int N) {
    __shared__ float As[BK][BM + 4];
    __shared__ float Bs[BK][BN];
    int tid = threadIdx.x;
    int tx = tid % 16, ty = tid / 16;
    int m0 = blockIdx.y * BM, n0 = blockIdx.x * BN;
    float acc[4][4] = {};
    for (int kk0 = 0; kk0 < K; kk0 += BK) {
#pragma unroll
        for (int i = 0; i < (BM * BK) / 256; ++i) {
            int idx = tid + i * 256;
            int m = idx / BK, k = idx % BK;
            float v = 0.f;
            if (m0 + m < M && kk0 + k < K) v = A[(size_t)(m0 + m) * K + kk0 + k];
            As[k][m] = v;
        }
#pragma unroll
        for (int i = 0; i < (BK * BN) / 1024; ++i) {
            int idx = tid + i * 256;
            int k = idx / (BN / 4), n4 = idx % (BN / 4);
            float4 v = make_float4(0.f, 0.f, 0.f, 0.f);
            if (kk0 + k < K && n0 + n4 * 4 < N)
                v = *(const float4*)&B[(size_t)(kk0 + k) * N + n0 + n4 * 4];
            *(float4*)&Bs[k][n4 * 4] = v;
        }
        __syncthreads();
#pragma unroll
        for (int k = 0; k < BK; ++k) {
            float4 av = *(const float4*)&As[k][ty * 4];
            float4 bv = *(const float4*)&Bs[k][tx * 4];
            float a[4] = {av.x, av.y, av.z, av.w};
            float b[4] = {bv.x, bv.y, bv.z, bv.w};
#pragma unroll
            for (int i = 0; i < 4; ++i)
#pragma unroll
                for (int j = 0; j < 4; ++j) acc[i][j] += a[i] * b[j];
        }
        __syncthreads();
    }
    bool colok = (n0 + tx * 4) < N;
    float asv[4], adv[4];
#pragma unroll
    for (int j = 0; j < 4; ++j) {
        int col = n0 + tx * 4 + j;
        asv[j] = (col < N) ? as_[col] : 0.f;
        adv[j] = (col < N) ? ad_[col] : 0.f;
    }
#pragma unroll
    for (int i = 0; i < 4; ++i) {
        int m = m0 + ty * 4 + i;
        bool mok = m < M;
        if (mok && colok) {
            __hip_bfloat16 tmp[4];
#pragma unroll
            for (int j = 0; j < 4; ++j) tmp[j] = __float2bfloat16(acc[i][j]);
            *(uint2*)&C[(size_t)m * N + n0 + tx * 4] = *(uint2*)tmp;
        }
        float ps = 0.f, pd = 0.f;
#pragma unroll
        for (int j = 0; j < 4; ++j) {
            ps += acc[i][j] * asv[j];
            pd += acc[i][j] * adv[j];
        }
        ps += __shfl_down(ps, 2, 4);
        ps += __shfl_down(ps, 1, 4);
        pd += __shfl_down(pd, 2, 4);
        pd += __shfl_down(pd, 1, 4);
        if (mok && colok && (tx & 3) == 0) {
            int hd = (n0 + tx * 4) >> 4;  // F=16
            es[(size_t)m * HHEADS + hd] = ps;
            ed[(size_t)m * HHEADS + hd] = pd;
        }
    }
}

// ---------------- MFMA split-bf16 GEMM + fused attn (layers 2/3) ----------------
// R24: 2-phase pipeline: double LDS buffers; per kt issue next-tile
// global_load_lds BEFORE compute; counted waits (lgkmcnt for ds_read->MFMA,
// vmcnt+raw barrier at phase end). XCD-bijective work swizzle (m204).
// F==64: C fp8 e4m3; gmax slots 0-5. F==32: C bf16; gmax slots 6-11.
template <int K, int NREAL, int NPAD, int F>
__global__ __launch_bounds__(256) void gemm_attn_mfma(
    const unsigned short* __restrict__ Ah, const unsigned short* __restrict__ Al,
    const unsigned short* __restrict__ Bh, const unsigned short* __restrict__ Bl,
    __hip_bfloat16* __restrict__ C, unsigned char* __restrict__ C8,
    const float* __restrict__ as_, const float* __restrict__ ad_, float* __restrict__ es,
    float* __restrict__ ed, unsigned* __restrict__ gmax, int M) {
    constexpr int NKT = K / 32;
    __shared__ unsigned short sAh[2][4096], sAl[2][4096], sBh[2][4096], sBl[2][4096];
    int tid = threadIdx.x;
    int lane = tid & 63, wave = tid >> 6;
    int wrow = wave >> 1, wcol = wave & 1;
    int quad = lane >> 4, c16 = lane & 15;

    // XCD-bijective swizzle (m204): hardware dispatch id -> contiguous work
    // band per XCD, so the gridDim.x x-siblings sharing an A-tile co-locate.
    int nwg = gridDim.x * gridDim.y;
    int h = blockIdx.y * gridDim.x + blockIdx.x;  // dispatch order (x fastest)
    int q = nwg >> 3, r = nwg & 7;
    int xcd = h & 7, pos = h >> 3;
    int wk = (xcd < r ? xcd * (q + 1) : r * (q + 1) + (xcd - r) * q) + pos;
    int bx = wk % gridDim.x, by = wk / gridDim.x;

    int m0 = by * 128, n0 = bx * 128;
    int bt16 = m0 >> 4, bn16 = n0 >> 4;

    auto STAGE = [&](int kt, int buf) {
#pragma unroll
        for (int rep = 0; rep < 2; ++rep) {
            int chunk = tid + rep * 256;
            int tile = chunk >> 6, e8 = chunk & 63;
            size_t aoff = ((size_t)((bt16 + tile) * NKT + kt) * 64 + e8) * 8;
            size_t boff = ((size_t)((bn16 + tile) * NKT + kt) * 64 + e8) * 8;
            __builtin_amdgcn_global_load_lds((glb_uint*)&Ah[aoff],
                                             (lds_uint*)&sAh[buf][chunk * 8], 16, 0, 0);
            __builtin_amdgcn_global_load_lds((glb_uint*)&Al[aoff],
                                             (lds_uint*)&sAl[buf][chunk * 8], 16, 0, 0);
            __builtin_amdgcn_global_load_lds((glb_uint*)&Bh[boff],
                                             (lds_uint*)&sBh[buf][chunk * 8], 16, 0, 0);
            __builtin_amdgcn_global_load_lds((glb_uint*)&Bl[boff],
                                             (lds_uint*)&sBl[buf][chunk * 8], 16, 0, 0);
        }
    };

    f32x4 acc[4][4] = {};
    // prologue: stage tile 0, drain, barrier
    STAGE(0, 0);
    asm volatile("s_waitcnt vmcnt(0)" ::: "memory");
    __builtin_amdgcn_s_barrier();

#pragma unroll
    for (int kt = 0; kt < NKT; ++kt) {
        int cur = kt & 1;
        if (kt + 1 < NKT) STAGE(kt + 1, cur ^ 1);  // issue-early: hides latency
        bf16x8 fah[4], fal[4], fbh[4], fbl[4];
#pragma unroll
        for (int i = 0; i < 4; ++i) {
            fah[i] = *(const bf16x8*)&sAh[cur][(wrow * 4 + i) * 512 + lane * 8];
            fal[i] = *(const bf16x8*)&sAl[cur][(wrow * 4 + i) * 512 + lane * 8];
            fbh[i] = *(const bf16x8*)&sBh[cur][(wcol * 4 + i) * 512 + lane * 8];
            fbl[i] = *(const bf16x8*)&sBl[cur][(wcol * 4 + i) * 512 + lane * 8];
        }
        asm volatile("s_waitcnt lgkmcnt(0)" ::: "memory");
        __builtin_amdgcn_sched_barrier(0);  // rule #18: pin MFMA below the wait
#pragma unroll
        for (int i = 0; i < 4; ++i)
#pragma unroll
            for (int j = 0; j < 4; ++j) {
                acc[i][j] = __builtin_amdgcn_mfma_f32_16x16x32_bf16(fah[i], fbh[j], acc[i][j],
                                                                    0, 0, 0);
                acc[i][j] = __builtin_amdgcn_mfma_f32_16x16x32_bf16(fal[i], fbh[j], acc[i][j],
                                                                    0, 0, 0);
                acc[i][j] = __builtin_amdgcn_mfma_f32_16x16x32_bf16(fah[i], fbl[j], acc[i][j],
                                                                    0, 0, 0);
            }
        asm volatile("s_waitcnt vmcnt(0)" ::: "memory");  // next tile landed
        __builtin_amdgcn_s_barrier();
    }

    float asv[4], adv[4];
#pragma unroll
    for (int j = 0; j < 4; ++j) {
        int col = n0 + wcol * 64 + j * 16 + c16;
        bool ok = col < NREAL;
        asv[j] = ok ? as_[col] : 0.f;
        adv[j] = ok ? ad_[col] : 0.f;
    }
    float mx = -1e30f;                 // F==64 per-wave head max
    float mxA = -1e30f, mxB = -1e30f;  // F==32 per-wave 2-head max
    bool colvalid = (n0 + wcol * 64) < NREAL;

    // ---- es/ed + gmax (uses fragment layout; no C writes here) ----
#pragma unroll
    for (int i = 0; i < 4; ++i) {
#pragma unroll
        for (int r2 = 0; r2 < 4; ++r2) {
            int m = m0 + wrow * 64 + i * 16 + quad * 4 + r2;
            bool mok = m < M;
            if (F == 64) {
                float ps = acc[i][0][r2] * asv[0] + acc[i][1][r2] * asv[1] +
                           acc[i][2][r2] * asv[2] + acc[i][3][r2] * asv[3];
                float pd = acc[i][0][r2] * adv[0] + acc[i][1][r2] * adv[1] +
                           acc[i][2][r2] * adv[2] + acc[i][3][r2] * adv[3];
#pragma unroll
                for (int off = 8; off > 0; off >>= 1) {
                    ps += __shfl_down(ps, off, 16);
                    pd += __shfl_down(pd, off, 16);
                }
                if (mok && c16 == 0) {
                    int hd = (n0 + wcol * 64) / 64;
                    es[(size_t)m * HHEADS + hd] = ps;
                    ed[(size_t)m * HHEADS + hd] = pd;
                    mx = fmaxf(mx, ps);
                }
            } else {  // F == 32: two heads per wave-column
                float psA = acc[i][0][r2] * asv[0] + acc[i][1][r2] * asv[1];
                float pdA = acc[i][0][r2] * adv[0] + acc[i][1][r2] * adv[1];
                float psB = acc[i][2][r2] * asv[2] + acc[i][3][r2] * asv[3];
                float pdB = acc[i][2][r2] * adv[2] + acc[i][3][r2] * adv[3];
#pragma unroll
                for (int off = 8; off > 0; off >>= 1) {
                    psA += __shfl_down(psA, off, 16);
                    pdA += __shfl_down(pdA, off, 16);
                    psB += __shfl_down(psB, off, 16);
                    pdB += __shfl_down(pdB, off, 16);
                }
                if (mok && c16 == 0 && colvalid) {
                    int colbase = n0 + wcol * 64;
                    int hd = colbase / 32;
                    es[(size_t)m * HHEADS + hd] = psA;
                    ed[(size_t)m * HHEADS + hd] = pdA;
                    es[(size_t)m * HHEADS + hd + 1] = psB;
                    ed[(size_t)m * HHEADS + hd + 1] = pdB;
                    mxA = fmaxf(mxA, psA);
                    mxB = fmaxf(mxB, psB);
                }
            }
        }
    }
    if (F == 64) {  // per-head global es max, one atomic per wave (slots 0-5)
#pragma unroll
        for (int off = 32; off > 0; off >>= 1) mx = fmaxf(mx, __shfl_xor(mx, off));
        if (lane == 0) atomicMax(&gmax[(n0 + wcol * 64) / 64], fkey(mx));
    } else {  // slots 6-11
        mxA = fmaxf(mxA, __shfl_xor(mxA, 16));
        mxA = fmaxf(mxA, __shfl_xor(mxA, 32));
        mxB = fmaxf(mxB, __shfl_xor(mxB, 16));
        mxB = fmaxf(mxB, __shfl_xor(mxB, 32));
        if (lane == 0 && colvalid) {
            int hd = (n0 + wcol * 64) / 32;
            atomicMax(&gmax[6 + hd], fkey(mxA));
            atomicMax(&gmax[6 + hd + 1], fkey(mxB));
        }
    }

    // ---- C store: transpose each 16x16 block, packed wide stores ----
    int b4 = lane & 3;
#pragma unroll
    for (int i = 0; i < 4; ++i) {
        int m = m0 + wrow * 64 + i * 16 + quad * 4 + b4;  // row after transpose
        bool mok = m < M;
#pragma unroll
        for (int j = 0; j < 4; ++j) {
            float v0 = acc[i][j][0], v1 = acc[i][j][1], v2 = acc[i][j][2], v3 = acc[i][j][3];
            xpose4(v0, v1, v2, v3, b4);  // all lanes participate
            int colb = n0 + wcol * 64 + j * 16 + (c16 & 12);
            if (F == 64) {
                if (mok) {
                    int pk = __builtin_amdgcn_cvt_pk_fp8_f32(v0, v1, 0, false);
                    pk = __builtin_amdgcn_cvt_pk_fp8_f32(v2, v3, pk, true);
                    *(unsigned*)&C8[(size_t)m * NREAL + colb] = (unsigned)pk;
                }
            } else {
                if (mok && colvalid) {
                    unsigned lo = (unsigned)f2bf(v0) | ((unsigned)f2bf(v1) << 16);
                    unsigned hi = (unsigned)f2bf(v2) | ((unsigned)f2bf(v3) << 16);
                    uint2 pk2;
                    pk2.x = lo;
                    pk2.y = hi;
                    *(uint2*)&C[(size_t)m * NREAL + colb] = pk2;
                }
            }
        }
    }
}

// ---------------- online-rescale softmax-aggregate (layer 1) ----------------
template <int F>
__global__ __launch_bounds__(256) void aggregate_fused(
    const __hip_bfloat16* __restrict__ h, const float* __restrict__ es,
    const float* __restrict__ ed, const int* __restrict__ offsets,
    const int* __restrict__ ssrc, unsigned short* __restrict__ oh,
    unsigned short* __restrict__ ol, int n) {
    constexpr int HF = HHEADS * F;
    constexpr int C8 = HF / 8;
    int tid = blockIdx.x * blockDim.x + threadIdx.x;
    if (tid >= n * C8) return;
    int node = tid / C8, q = tid % C8;
    int c = q * 8, hd = c / F;
    int a = offsets[node], b = offsets[node + 1];
    float edv = ed[node * HHEADS + hd];
    float m = -1e30f, l = 0.f;
    float acc[8] = {};
    for (int j = a; j < b; ++j) {
        int s = ssrc[j];
        float v = es[s * HHEADS + hd] + edv;
        v = v > 0.f ? v : 0.2f * v;  // leaky relu 0.2
        float mn = fmaxf(m, v);
        float r = __expf(m - mn);
        float wgt = __expf(v - mn);
        uint4 hv = *(const uint4*)&h[(size_t)s * HF + c];
        l = l * r + wgt;
        acc[0] = acc[0] * r + wgt * bfl(hv.x);
        acc[1] = acc[1] * r + wgt * bfh(hv.x);
        acc[2] = acc[2] * r + wgt * bfl(hv.y);
        acc[3] = acc[3] * r + wgt * bfh(hv.y);
        acc[4] = acc[4] * r + wgt * bfl(hv.z);
        acc[5] = acc[5] * r + wgt * bfh(hv.z);
        acc[6] = acc[6] * r + wgt * bfl(hv.w);
        acc[7] = acc[7] * r + wgt * bfh(hv.w);
        m = mn;
    }
    float invd = 1.0f / (l + 1e-16f);
    float res[8];
#pragma unroll
    for (int k = 0; k < 8; ++k) {
        float v = acc[k] * invd;
        res[k] = v > 0.f ? v : (__expf(v) - 1.0f);  // elu
    }
    constexpr int NKT = HF / 32;
    unsigned short th[8], tl[8];
#pragma unroll
    for (int k = 0; k < 8; ++k) {
        unsigned short hh = f2bf(res[k]);
        th[k] = hh;
        tl[k] = f2bf(res[k] - bf2f(hh));
    }
    int lq = (node & 15) | (((c >> 3) & 3) << 4);
    size_t base = ((size_t)((node >> 4) * NKT + (c >> 5)) * 64 + lq) * 8;
    *(uint4*)&oh[base] = *(uint4*)th;
    *(uint4*)&ol[base] = *(uint4*)tl;
}

// ---------------- wave-per-node single-pass aggregate (layer 2) ----------------
__global__ __launch_bounds__(256) void aggregate_wpn2(
    const __hip_bfloat16* __restrict__ h, const float* __restrict__ es,
    const float* __restrict__ ed, const unsigned* __restrict__ gmax,
    const int* __restrict__ offsets, const int* __restrict__ ssrc,
    unsigned short* __restrict__ oh, unsigned short* __restrict__ ol, int n) {
    constexpr int HF = 192;
    int wid = (int)((blockIdx.x * (unsigned)blockDim.x + threadIdx.x) >> 6);
    int lane = threadIdx.x & 63;
    if (wid >= n || lane >= 48) return;
    int node = wid;
    int hd = lane >> 3;  // F=32: 8 lanes (32ch) per head
    int c = lane * 4;
    int a = offsets[node], b = offsets[node + 1];
    float edv = ed[node * HHEADS + hd];
    float mv = funkey(gmax[6 + hd]) + edv;
    float m = mv > 0.f ? mv : 0.2f * mv;
    float l = 0.f;
    float acc[4] = {};
    const unsigned short* hbase = (const unsigned short*)h + c;
    int j = a;
    for (; j + 1 < b; j += 2) {
        int s0 = ssrc[j], s1 = ssrc[j + 1];
        float ev0 = es[(size_t)s0 * HHEADS + hd];
        float ev1 = es[(size_t)s1 * HHEADS + hd];
        uint2 h0 = *(const uint2*)(hbase + (size_t)s0 * HF);
        uint2 h1 = *(const uint2*)(hbase + (size_t)s1 * HF);
        float v0 = ev0 + edv;
        v0 = v0 > 0.f ? v0 : 0.2f * v0;
        float v1 = ev1 + edv;
        v1 = v1 > 0.f ? v1 : 0.2f * v1;
        float w0 = __expf(v0 - m);
        float w1 = __expf(v1 - m);
        l += w0;
        acc[0] += w0 * bfl(h0.x);
        acc[1] += w0 * bfh(h0.x);
        acc[2] += w0 * bfl(h0.y);
        acc[3] += w0 * bfh(h0.y);
        l += w1;
        acc[0] += w1 * bfl(h1.x);
        acc[1] += w1 * bfh(h1.x);
        acc[2] += w1 * bfl(h1.y);
        acc[3] += w1 * bfh(h1.y);
    }
    if (j < b) {
        int s0 = ssrc[j];
        float ev0 = es[(size_t)s0 * HHEADS + hd];
        uint2 h0 = *(const uint2*)(hbase + (size_t)s0 * HF);
        float v0 = ev0 + edv;
        v0 = v0 > 0.f ? v0 : 0.2f * v0;
        float w0 = __expf(v0 - m);
        l += w0;
        acc[0] += w0 * bfl(h0.x);
        acc[1] += w0 * bfh(h0.x);
        acc[2] += w0 * bfl(h0.y);
        acc[3] += w0 * bfh(h0.y);
    }
    float invd = 1.0f / (l + 1e-16f);
    unsigned short th[4], tl[4];
#pragma unroll
    for (int k = 0; k < 4; ++k) {
        float v = acc[k] * invd;
        v = v > 0.f ? v : (__expf(v) - 1.0f);  // elu
        unsigned short hh = f2bf(v);
        th[k] = hh;
        tl[k] = f2bf(v - bf2f(hh));
    }
    int lq = (node & 15) | (((c >> 3) & 3) << 4);
    size_t base = ((size_t)((node >> 4) * (HF / 32) + (c >> 5)) * 64 + lq) * 8 + (c & 7);
    *(uint2*)&oh[base] = *(uint2*)th;
    *(uint2*)&ol[base] = *(uint2*)tl;
}

// ---------------- wave-per-node single-pass aggregate (layer 3, fp8 h) --------
__global__ __launch_bounds__(256) void aggregate_wpn3(
    const unsigned char* __restrict__ h8, const float* __restrict__ es,
    const float* __restrict__ ed, const unsigned* __restrict__ gmax,
    const int* __restrict__ offsets, const int* __restrict__ ssrc,
    __hip_bfloat16* __restrict__ outb, int n) {
    constexpr int HF = 384;
    int wid = (int)((blockIdx.x * (unsigned)blockDim.x + threadIdx.x) >> 6);
    int lane = threadIdx.x & 63;
    if (wid >= n || lane >= 48) return;
    int node = wid;
    int hd = lane >> 3;  // 8 lanes (64ch) per head
    int c = lane * 8;
    int a = offsets[node], b = offsets[node + 1];
    float edv = ed[node * HHEADS + hd];
    float mv = funkey(gmax[hd]) + edv;
    float m = mv > 0.f ? mv : 0.2f * mv;
    float l = 0.f;
    float acc[8] = {};
    const unsigned char* hbase = h8 + c;
    int j = a;
    for (; j + 1 < b; j += 2) {
        int s0 = ssrc[j], s1 = ssrc[j + 1];
        float ev0 = es[(size_t)s0 * HHEADS + hd];
        float ev1 = es[(size_t)s1 * HHEADS + hd];
        uint2 h0 = *(const uint2*)(hbase + (size_t)s0 * HF);
        uint2 h1 = *(const uint2*)(hbase + (size_t)s1 * HF);
        float v0 = ev0 + edv;
        v0 = v0 > 0.f ? v0 : 0.2f * v0;
        float v1 = ev1 + edv;
        v1 = v1 > 0.f ? v1 : 0.2f * v1;
        float w0 = __expf(v0 - m);
        float w1 = __expf(v1 - m);
        {
            f32x2 p0 = __builtin_amdgcn_cvt_pk_f32_fp8((int)h0.x, false);
            f32x2 p1 = __builtin_amdgcn_cvt_pk_f32_fp8((int)h0.x, true);
            f32x2 p2 = __builtin_amdgcn_cvt_pk_f32_fp8((int)h0.y, false);
            f32x2 p3 = __builtin_amdgcn_cvt_pk_f32_fp8((int)h0.y, true);
            l += w0;
            acc[0] += w0 * p0[0];
            acc[1] += w0 * p0[1];
            acc[2] += w0 * p1[0];
            acc[3] += w0 * p1[1];
            acc[4] += w0 * p2[0];
            acc[5] += w0 * p2[1];
            acc[6] += w0 * p3[0];
            acc[7] += w0 * p3[1];
        }
        {
            f32x2 p0 = __builtin_amdgcn_cvt_pk_f32_fp8((int)h1.x, false);
            f32x2 p1 = __builtin_amdgcn_cvt_pk_f32_fp8((int)h1.x, true);
            f32x2 p2 = __builtin_amdgcn_cvt_pk_f32_fp8((int)h1.y, false);
            f32x2 p3 = __builtin_amdgcn_cvt_pk_f32_fp8((int)h1.y, true);
            l += w1;
            acc[0] += w1 * p0[0];
            acc[1] += w1 * p0[1];
            acc[2] += w1 * p1[0];
            acc[3] += w1 * p1[1];
            acc[4] += w1 * p2[0];
            acc[5] += w1 * p2[1];
            acc[6] += w1 * p3[0];
            acc[7] += w1 * p3[1];
        }
    }
    if (j < b) {
        int s0 = ssrc[j];
        float ev0 = es[(size_t)s0 * HHEADS + hd];
        uint2 h0 = *(const uint2*)(hbase + (size_t)s0 * HF);
        float v0 = ev0 + edv;
        v0 = v0 > 0.f ? v0 : 0.2f * v0;
        float w0 = __expf(v0 - m);
        f32x2 p0 = __builtin_amdgcn_cvt_pk_f32_fp8((int)h0.x, false);
        f32x2 p1 = __builtin_amdgcn_cvt_pk_f32_fp8((int)h0.x, true);
        f32x2 p2 = __builtin_amdgcn_cvt_pk_f32_fp8((int)h0.y, false);
        f32x2 p3 = __builtin_amdgcn_cvt_pk_f32_fp8((int)h0.y, true);
        l += w0;
        acc[0] += w0 * p0[0];
        acc[1] += w0 * p0[1];
        acc[2] += w0 * p1[0];
        acc[3] += w0 * p1[1];
        acc[4] += w0 * p2[0];
        acc[5] += w0 * p2[1];
        acc[6] += w0 * p3[0];
        acc[7] += w0 * p3[1];
    }
    float invd = 1.0f / (l + 1e-16f);
    __hip_bfloat16 tb[8];
#pragma unroll
    for (int k = 0; k < 8; ++k) {
        float v = acc[k] * invd;
        v = v > 0.f ? v : (__expf(v) - 1.0f);  // elu
        tb[k] = __float2bfloat16(v);
    }
    *(uint4*)&outb[(size_t)node * HF + c] = *(uint4*)tb;
}

// ---------------- pooling (bf16 input) + head ----------------
__global__ void pool_kernel(const __hip_bfloat16* __restrict__ out3, float* __restrict__ g,
                            int n) {
    int b = blockIdx.x, t = threadIdx.x;  // blockDim = 192
    int chunk = (n + gridDim.x - 1) / gridDim.x;
    int n0 = b * chunk, n1 = min(n, n0 + chunk);
    float a0 = 0.f, a1 = 0.f;
    const unsigned* p = (const unsigned*)out3;
    for (int node = n0; node < n1; ++node) {
        unsigned u = p[(size_t)node * 192 + t];
        a0 += bfl(u);
        a1 += bfh(u);
    }
    atomicAdd(&g[2 * t], a0);
    atomicAdd(&g[2 * t + 1], a1);
}

__global__ void final_kernel(const float* __restrict__ g, const float* __restrict__ Wd,
                             const float* __restrict__ bd, float* __restrict__ outp) {
    __shared__ float red[384];
    int t = threadIdx.x;  // blockDim = 384
    float v = g[t];
    red[t] = v * v;
    __syncthreads();
    for (int s = 192; s >= 3; s >>= 1) {
        if (t < s) red[t] += red[t + s];
        __syncthreads();
    }
    __shared__ float scale_s;
    if (t == 0) {
        float norm = sqrtf(red[0] + red[1] + red[2]);
        scale_s = 1.0f / fmaxf(norm, 1e-12f);
    }
    __syncthreads();
    float scale = scale_s;
    red[t] = v * scale * Wd[t];
    __syncthreads();
    for (int s = 192; s >= 3; s >>= 1) {
        if (t < s) red[t] += red[t + s];
        __syncthreads();
    }
    if (t == 0) outp[0] = red[0] + red[1] + red[2] + bd[0];
}

// ---------------- host side ----------------
extern "C" void kernel_launch(void* const* d_in, const int* in_sizes, int n_in, void* d_out,
                              int out_size, void* d_ws, size_t ws_size, hipStream_t stream) {
    const float* x = (const float*)d_in[0];
    const int* ei = (const int*)d_in[1];
    const float* W1 = (const float*)d_in[2];
    const float* a1s = (const float*)d_in[3];
    const float* a1d = (const float*)d_in[4];
    const float* W2 = (const float*)d_in[5];
    const float* a2s = (const float*)d_in[6];
    const float* a2d = (const float*)d_in[7];
    const float* W3 = (const float*)d_in[8];
    const float* a3s = (const float*)d_in[9];
    const float* a3d = (const float*)d_in[10];
    const float* Wd = (const float*)d_in[11];
    const float* bd = (const float*)d_in[12];
    float* outp = (float*)d_out;

    const int N = in_sizes[0] / 11;
    const int E = in_sizes[1] / 2;
    const int* src = ei;
    const int* dst = ei + E;

    const int NT16 = ((N + 127) / 128) * 8;  // padded 16-row tiles

    char* w = (char*)d_ws;
    size_t off = 0;
    auto A = [&](size_t bytes) {
        size_t o = off;
        off += (bytes + 255) & ~(size_t)255;
        return o;
    };
    __hip_bfloat16* bufH = (__hip_bfloat16*)(w + A((size_t)N * 384 * 2));  // h (bf16 / fp8@L3)
    __hip_bfloat16* bufO = (__hip_bfloat16*)(w + A((size_t)N * 384 * 2));  // layer3 out (bf16)
    unsigned short* apH = (unsigned short*)(w + A((size_t)NT16 * 6 * 512 * 2));  // A-pack hi
    unsigned short* apL = (unsigned short*)(w + A((size_t)NT16 * 6 * 512 * 2));  // A-pack lo
    unsigned short* b2H = (unsigned short*)(w + A((size_t)16 * 3 * 512 * 2));    // W2 pack
    unsigned short* b2L = (unsigned short*)(w + A((size_t)16 * 3 * 512 * 2));
    unsigned short* b3H = (unsigned short*)(w + A((size_t)24 * 6 * 512 * 2));    // W3 pack
    unsigned short* b3L = (unsigned short*)(w + A((size_t)24 * 6 * 512 * 2));
    float* es = (float*)(w + A((size_t)N * HHEADS * 4));
    float* ed = (float*)(w + A((size_t)N * HHEADS * 4));
    unsigned* gmax = (unsigned*)(w + A(256));
    float* wp = (float*)(w + A((size_t)11 * 96 * 4));  // layer-1 f32 repack
    int* count = (int*)(w + A((size_t)(N + 1) * 4));
    int* cursor = (int*)(w + A((size_t)(N + 1) * 4));
    int* offsets = (int*)(w + A((size_t)(N + 1) * 4));
    int* bsum = (int*)(w + A(64 * 4));
    int* ssrc = (int*)(w + A((size_t)E * 4));
    float* g = (float*)(w + A(384 * 4));

    // one-shot zero of all small scratch (count, cursor, g, gmax, A-pack pads)
    const long t16v = N / 16;
    const long padT = NT16 - t16v;
    zero_misc<<<(N + 255) / 256, 256, 0, stream>>>(count, cursor, g, gmax, apH, apL,
                                                   t16v * 3 * 512, padT * 3 * 512,
                                                   t16v * 6 * 512, padT * 6 * 512, N);

    // CSR build (by dst)
    hist_kernel<<<(E + 255) / 256, 256, 0, stream>>>(dst, count, E);
    int nb = (N + 1023) / 1024;
    scan_block<<<nb, 1024, 0, stream>>>(count, offsets, bsum, N);
    scan_tops<<<1, 64, 0, stream>>>(bsum, nb);
    scan_add<<<nb, 1024, 0, stream>>>(offsets, bsum, N, E);
    scatter_kernel<<<(E + 255) / 256, 256, 0, stream>>>(src, dst, offsets, cursor, ssrc, E);

    // weight packs
    repack_w<<<(11 * 96 + 255) / 256, 256, 0, stream>>>(W1, wp, 11, 16);
    repack_w_mfma<<<(96 * 256 + 255) / 256, 256, 0, stream>>>(W2, b2H, b2L, 96, 32, 256);
    repack_w_mfma<<<(192 * 384 + 255) / 256, 256, 0, stream>>>(W3, b3H, b3L, 192, 64, 384);

    // ---- layer 1 (FIN=11, F=16): gemm + fused attn terms ----
    {
        dim3 grid((96 + 63) / 64, (N + 63) / 64);
        gemm_small_attn<64, 64, 32><<<grid, 256, 0, stream>>>(x, wp, bufH, a1s, a1d, es, ed, N,
                                                              11, 96);
    }
    {
        long total = (long)N * (96 / 8);
        aggregate_fused<16><<<(total + 255) / 256, 256, 0, stream>>>(bufH, es, ed, offsets,
                                                                     ssrc, apH, apL, N);
    }

    // ---- layer 2 (K=96, N=192 pad 256, F=32): bf16 C + fused gmax(6-11) ----
    {
        dim3 grid(256 / 128, (N + 127) / 128);
        gemm_attn_mfma<96, 192, 256, 32><<<grid, 256, 0, stream>>>(
            apH, apL, b2H, b2L, bufH, (unsigned char*)nullptr, a2s, a2d, es, ed, gmax, N);
    }
    {
        int grid = (N + 3) / 4;  // 4 waves/block, wave-per-node
        aggregate_wpn2<<<grid, 256, 0, stream>>>(bufH, es, ed, gmax, offsets, ssrc, apH, apL,
                                                 N);
    }

    // ---- layer 3 (K=192, N=384, F=64): fp8 C + fused gmax(0-5) ----
    {
        dim3 grid(384 / 128, (N + 127) / 128);
        gemm_attn_mfma<192, 384, 384, 64><<<grid, 256, 0, stream>>>(
            apH, apL, b3H, b3L, bufH, (unsigned char*)bufH, a3s, a3d, es, ed, gmax, N);
    }
    {
        int grid = (N + 3) / 4;
        aggregate_wpn3<<<grid, 256, 0, stream>>>((const unsigned char*)bufH, es, ed, gmax,
                                                 offsets, ssrc, bufO, N);
    }

    // sum-pool (bf16 in) -> normalize -> dense
    pool_kernel<<<256, 192, 0, stream>>>(bufO, g, N);
    final_kernel<<<1, 384, 0, stream>>>(g, Wd, bd, outp);
}

// Round 8
// 555.372 us; speedup vs baseline: 1.0428x; 1.0387x over previous
//
#include <hip/hip_runtime.h>
#include <hip/hip_bf16.h>

// GAT 3-layer: N=50000 nodes, E=800000 edges, H=6 heads.
// R1-R17: MFMA split-bf16 GEMMs + CSR fused softmax/aggregate ladder (545us).
// R20: L3 aggregate wave-per-node; aggregates pin at bytes-through-L2-miss.
// R21: L3 h -> fp8 e4m3 (4.4% per-elem error, absmax STILL 0) + L2 wpn agg.
// R22/R23: packed stores, global_load_lds: both NULL - GEMM not store/stage
//      bound. R24: 2-phase pipeline + XCD swizzle: FETCH 59->20MB (swizzle
//      works) but dur only 83->75.8us; block lifetime ~33us vs ~2k cycles of
//      MFMA - fixed per-block latency dominates at 2 blocks/CU.
// R25: drop split-bf16 (precision headroom proven by fp8 passing): plain
//      bf16xbf16 GEMM = 3x fewer MFMA, half the staging, LDS 64->32KB
//      (occupancy 2->3 blocks/CU), aggregates emit hi plane only, repacks
//      single-plane. Pipeline + swizzle kept.

#define HHEADS 6

typedef __attribute__((ext_vector_type(8))) short bf16x8;   // 8 bf16 = 4 VGPR
typedef __attribute__((ext_vector_type(4))) float f32x4;    // mfma C/D
typedef __attribute__((ext_vector_type(2))) float f32x2;

typedef __attribute__((address_space(3))) unsigned int lds_uint;
typedef const __attribute__((address_space(1))) unsigned int glb_uint;

__device__ __forceinline__ float bfl(unsigned u) { return __uint_as_float(u << 16); }
__device__ __forceinline__ float bfh(unsigned u) { return __uint_as_float(u & 0xffff0000u); }
__device__ __forceinline__ unsigned short f2bf(float v) {  // RNE f32->bf16
    unsigned u = __float_as_uint(v);
    return (unsigned short)((u + 0x7fffu + ((u >> 16) & 1u)) >> 16);
}
__device__ __forceinline__ float bf2f(unsigned short h) {
    return __uint_as_float((unsigned)h << 16);
}
// monotone float<->uint for atomicMax on floats (memset-0 = -inf identity)
__device__ __forceinline__ unsigned fkey(float f) {
    unsigned u = __float_as_uint(f);
    return (u >> 31) ? ~u : (u | 0x80000000u);
}
__device__ __forceinline__ float funkey(unsigned k) {
    return (k >> 31) ? __uint_as_float(k & 0x7fffffffu) : __uint_as_float(~k);
}

// 4x4 transpose across a 4-lane group (lanes share lane>>2). In: v0..v3 =
// rows 0..3 at this lane's column. Out: v0..v3 = cols 0..3 at row (lane&3).
__device__ __forceinline__ void xpose4(float& v0, float& v1, float& v2, float& v3, int b) {
    bool hi = (b & 2) != 0;
    float s0 = hi ? v0 : v2;
    float s1 = hi ? v1 : v3;
    s0 = __shfl_xor(s0, 2, 64);
    s1 = __shfl_xor(s1, 2, 64);
    v0 = hi ? s0 : v0;
    v1 = hi ? s1 : v1;
    v2 = hi ? v2 : s0;
    v3 = hi ? v3 : s1;
    bool od = (b & 1) != 0;
    float t0 = od ? v0 : v1;
    t0 = __shfl_xor(t0, 1, 64);
    v0 = od ? t0 : v0;
    v1 = od ? v1 : t0;
    float t1 = od ? v2 : v3;
    t1 = __shfl_xor(t1, 1, 64);
    v2 = od ? t1 : v2;
    v3 = od ? v3 : t1;
}

// ---------------- one-shot zero of all small scratch ----------------
__global__ void zero_misc(int* __restrict__ count, int* __restrict__ cursor,
                          float* __restrict__ g, unsigned* __restrict__ gmax,
                          unsigned short* __restrict__ apH,
                          long pad3_off, long pad3_cnt, long pad6_off, long pad6_cnt, int n) {
    long i = (long)blockIdx.x * blockDim.x + threadIdx.x;
    long stride = (long)gridDim.x * blockDim.x;
    for (long j = i; j < n; j += stride) {
        count[j] = 0;
        cursor[j] = 0;
    }
    if (i < 384) g[i] = 0.f;
    if (i < 12) gmax[i] = 0u;  // slots 0-5: L3, 6-11: L2
    for (long j = i; j < pad3_cnt; j += stride) apH[pad3_off + j] = 0;
    for (long j = i; j < pad6_cnt; j += stride) apH[pad6_off + j] = 0;
}

// ---------------- CSR build ----------------
__global__ void hist_kernel(const int* __restrict__ dst, int* __restrict__ count, int E) {
    int e = blockIdx.x * blockDim.x + threadIdx.x;
    if (e >= E) return;
    atomicAdd(&count[dst[e]], 1);
}

__global__ void scan_block(const int* __restrict__ count, int* __restrict__ offsets,
                           int* __restrict__ bsum, int n) {
    __shared__ int s[1024];
    int i = blockIdx.x * 1024 + threadIdx.x;
    int v = (i < n) ? count[i] : 0;
    s[threadIdx.x] = v;
    __syncthreads();
    for (int off = 1; off < 1024; off <<= 1) {
        int t = (threadIdx.x >= (unsigned)off) ? s[threadIdx.x - off] : 0;
        __syncthreads();
        s[threadIdx.x] += t;
        __syncthreads();
    }
    if (i < n) offsets[i] = s[threadIdx.x] - v;
    if (threadIdx.x == 1023) bsum[blockIdx.x] = s[1023];
}

__global__ void scan_tops(int* __restrict__ bsum, int nb) {
    __shared__ int s[64];
    int t = threadIdx.x;
    int v = (t < nb) ? bsum[t] : 0;
    s[t] = v;
    __syncthreads();
    for (int off = 1; off < 64; off <<= 1) {
        int tmp = (t >= off) ? s[t - off] : 0;
        __syncthreads();
        s[t] += tmp;
        __syncthreads();
    }
    if (t < nb) bsum[t] = s[t] - v;
}

__global__ void scan_add(int* __restrict__ offsets, const int* __restrict__ bsum, int n,
                         int total) {
    int i = blockIdx.x * 1024 + threadIdx.x;
    if (i < n) offsets[i] += bsum[blockIdx.x];
    if (i == 0) offsets[n] = total;
}

__global__ void scatter_kernel(const int* __restrict__ src, const int* __restrict__ dst,
                               const int* __restrict__ offsets, int* __restrict__ cursor,
                               int* __restrict__ ssrc, int E) {
    int e = blockIdx.x * blockDim.x + threadIdx.x;
    if (e >= E) return;
    int d = dst[e];
    int pos = offsets[d] + atomicAdd(&cursor[d], 1);
    ssrc[pos] = src[e];
}

// ---------------- weight repacks ----------------
__global__ void repack_w(const float* __restrict__ W, float* __restrict__ Wp, int FIN, int F) {
    int HF = HHEADS * F;
    int i = blockIdx.x * blockDim.x + threadIdx.x;
    if (i >= FIN * HF) return;
    int k = i / HF, c = i % HF;
    int hd = c / F, f = c % F;
    Wp[i] = W[(hd * FIN + k) * F + f];
}

// bf16 pack in MFMA B-fragment layout (B^T: lane n=..&15, k contiguous)
__global__ void repack_w_mfma(const float* __restrict__ W, unsigned short* __restrict__ bh,
                              int FIN, int F, int NPAD) {
    int i = blockIdx.x * blockDim.x + threadIdx.x;
    if (i >= FIN * NPAD) return;
    int k = i / NPAD, n = i % NPAD;
    int NKT = FIN / 32;
    int HF = HHEADS * F;
    float w = 0.f;
    if (n < HF) {
        int hd = n / F, f = n % F;
        w = W[(hd * FIN + k) * F + f];
    }
    size_t e = ((size_t)((n >> 4) * NKT + (k >> 5)) * 64 + ((n & 15) | (((k >> 3) & 3) << 4))) * 8 +
               (k & 7);
    bh[e] = f2bf(w);
}

// ---------------- small GEMM + fused attn (layer 1, K=11, F=16) ----------------
template <int BM, int BN, int BK>
__global__ __launch_bounds__(256) void gemm_small_attn(const float* __restrict__ A,
                                                       const float* __restrict__ B,
                                                       __hip_bfloat16* __restrict__ C,
                                                       const float* __restrict__ as_,
                                                       const float* __restrict__ ad_,
                                                       float* __restrict__ es,
                                                       float* __restrict__ ed, int M, int K,
                                                       int N) {
    __shared__ float As[BK][BM + 4];
    __shared__ float Bs[BK][BN];
    int tid = threadIdx.x;
    int tx = tid % 16, ty = tid / 16;
    int m0 = blockIdx.y * BM, n0 = blockIdx.x * BN;
    float acc[4][4] = {};
    for (int kk0 = 0; kk0 < K; kk0 += BK) {
#pragma unroll
        for (int i = 0; i < (BM * BK) / 256; ++i) {
            int idx = tid + i * 256;
            int m = idx / BK, k = idx % BK;
            float v = 0.f;
            if (m0 + m < M && kk0 + k < K) v = A[(size_t)(m0 + m) * K + kk0 + k];
            As[k][m] = v;
        }
#pragma unroll
        for (int i = 0; i < (BK * BN) / 1024; ++i) {
            int idx = tid + i * 256;
            int k = idx / (BN / 4), n4 = idx % (BN / 4);
            float4 v = make_float4(0.f, 0.f, 0.f, 0.f);
            if (kk0 + k < K && n0 + n4 * 4 < N)
                v = *(const float4*)&B[(size_t)(kk0 + k) * N + n0 + n4 * 4];
            *(float4*)&Bs[k][n4 * 4] = v;
        }
        __syncthreads();
#pragma unroll
        for (int k = 0; k < BK; ++k) {
            float4 av = *(const float4*)&As[k][ty * 4];
            float4 bv = *(const float4*)&Bs[k][tx * 4];
            float a[4] = {av.x, av.y, av.z, av.w};
            float b[4] = {bv.x, bv.y, bv.z, bv.w};
#pragma unroll
            for (int i = 0; i < 4; ++i)
#pragma unroll
                for (int j = 0; j < 4; ++j) acc[i][j] += a[i] * b[j];
        }
        __syncthreads();
    }
    bool colok = (n0 + tx * 4) < N;
    float asv[4], adv[4];
#pragma unroll
    for (int j = 0; j < 4; ++j) {
        int col = n0 + tx * 4 + j;
        asv[j] = (col < N) ? as_[col] : 0.f;
        adv[j] = (col < N) ? ad_[col] : 0.f;
    }
#pragma unroll
    for (int i = 0; i < 4; ++i) {
        int m = m0 + ty * 4 + i;
        bool mok = m < M;
        if (mok && colok) {
            __hip_bfloat16 tmp[4];
#pragma unroll
            for (int j = 0; j < 4; ++j) tmp[j] = __float2bfloat16(acc[i][j]);
            *(uint2*)&C[(size_t)m * N + n0 + tx * 4] = *(uint2*)tmp;
        }
        float ps = 0.f, pd = 0.f;
#pragma unroll
        for (int j = 0; j < 4; ++j) {
            ps += acc[i][j] * asv[j];
            pd += acc[i][j] * adv[j];
        }
        ps += __shfl_down(ps, 2, 4);
        ps += __shfl_down(ps, 1, 4);
        pd += __shfl_down(pd, 2, 4);
        pd += __shfl_down(pd, 1, 4);
        if (mok && colok && (tx & 3) == 0) {
            int hd = (n0 + tx * 4) >> 4;  // F=16
            es[(size_t)m * HHEADS + hd] = ps;
            ed[(size_t)m * HHEADS + hd] = pd;
        }
    }
}

// ---------------- MFMA bf16 GEMM + fused attn (layers 2/3) ----------------
// Plain bf16 (R25; split-bf16 dropped - fp8-passing headroom). 2-phase
// pipeline, double LDS buffers, counted waits, XCD-bijective swizzle.
// F==64: C fp8 e4m3; gmax slots 0-5. F==32: C bf16; gmax slots 6-11.
template <int K, int NREAL, int NPAD, int F>
__global__ __launch_bounds__(256) void gemm_attn_mfma(
    const unsigned short* __restrict__ Ah, const unsigned short* __restrict__ Bh,
    __hip_bfloat16* __restrict__ C, unsigned char* __restrict__ C8,
    const float* __restrict__ as_, const float* __restrict__ ad_, float* __restrict__ es,
    float* __restrict__ ed, unsigned* __restrict__ gmax, int M) {
    constexpr int NKT = K / 32;
    __shared__ unsigned short sAh[2][4096], sBh[2][4096];
    int tid = threadIdx.x;
    int lane = tid & 63, wave = tid >> 6;
    int wrow = wave >> 1, wcol = wave & 1;
    int quad = lane >> 4, c16 = lane & 15;

    // XCD-bijective swizzle (m204): co-locate the x-siblings sharing A-tiles.
    int nwg = gridDim.x * gridDim.y;
    int h = blockIdx.y * gridDim.x + blockIdx.x;
    int q = nwg >> 3, r = nwg & 7;
    int xcd = h & 7, pos = h >> 3;
    int wk = (xcd < r ? xcd * (q + 1) : r * (q + 1) + (xcd - r) * q) + pos;
    int bx = wk % gridDim.x, by = wk / gridDim.x;

    int m0 = by * 128, n0 = bx * 128;
    int bt16 = m0 >> 4, bn16 = n0 >> 4;

    auto STAGE = [&](int kt, int buf) {
#pragma unroll
        for (int rep = 0; rep < 2; ++rep) {
            int chunk = tid + rep * 256;
            int tile = chunk >> 6, e8 = chunk & 63;
            size_t aoff = ((size_t)((bt16 + tile) * NKT + kt) * 64 + e8) * 8;
            size_t boff = ((size_t)((bn16 + tile) * NKT + kt) * 64 + e8) * 8;
            __builtin_amdgcn_global_load_lds((glb_uint*)&Ah[aoff],
                                             (lds_uint*)&sAh[buf][chunk * 8], 16, 0, 0);
            __builtin_amdgcn_global_load_lds((glb_uint*)&Bh[boff],
                                             (lds_uint*)&sBh[buf][chunk * 8], 16, 0, 0);
        }
    };

    f32x4 acc[4][4] = {};
    STAGE(0, 0);
    asm volatile("s_waitcnt vmcnt(0)" ::: "memory");
    __builtin_amdgcn_s_barrier();

#pragma unroll
    for (int kt = 0; kt < NKT; ++kt) {
        int cur = kt & 1;
        if (kt + 1 < NKT) STAGE(kt + 1, cur ^ 1);  // issue-early
        bf16x8 fah[4], fbh[4];
#pragma unroll
        for (int i = 0; i < 4; ++i) {
            fah[i] = *(const bf16x8*)&sAh[cur][(wrow * 4 + i) * 512 + lane * 8];
            fbh[i] = *(const bf16x8*)&sBh[cur][(wcol * 4 + i) * 512 + lane * 8];
        }
        asm volatile("s_waitcnt lgkmcnt(0)" ::: "memory");
        __builtin_amdgcn_sched_barrier(0);  // rule #18
#pragma unroll
        for (int i = 0; i < 4; ++i)
#pragma unroll
            for (int j = 0; j < 4; ++j)
                acc[i][j] = __builtin_amdgcn_mfma_f32_16x16x32_bf16(fah[i], fbh[j], acc[i][j],
                                                                    0, 0, 0);
        asm volatile("s_waitcnt vmcnt(0)" ::: "memory");
        __builtin_amdgcn_s_barrier();
    }

    float asv[4], adv[4];
#pragma unroll
    for (int j = 0; j < 4; ++j) {
        int col = n0 + wcol * 64 + j * 16 + c16;
        bool ok = col < NREAL;
        asv[j] = ok ? as_[col] : 0.f;
        adv[j] = ok ? ad_[col] : 0.f;
    }
    float mx = -1e30f;                 // F==64 per-wave head max
    float mxA = -1e30f, mxB = -1e30f;  // F==32 per-wave 2-head max
    bool colvalid = (n0 + wcol * 64) < NREAL;

    // ---- es/ed + gmax (fragment layout; no C writes here) ----
#pragma unroll
    for (int i = 0; i < 4; ++i) {
#pragma unroll
        for (int r2 = 0; r2 < 4; ++r2) {
            int m = m0 + wrow * 64 + i * 16 + quad * 4 + r2;
            bool mok = m < M;
            if (F == 64) {
                float ps = acc[i][0][r2] * asv[0] + acc[i][1][r2] * asv[1] +
                           acc[i][2][r2] * asv[2] + acc[i][3][r2] * asv[3];
                float pd = acc[i][0][r2] * adv[0] + acc[i][1][r2] * adv[1] +
                           acc[i][2][r2] * adv[2] + acc[i][3][r2] * adv[3];
#pragma unroll
                for (int off = 8; off > 0; off >>= 1) {
                    ps += __shfl_down(ps, off, 16);
                    pd += __shfl_down(pd, off, 16);
                }
                if (mok && c16 == 0) {
                    int hd = (n0 + wcol * 64) / 64;
                    es[(size_t)m * HHEADS + hd] = ps;
                    ed[(size_t)m * HHEADS + hd] = pd;
                    mx = fmaxf(mx, ps);
                }
            } else {  // F == 32: two heads per wave-column
                float psA = acc[i][0][r2] * asv[0] + acc[i][1][r2] * asv[1];
                float pdA = acc[i][0][r2] * adv[0] + acc[i][1][r2] * adv[1];
                float psB = acc[i][2][r2] * asv[2] + acc[i][3][r2] * asv[3];
                float pdB = acc[i][2][r2] * adv[2] + acc[i][3][r2] * adv[3];
#pragma unroll
                for (int off = 8; off > 0; off >>= 1) {
                    psA += __shfl_down(psA, off, 16);
                    pdA += __shfl_down(pdA, off, 16);
                    psB += __shfl_down(psB, off, 16);
                    pdB += __shfl_down(pdB, off, 16);
                }
                if (mok && c16 == 0 && colvalid) {
                    int colbase = n0 + wcol * 64;
                    int hd = colbase / 32;
                    es[(size_t)m * HHEADS + hd] = psA;
                    ed[(size_t)m * HHEADS + hd] = pdA;
                    es[(size_t)m * HHEADS + hd + 1] = psB;
                    ed[(size_t)m * HHEADS + hd + 1] = pdB;
                    mxA = fmaxf(mxA, psA);
                    mxB = fmaxf(mxB, psB);
                }
            }
        }
    }
    if (F == 64) {
#pragma unroll
        for (int off = 32; off > 0; off >>= 1) mx = fmaxf(mx, __shfl_xor(mx, off));
        if (lane == 0) atomicMax(&gmax[(n0 + wcol * 64) / 64], fkey(mx));
    } else {
        mxA = fmaxf(mxA, __shfl_xor(mxA, 16));
        mxA = fmaxf(mxA, __shfl_xor(mxA, 32));
        mxB = fmaxf(mxB, __shfl_xor(mxB, 16));
        mxB = fmaxf(mxB, __shfl_xor(mxB, 32));
        if (lane == 0 && colvalid) {
            int hd = (n0 + wcol * 64) / 32;
            atomicMax(&gmax[6 + hd], fkey(mxA));
            atomicMax(&gmax[6 + hd + 1], fkey(mxB));
        }
    }

    // ---- C store: transpose each 16x16 block, packed wide stores ----
    int b4 = lane & 3;
#pragma unroll
    for (int i = 0; i < 4; ++i) {
        int m = m0 + wrow * 64 + i * 16 + quad * 4 + b4;
        bool mok = m < M;
#pragma unroll
        for (int j = 0; j < 4; ++j) {
            float v0 = acc[i][j][0], v1 = acc[i][j][1], v2 = acc[i][j][2], v3 = acc[i][j][3];
            xpose4(v0, v1, v2, v3, b4);
            int colb = n0 + wcol * 64 + j * 16 + (c16 & 12);
            if (F == 64) {
                if (mok) {
                    int pk = __builtin_amdgcn_cvt_pk_fp8_f32(v0, v1, 0, false);
                    pk = __builtin_amdgcn_cvt_pk_fp8_f32(v2, v3, pk, true);
                    *(unsigned*)&C8[(size_t)m * NREAL + colb] = (unsigned)pk;
                }
            } else {
                if (mok && colvalid) {
                    unsigned lo = (unsigned)f2bf(v0) | ((unsigned)f2bf(v1) << 16);
                    unsigned hi = (unsigned)f2bf(v2) | ((unsigned)f2bf(v3) << 16);
                    uint2 pk2;
                    pk2.x = lo;
                    pk2.y = hi;
                    *(uint2*)&C[(size_t)m * NREAL + colb] = pk2;
                }
            }
        }
    }
}

// ---------------- online-rescale softmax-aggregate (layer 1) ----------------
// Thread per (node, 8ch); emits bf16 MFMA A-operand plane (hi only).
template <int F>
__global__ __launch_bounds__(256) void aggregate_fused(
    const __hip_bfloat16* __restrict__ h, const float* __restrict__ es,
    const float* __restrict__ ed, const int* __restrict__ offsets,
    const int* __restrict__ ssrc, unsigned short* __restrict__ oh, int n) {
    constexpr int HF = HHEADS * F;
    constexpr int C8 = HF / 8;
    int tid = blockIdx.x * blockDim.x + threadIdx.x;
    if (tid >= n * C8) return;
    int node = tid / C8, q = tid % C8;
    int c = q * 8, hd = c / F;
    int a = offsets[node], b = offsets[node + 1];
    float edv = ed[node * HHEADS + hd];
    float m = -1e30f, l = 0.f;
    float acc[8] = {};
    for (int j = a; j < b; ++j) {
        int s = ssrc[j];
        float v = es[s * HHEADS + hd] + edv;
        v = v > 0.f ? v : 0.2f * v;  // leaky relu 0.2
        float mn = fmaxf(m, v);
        float r = __expf(m - mn);
        float wgt = __expf(v - mn);
        uint4 hv = *(const uint4*)&h[(size_t)s * HF + c];
        l = l * r + wgt;
        acc[0] = acc[0] * r + wgt * bfl(hv.x);
        acc[1] = acc[1] * r + wgt * bfh(hv.x);
        acc[2] = acc[2] * r + wgt * bfl(hv.y);
        acc[3] = acc[3] * r + wgt * bfh(hv.y);
        acc[4] = acc[4] * r + wgt * bfl(hv.z);
        acc[5] = acc[5] * r + wgt * bfh(hv.z);
        acc[6] = acc[6] * r + wgt * bfl(hv.w);
        acc[7] = acc[7] * r + wgt * bfh(hv.w);
        m = mn;
    }
    float invd = 1.0f / (l + 1e-16f);
    unsigned short th[8];
#pragma unroll
    for (int k = 0; k < 8; ++k) {
        float v = acc[k] * invd;
        v = v > 0.f ? v : (__expf(v) - 1.0f);  // elu
        th[k] = f2bf(v);
    }
    constexpr int NKT = HF / 32;
    int lq = (node & 15) | (((c >> 3) & 3) << 4);
    size_t base = ((size_t)((node >> 4) * NKT + (c >> 5)) * 64 + lq) * 8;
    *(uint4*)&oh[base] = *(uint4*)th;
}

// ---------------- wave-per-node single-pass aggregate (layer 2) ----------------
__global__ __launch_bounds__(256) void aggregate_wpn2(
    const __hip_bfloat16* __restrict__ h, const float* __restrict__ es,
    const float* __restrict__ ed, const unsigned* __restrict__ gmax,
    const int* __restrict__ offsets, const int* __restrict__ ssrc,
    unsigned short* __restrict__ oh, int n) {
    constexpr int HF = 192;
    int wid = (int)((blockIdx.x * (unsigned)blockDim.x + threadIdx.x) >> 6);
    int lane = threadIdx.x & 63;
    if (wid >= n || lane >= 48) return;
    int node = wid;
    int hd = lane >> 3;  // F=32: 8 lanes (32ch) per head
    int c = lane * 4;
    int a = offsets[node], b = offsets[node + 1];
    float edv = ed[node * HHEADS + hd];
    float mv = funkey(gmax[6 + hd]) + edv;
    float m = mv > 0.f ? mv : 0.2f * mv;
    float l = 0.f;
    float acc[4] = {};
    const unsigned short* hbase = (const unsigned short*)h + c;
    int j = a;
    for (; j + 1 < b; j += 2) {
        int s0 = ssrc[j], s1 = ssrc[j + 1];
        float ev0 = es[(size_t)s0 * HHEADS + hd];
        float ev1 = es[(size_t)s1 * HHEADS + hd];
        uint2 h0 = *(const uint2*)(hbase + (size_t)s0 * HF);
        uint2 h1 = *(const uint2*)(hbase + (size_t)s1 * HF);
        float v0 = ev0 + edv;
        v0 = v0 > 0.f ? v0 : 0.2f * v0;
        float v1 = ev1 + edv;
        v1 = v1 > 0.f ? v1 : 0.2f * v1;
        float w0 = __expf(v0 - m);
        float w1 = __expf(v1 - m);
        l += w0;
        acc[0] += w0 * bfl(h0.x);
        acc[1] += w0 * bfh(h0.x);
        acc[2] += w0 * bfl(h0.y);
        acc[3] += w0 * bfh(h0.y);
        l += w1;
        acc[0] += w1 * bfl(h1.x);
        acc[1] += w1 * bfh(h1.x);
        acc[2] += w1 * bfl(h1.y);
        acc[3] += w1 * bfh(h1.y);
    }
    if (j < b) {
        int s0 = ssrc[j];
        float ev0 = es[(size_t)s0 * HHEADS + hd];
        uint2 h0 = *(const uint2*)(hbase + (size_t)s0 * HF);
        float v0 = ev0 + edv;
        v0 = v0 > 0.f ? v0 : 0.2f * v0;
        float w0 = __expf(v0 - m);
        l += w0;
        acc[0] += w0 * bfl(h0.x);
        acc[1] += w0 * bfh(h0.x);
        acc[2] += w0 * bfl(h0.y);
        acc[3] += w0 * bfh(h0.y);
    }
    float invd = 1.0f / (l + 1e-16f);
    unsigned short th[4];
#pragma unroll
    for (int k = 0; k < 4; ++k) {
        float v = acc[k] * invd;
        v = v > 0.f ? v : (__expf(v) - 1.0f);  // elu
        th[k] = f2bf(v);
    }
    int lq = (node & 15) | (((c >> 3) & 3) << 4);
    size_t base = ((size_t)((node >> 4) * (HF / 32) + (c >> 5)) * 64 + lq) * 8 + (c & 7);
    *(uint2*)&oh[base] = *(uint2*)th;
}

// ---------------- wave-per-node single-pass aggregate (layer 3, fp8 h) --------
__global__ __launch_bounds__(256) void aggregate_wpn3(
    const unsigned char* __restrict__ h8, const float* __restrict__ es,
    const float* __restrict__ ed, const unsigned* __restrict__ gmax,
    const int* __restrict__ offsets, const int* __restrict__ ssrc,
    __hip_bfloat16* __restrict__ outb, int n) {
    constexpr int HF = 384;
    int wid = (int)((blockIdx.x * (unsigned)blockDim.x + threadIdx.x) >> 6);
    int lane = threadIdx.x & 63;
    if (wid >= n || lane >= 48) return;
    int node = wid;
    int hd = lane >> 3;  // 8 lanes (64ch) per head
    int c = lane * 8;
    int a = offsets[node], b = offsets[node + 1];
    float edv = ed[node * HHEADS + hd];
    float mv = funkey(gmax[hd]) + edv;
    float m = mv > 0.f ? mv : 0.2f * mv;
    float l = 0.f;
    float acc[8] = {};
    const unsigned char* hbase = h8 + c;
    int j = a;
    for (; j + 1 < b; j += 2) {
        int s0 = ssrc[j], s1 = ssrc[j + 1];
        float ev0 = es[(size_t)s0 * HHEADS + hd];
        float ev1 = es[(size_t)s1 * HHEADS + hd];
        uint2 h0 = *(const uint2*)(hbase + (size_t)s0 * HF);
        uint2 h1 = *(const uint2*)(hbase + (size_t)s1 * HF);
        float v0 = ev0 + edv;
        v0 = v0 > 0.f ? v0 : 0.2f * v0;
        float v1 = ev1 + edv;
        v1 = v1 > 0.f ? v1 : 0.2f * v1;
        float w0 = __expf(v0 - m);
        float w1 = __expf(v1 - m);
        {
            f32x2 p0 = __builtin_amdgcn_cvt_pk_f32_fp8((int)h0.x, false);
            f32x2 p1 = __builtin_amdgcn_cvt_pk_f32_fp8((int)h0.x, true);
            f32x2 p2 = __builtin_amdgcn_cvt_pk_f32_fp8((int)h0.y, false);
            f32x2 p3 = __builtin_amdgcn_cvt_pk_f32_fp8((int)h0.y, true);
            l += w0;
            acc[0] += w0 * p0[0];
            acc[1] += w0 * p0[1];
            acc[2] += w0 * p1[0];
            acc[3] += w0 * p1[1];
            acc[4] += w0 * p2[0];
            acc[5] += w0 * p2[1];
            acc[6] += w0 * p3[0];
            acc[7] += w0 * p3[1];
        }
        {
            f32x2 p0 = __builtin_amdgcn_cvt_pk_f32_fp8((int)h1.x, false);
            f32x2 p1 = __builtin_amdgcn_cvt_pk_f32_fp8((int)h1.x, true);
            f32x2 p2 = __builtin_amdgcn_cvt_pk_f32_fp8((int)h1.y, false);
            f32x2 p3 = __builtin_amdgcn_cvt_pk_f32_fp8((int)h1.y, true);
            l += w1;
            acc[0] += w1 * p0[0];
            acc[1] += w1 * p0[1];
            acc[2] += w1 * p1[0];
            acc[3] += w1 * p1[1];
            acc[4] += w1 * p2[0];
            acc[5] += w1 * p2[1];
            acc[6] += w1 * p3[0];
            acc[7] += w1 * p3[1];
        }
    }
    if (j < b) {
        int s0 = ssrc[j];
        float ev0 = es[(size_t)s0 * HHEADS + hd];
        uint2 h0 = *(const uint2*)(hbase + (size_t)s0 * HF);
        float v0 = ev0 + edv;
        v0 = v0 > 0.f ? v0 : 0.2f * v0;
        float w0 = __expf(v0 - m);
        f32x2 p0 = __builtin_amdgcn_cvt_pk_f32_fp8((int)h0.x, false);
        f32x2 p1 = __builtin_amdgcn_cvt_pk_f32_fp8((int)h0.x, true);
        f32x2 p2 = __builtin_amdgcn_cvt_pk_f32_fp8((int)h0.y, false);
        f32x2 p3 = __builtin_amdgcn_cvt_pk_f32_fp8((int)h0.y, true);
        l += w0;
        acc[0] += w0 * p0[0];
        acc[1] += w0 * p0[1];
        acc[2] += w0 * p1[0];
        acc[3] += w0 * p1[1];
        acc[4] += w0 * p2[0];
        acc[5] += w0 * p2[1];
        acc[6] += w0 * p3[0];
        acc[7] += w0 * p3[1];
    }
    float invd = 1.0f / (l + 1e-16f);
    __hip_bfloat16 tb[8];
#pragma unroll
    for (int k = 0; k < 8; ++k) {
        float v = acc[k] * invd;
        v = v > 0.f ? v : (__expf(v) - 1.0f);  // elu
        tb[k] = __float2bfloat16(v);
    }
    *(uint4*)&outb[(size_t)node * HF + c] = *(uint4*)tb;
}

// ---------------- pooling (bf16 input) + head ----------------
__global__ void pool_kernel(const __hip_bfloat16* __restrict__ out3, float* __restrict__ g,
                            int n) {
    int b = blockIdx.x, t = threadIdx.x;  // blockDim = 192
    int chunk = (n + gridDim.x - 1) / gridDim.x;
    int n0 = b * chunk, n1 = min(n, n0 + chunk);
    float a0 = 0.f, a1 = 0.f;
    const unsigned* p = (const unsigned*)out3;
    for (int node = n0; node < n1; ++node) {
        unsigned u = p[(size_t)node * 192 + t];
        a0 += bfl(u);
        a1 += bfh(u);
    }
    atomicAdd(&g[2 * t], a0);
    atomicAdd(&g[2 * t + 1], a1);
}

__global__ void final_kernel(const float* __restrict__ g, const float* __restrict__ Wd,
                             const float* __restrict__ bd, float* __restrict__ outp) {
    __shared__ float red[384];
    int t = threadIdx.x;  // blockDim = 384
    float v = g[t];
    red[t] = v * v;
    __syncthreads();
    for (int s = 192; s >= 3; s >>= 1) {
        if (t < s) red[t] += red[t + s];
        __syncthreads();
    }
    __shared__ float scale_s;
    if (t == 0) {
        float norm = sqrtf(red[0] + red[1] + red[2]);
        scale_s = 1.0f / fmaxf(norm, 1e-12f);
    }
    __syncthreads();
    float scale = scale_s;
    red[t] = v * scale * Wd[t];
    __syncthreads();
    for (int s = 192; s >= 3; s >>= 1) {
        if (t < s) red[t] += red[t + s];
        __syncthreads();
    }
    if (t == 0) outp[0] = red[0] + red[1] + red[2] + bd[0];
}

// ---------------- host side ----------------
extern "C" void kernel_launch(void* const* d_in, const int* in_sizes, int n_in, void* d_out,
                              int out_size, void* d_ws, size_t ws_size, hipStream_t stream) {
    const float* x = (const float*)d_in[0];
    const int* ei = (const int*)d_in[1];
    const float* W1 = (const float*)d_in[2];
    const float* a1s = (const float*)d_in[3];
    const float* a1d = (const float*)d_in[4];
    const float* W2 = (const float*)d_in[5];
    const float* a2s = (const float*)d_in[6];
    const float* a2d = (const float*)d_in[7];
    const float* W3 = (const float*)d_in[8];
    const float* a3s = (const float*)d_in[9];
    const float* a3d = (const float*)d_in[10];
    const float* Wd = (const float*)d_in[11];
    const float* bd = (const float*)d_in[12];
    float* outp = (float*)d_out;

    const int N = in_sizes[0] / 11;
    const int E = in_sizes[1] / 2;
    const int* src = ei;
    const int* dst = ei + E;

    const int NT16 = ((N + 127) / 128) * 8;  // padded 16-row tiles

    char* w = (char*)d_ws;
    size_t off = 0;
    auto A = [&](size_t bytes) {
        size_t o = off;
        off += (bytes + 255) & ~(size_t)255;
        return o;
    };
    __hip_bfloat16* bufH = (__hip_bfloat16*)(w + A((size_t)N * 384 * 2));  // h (bf16 / fp8@L3)
    __hip_bfloat16* bufO = (__hip_bfloat16*)(w + A((size_t)N * 384 * 2));  // layer3 out (bf16)
    unsigned short* apH = (unsigned short*)(w + A((size_t)NT16 * 6 * 512 * 2));  // A-pack
    unsigned short* b2H = (unsigned short*)(w + A((size_t)16 * 3 * 512 * 2));    // W2 pack
    unsigned short* b3H = (unsigned short*)(w + A((size_t)24 * 6 * 512 * 2));    // W3 pack
    float* es = (float*)(w + A((size_t)N * HHEADS * 4));
    float* ed = (float*)(w + A((size_t)N * HHEADS * 4));
    unsigned* gmax = (unsigned*)(w + A(256));
    float* wp = (float*)(w + A((size_t)11 * 96 * 4));  // layer-1 f32 repack
    int* count = (int*)(w + A((size_t)(N + 1) * 4));
    int* cursor = (int*)(w + A((size_t)(N + 1) * 4));
    int* offsets = (int*)(w + A((size_t)(N + 1) * 4));
    int* bsum = (int*)(w + A(64 * 4));
    int* ssrc = (int*)(w + A((size_t)E * 4));
    float* g = (float*)(w + A(384 * 4));

    // one-shot zero of all small scratch (count, cursor, g, gmax, A-pack pads)
    const long t16v = N / 16;
    const long padT = NT16 - t16v;
    zero_misc<<<(N + 255) / 256, 256, 0, stream>>>(count, cursor, g, gmax, apH,
                                                   t16v * 3 * 512, padT * 3 * 512,
                                                   t16v * 6 * 512, padT * 6 * 512, N);

    // CSR build (by dst)
    hist_kernel<<<(E + 255) / 256, 256, 0, stream>>>(dst, count, E);
    int nb = (N + 1023) / 1024;
    scan_block<<<nb, 1024, 0, stream>>>(count, offsets, bsum, N);
    scan_tops<<<1, 64, 0, stream>>>(bsum, nb);
    scan_add<<<nb, 1024, 0, stream>>>(offsets, bsum, N, E);
    scatter_kernel<<<(E + 255) / 256, 256, 0, stream>>>(src, dst, offsets, cursor, ssrc, E);

    // weight packs
    repack_w<<<(11 * 96 + 255) / 256, 256, 0, stream>>>(W1, wp, 11, 16);
    repack_w_mfma<<<(96 * 256 + 255) / 256, 256, 0, stream>>>(W2, b2H, 96, 32, 256);
    repack_w_mfma<<<(192 * 384 + 255) / 256, 256, 0, stream>>>(W3, b3H, 192, 64, 384);

    // ---- layer 1 (FIN=11, F=16): gemm + fused attn terms ----
    {
        dim3 grid((96 + 63) / 64, (N + 63) / 64);
        gemm_small_attn<64, 64, 32><<<grid, 256, 0, stream>>>(x, wp, bufH, a1s, a1d, es, ed, N,
                                                              11, 96);
    }
    {
        long total = (long)N * (96 / 8);
        aggregate_fused<16><<<(total + 255) / 256, 256, 0, stream>>>(bufH, es, ed, offsets,
                                                                     ssrc, apH, N);
    }

    // ---- layer 2 (K=96, N=192 pad 256, F=32): bf16 C + fused gmax(6-11) ----
    {
        dim3 grid(256 / 128, (N + 127) / 128);
        gemm_attn_mfma<96, 192, 256, 32><<<grid, 256, 0, stream>>>(
            apH, b2H, bufH, (unsigned char*)nullptr, a2s, a2d, es, ed, gmax, N);
    }
    {
        int grid = (N + 3) / 4;  // 4 waves/block, wave-per-node
        aggregate_wpn2<<<grid, 256, 0, stream>>>(bufH, es, ed, gmax, offsets, ssrc, apH, N);
    }

    // ---- layer 3 (K=192, N=384, F=64): fp8 C + fused gmax(0-5) ----
    {
        dim3 grid(384 / 128, (N + 127) / 128);
        gemm_attn_mfma<192, 384, 384, 64><<<grid, 256, 0, stream>>>(
            apH, b3H, bufH, (unsigned char*)bufH, a3s, a3d, es, ed, gmax, N);
    }
    {
        int grid = (N + 3) / 4;
        aggregate_wpn3<<<grid, 256, 0, stream>>>((const unsigned char*)bufH, es, ed, gmax,
                                                 offsets, ssrc, bufO, N);
    }

    // sum-pool (bf16 in) -> normalize -> dense
    pool_kernel<<<256, 192, 0, stream>>>(bufO, g, N);
    final_kernel<<<1, 384, 0, stream>>>(g, Wd, bd, outp);
}

// Round 9
// 526.720 us; speedup vs baseline: 1.0995x; 1.0544x over previous
//
#include <hip/hip_runtime.h>
#include <hip/hip_bf16.h>

// GAT 3-layer: N=50000 nodes, E=800000 edges, H=6 heads.
// R1-R17: MFMA split-bf16 GEMMs + CSR fused softmax/aggregate ladder (545us).
// R20: L3 aggregate wave-per-node; aggregates pin at bytes-through-L2-miss.
// R21: L3 h -> fp8 e4m3 (absmax 0) + L2 wpn agg.
// R22-R25 GEMM ladder: packed stores NULL, global_load_lds NULL, 2-phase
//      pipeline+XCD swizzle (FETCH 59->20MB, dur -7us), drop split-bf16
//      (3x fewer MFMA, dur only -5us, MfmaUtil 11->3.8%). CONCLUSION: GEMM
//      duration is invariant under compute/staging/store/fetch changes with
//      all pipes idle -> per-BLOCK fixed overhead (~20x useful work)
//      dominates at 1173 tiny blocks.
// R26: amortize it. Each GEMM block = MT=4 consecutive 128-row M-tiles at one
//      bx: B-panel (all NKT tiles) staged to LDS ONCE, reused; A double-
//      buffered, issue-early; per-M-tile epilogue overlapped with next A
//      stage. Blocks: L3 1173->294, L2 782->196. Numerics identical to R25.

#define HHEADS 6

typedef __attribute__((ext_vector_type(8))) short bf16x8;   // 8 bf16 = 4 VGPR
typedef __attribute__((ext_vector_type(4))) float f32x4;    // mfma C/D
typedef __attribute__((ext_vector_type(2))) float f32x2;

typedef __attribute__((address_space(3))) unsigned int lds_uint;
typedef const __attribute__((address_space(1))) unsigned int glb_uint;

__device__ __forceinline__ float bfl(unsigned u) { return __uint_as_float(u << 16); }
__device__ __forceinline__ float bfh(unsigned u) { return __uint_as_float(u & 0xffff0000u); }
__device__ __forceinline__ unsigned short f2bf(float v) {  // RNE f32->bf16
    unsigned u = __float_as_uint(v);
    return (unsigned short)((u + 0x7fffu + ((u >> 16) & 1u)) >> 16);
}
__device__ __forceinline__ float bf2f(unsigned short h) {
    return __uint_as_float((unsigned)h << 16);
}
// monotone float<->uint for atomicMax on floats (memset-0 = -inf identity)
__device__ __forceinline__ unsigned fkey(float f) {
    unsigned u = __float_as_uint(f);
    return (u >> 31) ? ~u : (u | 0x80000000u);
}
__device__ __forceinline__ float funkey(unsigned k) {
    return (k >> 31) ? __uint_as_float(k & 0x7fffffffu) : __uint_as_float(~k);
}

// 4x4 transpose across a 4-lane group (lanes share lane>>2). In: v0..v3 =
// rows 0..3 at this lane's column. Out: v0..v3 = cols 0..3 at row (lane&3).
__device__ __forceinline__ void xpose4(float& v0, float& v1, float& v2, float& v3, int b) {
    bool hi = (b & 2) != 0;
    float s0 = hi ? v0 : v2;
    float s1 = hi ? v1 : v3;
    s0 = __shfl_xor(s0, 2, 64);
    s1 = __shfl_xor(s1, 2, 64);
    v0 = hi ? s0 : v0;
    v1 = hi ? s1 : v1;
    v2 = hi ? v2 : s0;
    v3 = hi ? v3 : s1;
    bool od = (b & 1) != 0;
    float t0 = od ? v0 : v1;
    t0 = __shfl_xor(t0, 1, 64);
    v0 = od ? t0 : v0;
    v1 = od ? v1 : t0;
    float t1 = od ? v2 : v3;
    t1 = __shfl_xor(t1, 1, 64);
    v2 = od ? t1 : v2;
    v3 = od ? v3 : t1;
}

// ---------------- one-shot zero of all small scratch ----------------
__global__ void zero_misc(int* __restrict__ count, int* __restrict__ cursor,
                          float* __restrict__ g, unsigned* __restrict__ gmax,
                          unsigned short* __restrict__ apH,
                          long pad3_off, long pad3_cnt, long pad6_off, long pad6_cnt, int n) {
    long i = (long)blockIdx.x * blockDim.x + threadIdx.x;
    long stride = (long)gridDim.x * blockDim.x;
    for (long j = i; j < n; j += stride) {
        count[j] = 0;
        cursor[j] = 0;
    }
    if (i < 384) g[i] = 0.f;
    if (i < 12) gmax[i] = 0u;  // slots 0-5: L3, 6-11: L2
    for (long j = i; j < pad3_cnt; j += stride) apH[pad3_off + j] = 0;
    for (long j = i; j < pad6_cnt; j += stride) apH[pad6_off + j] = 0;
}

// ---------------- CSR build ----------------
__global__ void hist_kernel(const int* __restrict__ dst, int* __restrict__ count, int E) {
    int e = blockIdx.x * blockDim.x + threadIdx.x;
    if (e >= E) return;
    atomicAdd(&count[dst[e]], 1);
}

__global__ void scan_block(const int* __restrict__ count, int* __restrict__ offsets,
                           int* __restrict__ bsum, int n) {
    __shared__ int s[1024];
    int i = blockIdx.x * 1024 + threadIdx.x;
    int v = (i < n) ? count[i] : 0;
    s[threadIdx.x] = v;
    __syncthreads();
    for (int off = 1; off < 1024; off <<= 1) {
        int t = (threadIdx.x >= (unsigned)off) ? s[threadIdx.x - off] : 0;
        __syncthreads();
        s[threadIdx.x] += t;
        __syncthreads();
    }
    if (i < n) offsets[i] = s[threadIdx.x] - v;
    if (threadIdx.x == 1023) bsum[blockIdx.x] = s[1023];
}

__global__ void scan_tops(int* __restrict__ bsum, int nb) {
    __shared__ int s[64];
    int t = threadIdx.x;
    int v = (t < nb) ? bsum[t] : 0;
    s[t] = v;
    __syncthreads();
    for (int off = 1; off < 64; off <<= 1) {
        int tmp = (t >= off) ? s[t - off] : 0;
        __syncthreads();
        s[t] += tmp;
        __syncthreads();
    }
    if (t < nb) bsum[t] = s[t] - v;
}

__global__ void scan_add(int* __restrict__ offsets, const int* __restrict__ bsum, int n,
                         int total) {
    int i = blockIdx.x * 1024 + threadIdx.x;
    if (i < n) offsets[i] += bsum[blockIdx.x];
    if (i == 0) offsets[n] = total;
}

__global__ void scatter_kernel(const int* __restrict__ src, const int* __restrict__ dst,
                               const int* __restrict__ offsets, int* __restrict__ cursor,
                               int* __restrict__ ssrc, int E) {
    int e = blockIdx.x * blockDim.x + threadIdx.x;
    if (e >= E) return;
    int d = dst[e];
    int pos = offsets[d] + atomicAdd(&cursor[d], 1);
    ssrc[pos] = src[e];
}

// ---------------- weight repacks ----------------
__global__ void repack_w(const float* __restrict__ W, float* __restrict__ Wp, int FIN, int F) {
    int HF = HHEADS * F;
    int i = blockIdx.x * blockDim.x + threadIdx.x;
    if (i >= FIN * HF) return;
    int k = i / HF, c = i % HF;
    int hd = c / F, f = c % F;
    Wp[i] = W[(hd * FIN + k) * F + f];
}

// bf16 pack in MFMA B-fragment layout (B^T: lane n=..&15, k contiguous)
__global__ void repack_w_mfma(const float* __restrict__ W, unsigned short* __restrict__ bh,
                              int FIN, int F, int NPAD) {
    int i = blockIdx.x * blockDim.x + threadIdx.x;
    if (i >= FIN * NPAD) return;
    int k = i / NPAD, n = i % NPAD;
    int NKT = FIN / 32;
    int HF = HHEADS * F;
    float w = 0.f;
    if (n < HF) {
        int hd = n / F, f = n % F;
        w = W[(hd * FIN + k) * F + f];
    }
    size_t e = ((size_t)((n >> 4) * NKT + (k >> 5)) * 64 + ((n & 15) | (((k >> 3) & 3) << 4))) * 8 +
               (k & 7);
    bh[e] = f2bf(w);
}

// ---------------- small GEMM + fused attn (layer 1, K=11, F=16) ----------------
template <int BM, int BN, int BK>
__global__ __launch_bounds__(256) void gemm_small_attn(const float* __restrict__ A,
                                                       const float* __restrict__ B,
                                                       __hip_bfloat16* __restrict__ C,
                                                       const float* __restrict__ as_,
                                                       const float* __restrict__ ad_,
                                                       float* __restrict__ es,
                                                       float* __restrict__ ed, int M, int K,
                                                       int N) {
    __shared__ float As[BK][BM + 4];
    __shared__ float Bs[BK][BN];
    int tid = threadIdx.x;
    int tx = tid % 16, ty = tid / 16;
    int m0 = blockIdx.y * BM, n0 = blockIdx.x * BN;
    float acc[4][4] = {};
    for (int kk0 = 0; kk0 < K; kk0 += BK) {
#pragma unroll
        for (int i = 0; i < (BM * BK) / 256; ++i) {
            int idx = tid + i * 256;
            int m = idx / BK, k = idx % BK;
            float v = 0.f;
            if (m0 + m < M && kk0 + k < K) v = A[(size_t)(m0 + m) * K + kk0 + k];
            As[k][m] = v;
        }
#pragma unroll
        for (int i = 0; i < (BK * BN) / 1024; ++i) {
            int idx = tid + i * 256;
            int k = idx / (BN / 4), n4 = idx % (BN / 4);
            float4 v = make_float4(0.f, 0.f, 0.f, 0.f);
            if (kk0 + k < K && n0 + n4 * 4 < N)
                v = *(const float4*)&B[(size_t)(kk0 + k) * N + n0 + n4 * 4];
            *(float4*)&Bs[k][n4 * 4] = v;
        }
        __syncthreads();
#pragma unroll
        for (int k = 0; k < BK; ++k) {
            float4 av = *(const float4*)&As[k][ty * 4];
            float4 bv = *(const float4*)&Bs[k][tx * 4];
            float a[4] = {av.x, av.y, av.z, av.w};
            float b[4] = {bv.x, bv.y, bv.z, bv.w};
#pragma unroll
            for (int i = 0; i < 4; ++i)
#pragma unroll
                for (int j = 0; j < 4; ++j) acc[i][j] += a[i] * b[j];
        }
        __syncthreads();
    }
    bool colok = (n0 + tx * 4) < N;
    float asv[4], adv[4];
#pragma unroll
    for (int j = 0; j < 4; ++j) {
        int col = n0 + tx * 4 + j;
        asv[j] = (col < N) ? as_[col] : 0.f;
        adv[j] = (col < N) ? ad_[col] : 0.f;
    }
#pragma unroll
    for (int i = 0; i < 4; ++i) {
        int m = m0 + ty * 4 + i;
        bool mok = m < M;
        if (mok && colok) {
            __hip_bfloat16 tmp[4];
#pragma unroll
            for (int j = 0; j < 4; ++j) tmp[j] = __float2bfloat16(acc[i][j]);
            *(uint2*)&C[(size_t)m * N + n0 + tx * 4] = *(uint2*)tmp;
        }
        float ps = 0.f, pd = 0.f;
#pragma unroll
        for (int j = 0; j < 4; ++j) {
            ps += acc[i][j] * asv[j];
            pd += acc[i][j] * adv[j];
        }
        ps += __shfl_down(ps, 2, 4);
        ps += __shfl_down(ps, 1, 4);
        pd += __shfl_down(pd, 2, 4);
        pd += __shfl_down(pd, 1, 4);
        if (mok && colok && (tx & 3) == 0) {
            int hd = (n0 + tx * 4) >> 4;  // F=16
            es[(size_t)m * HHEADS + hd] = ps;
            ed[(size_t)m * HHEADS + hd] = pd;
        }
    }
}

// ---------------- MFMA bf16 GEMM + fused attn (layers 2/3) ----------------
// R26: MT M-tiles per block; persistent B in LDS (all NKT tiles, staged once);
// A double-buffered issue-early; per-M-tile epilogue inside the loop.
// F==64: C fp8 e4m3; gmax slots 0-5. F==32: C bf16; gmax slots 6-11.
template <int K, int NREAL, int NPAD, int F, int MT>
__global__ __launch_bounds__(256) void gemm_attn_mfma(
    const unsigned short* __restrict__ Ah, const unsigned short* __restrict__ Bh,
    __hip_bfloat16* __restrict__ C, unsigned char* __restrict__ C8,
    const float* __restrict__ as_, const float* __restrict__ ad_, float* __restrict__ es,
    float* __restrict__ ed, unsigned* __restrict__ gmax, int M) {
    constexpr int NKT = K / 32;
    __shared__ unsigned short sB[NKT * 4096];  // persistent B panel
    __shared__ unsigned short sA[2][4096];     // A double buffer
    int tid = threadIdx.x;
    int lane = tid & 63, wave = tid >> 6;
    int wrow = wave >> 1, wcol = wave & 1;
    int quad = lane >> 4, c16 = lane & 15;

    // XCD-bijective swizzle (m204): co-locate blocks sharing B panels.
    int nwg = gridDim.x * gridDim.y;
    int hh = blockIdx.y * gridDim.x + blockIdx.x;
    int q = nwg >> 3, r = nwg & 7;
    int xcd = hh & 7, pos = hh >> 3;
    int wk = (xcd < r ? xcd * (q + 1) : r * (q + 1) + (xcd - r) * q) + pos;
    int bx = wk % gridDim.x, by = wk / gridDim.x;

    int n0 = bx * 128;
    int bn16 = n0 >> 4;
    int nmt = (M + 127) >> 7;  // number of valid 128-row M-tiles

    // ---- stage entire B panel (once) ----
#pragma unroll
    for (int kt2 = 0; kt2 < NKT; ++kt2) {
#pragma unroll
        for (int rep = 0; rep < 2; ++rep) {
            int chunk = tid + rep * 256;
            int tile = chunk >> 6, e8 = chunk & 63;
            size_t boff = ((size_t)((bn16 + tile) * NKT + kt2) * 64 + e8) * 8;
            __builtin_amdgcn_global_load_lds((glb_uint*)&Bh[boff],
                                             (lds_uint*)&sB[kt2 * 4096 + chunk * 8], 16, 0, 0);
        }
    }
    auto STAGE_A = [&](int mti, int kt2, int buf) {
#pragma unroll
        for (int rep = 0; rep < 2; ++rep) {
            int chunk = tid + rep * 256;
            int tile = chunk >> 6, e8 = chunk & 63;
            size_t aoff = ((size_t)((mti * 8 + tile) * NKT + kt2) * 64 + e8) * 8;
            __builtin_amdgcn_global_load_lds((glb_uint*)&Ah[aoff],
                                             (lds_uint*)&sA[buf][chunk * 8], 16, 0, 0);
        }
    };
    STAGE_A(min(by * MT, nmt - 1), 0, 0);
    asm volatile("s_waitcnt vmcnt(0)" ::: "memory");
    __builtin_amdgcn_s_barrier();

    float asv[4], adv[4];
#pragma unroll
    for (int j = 0; j < 4; ++j) {
        int col = n0 + wcol * 64 + j * 16 + c16;
        bool ok = col < NREAL;
        asv[j] = ok ? as_[col] : 0.f;
        adv[j] = ok ? ad_[col] : 0.f;
    }
    float mx = -1e30f;                 // F==64 per-wave head max (across mts)
    float mxA = -1e30f, mxB = -1e30f;  // F==32 per-wave 2-head max
    bool colvalid = (n0 + wcol * 64) < NREAL;
    int b4 = lane & 3;

    f32x4 acc[4][4] = {};
    const int T = MT * NKT;
    int mt = 0, kt = 0;
    for (int t = 0; t < T; ++t) {
        int cur = t & 1;
        int nkt = kt + 1, nmt2 = mt;
        if (nkt == NKT) {
            nkt = 0;
            nmt2 = mt + 1;
        }
        if (t + 1 < T) STAGE_A(min(by * MT + nmt2, nmt - 1), nkt, cur ^ 1);  // issue-early
        bf16x8 fah[4], fbh[4];
#pragma unroll
        for (int i = 0; i < 4; ++i) {
            fah[i] = *(const bf16x8*)&sA[cur][(wrow * 4 + i) * 512 + lane * 8];
            fbh[i] = *(const bf16x8*)&sB[kt * 4096 + (wcol * 4 + i) * 512 + lane * 8];
        }
        asm volatile("s_waitcnt lgkmcnt(0)" ::: "memory");
        __builtin_amdgcn_sched_barrier(0);  // rule #18
#pragma unroll
        for (int i = 0; i < 4; ++i)
#pragma unroll
            for (int j = 0; j < 4; ++j)
                acc[i][j] = __builtin_amdgcn_mfma_f32_16x16x32_bf16(fah[i], fbh[j], acc[i][j],
                                                                    0, 0, 0);
        if (kt == NKT - 1) {  // M-tile complete: epilogue (uniform branch)
            int m0 = (by * MT + mt) * 128;
            if (m0 < M) {
                // ---- es/ed + gmax partial (fragment layout) ----
#pragma unroll
                for (int i = 0; i < 4; ++i) {
#pragma unroll
                    for (int r2 = 0; r2 < 4; ++r2) {
                        int m = m0 + wrow * 64 + i * 16 + quad * 4 + r2;
                        bool mok = m < M;
                        if (F == 64) {
                            float ps = acc[i][0][r2] * asv[0] + acc[i][1][r2] * asv[1] +
                                       acc[i][2][r2] * asv[2] + acc[i][3][r2] * asv[3];
                            float pd = acc[i][0][r2] * adv[0] + acc[i][1][r2] * adv[1] +
                                       acc[i][2][r2] * adv[2] + acc[i][3][r2] * adv[3];
#pragma unroll
                            for (int off = 8; off > 0; off >>= 1) {
                                ps += __shfl_down(ps, off, 16);
                                pd += __shfl_down(pd, off, 16);
                            }
                            if (mok && c16 == 0) {
                                int hd = (n0 + wcol * 64) / 64;
                                es[(size_t)m * HHEADS + hd] = ps;
                                ed[(size_t)m * HHEADS + hd] = pd;
                                mx = fmaxf(mx, ps);
                            }
                        } else {  // F == 32: two heads per wave-column
                            float psA = acc[i][0][r2] * asv[0] + acc[i][1][r2] * asv[1];
                            float pdA = acc[i][0][r2] * adv[0] + acc[i][1][r2] * adv[1];
                            float psB = acc[i][2][r2] * asv[2] + acc[i][3][r2] * asv[3];
                            float pdB = acc[i][2][r2] * adv[2] + acc[i][3][r2] * adv[3];
#pragma unroll
                            for (int off = 8; off > 0; off >>= 1) {
                                psA += __shfl_down(psA, off, 16);
                                pdA += __shfl_down(pdA, off, 16);
                                psB += __shfl_down(psB, off, 16);
                                pdB += __shfl_down(pdB, off, 16);
                            }
                            if (mok && c16 == 0 && colvalid) {
                                int colbase = n0 + wcol * 64;
                                int hd = colbase / 32;
                                es[(size_t)m * HHEADS + hd] = psA;
                                ed[(size_t)m * HHEADS + hd] = pdA;
                                es[(size_t)m * HHEADS + hd + 1] = psB;
                                ed[(size_t)m * HHEADS + hd + 1] = pdB;
                                mxA = fmaxf(mxA, psA);
                                mxB = fmaxf(mxB, psB);
                            }
                        }
                    }
                }
                // ---- C store: transpose 16x16 blocks, packed wide stores ----
#pragma unroll
                for (int i = 0; i < 4; ++i) {
                    int m = m0 + wrow * 64 + i * 16 + quad * 4 + b4;
                    bool mok = m < M;
#pragma unroll
                    for (int j = 0; j < 4; ++j) {
                        float v0 = acc[i][j][0], v1 = acc[i][j][1], v2 = acc[i][j][2],
                              v3 = acc[i][j][3];
                        xpose4(v0, v1, v2, v3, b4);
                        int colb = n0 + wcol * 64 + j * 16 + (c16 & 12);
                        if (F == 64) {
                            if (mok) {
                                int pk = __builtin_amdgcn_cvt_pk_fp8_f32(v0, v1, 0, false);
                                pk = __builtin_amdgcn_cvt_pk_fp8_f32(v2, v3, pk, true);
                                *(unsigned*)&C8[(size_t)m * NREAL + colb] = (unsigned)pk;
                            }
                        } else {
                            if (mok && colvalid) {
                                unsigned lo = (unsigned)f2bf(v0) | ((unsigned)f2bf(v1) << 16);
                                unsigned hi = (unsigned)f2bf(v2) | ((unsigned)f2bf(v3) << 16);
                                uint2 pk2;
                                pk2.x = lo;
                                pk2.y = hi;
                                *(uint2*)&C[(size_t)m * NREAL + colb] = pk2;
                            }
                        }
                    }
                }
            }
#pragma unroll
            for (int i = 0; i < 4; ++i)
#pragma unroll
                for (int j = 0; j < 4; ++j) acc[i][j] = (f32x4){0.f, 0.f, 0.f, 0.f};
        }
        asm volatile("s_waitcnt vmcnt(0)" ::: "memory");
        __builtin_amdgcn_s_barrier();
        kt = nkt;
        mt = nmt2;
    }

    if (F == 64) {  // per-head global es max, one atomic per wave per block
#pragma unroll
        for (int off = 32; off > 0; off >>= 1) mx = fmaxf(mx, __shfl_xor(mx, off));
        if (lane == 0) atomicMax(&gmax[(n0 + wcol * 64) / 64], fkey(mx));
    } else {
        mxA = fmaxf(mxA, __shfl_xor(mxA, 16));
        mxA = fmaxf(mxA, __shfl_xor(mxA, 32));
        mxB = fmaxf(mxB, __shfl_xor(mxB, 16));
        mxB = fmaxf(mxB, __shfl_xor(mxB, 32));
        if (lane == 0 && colvalid) {
            int hd = (n0 + wcol * 64) / 32;
            atomicMax(&gmax[6 + hd], fkey(mxA));
            atomicMax(&gmax[6 + hd + 1], fkey(mxB));
        }
    }
}

// ---------------- online-rescale softmax-aggregate (layer 1) ----------------
// Thread per (node, 8ch); emits bf16 MFMA A-operand plane.
template <int F>
__global__ __launch_bounds__(256) void aggregate_fused(
    const __hip_bfloat16* __restrict__ h, const float* __restrict__ es,
    const float* __restrict__ ed, const int* __restrict__ offsets,
    const int* __restrict__ ssrc, unsigned short* __restrict__ oh, int n) {
    constexpr int HF = HHEADS * F;
    constexpr int C8 = HF / 8;
    int tid = blockIdx.x * blockDim.x + threadIdx.x;
    if (tid >= n * C8) return;
    int node = tid / C8, q = tid % C8;
    int c = q * 8, hd = c / F;
    int a = offsets[node], b = offsets[node + 1];
    float edv = ed[node * HHEADS + hd];
    float m = -1e30f, l = 0.f;
    float acc[8] = {};
    for (int j = a; j < b; ++j) {
        int s = ssrc[j];
        float v = es[s * HHEADS + hd] + edv;
        v = v > 0.f ? v : 0.2f * v;  // leaky relu 0.2
        float mn = fmaxf(m, v);
        float r = __expf(m - mn);
        float wgt = __expf(v - mn);
        uint4 hv = *(const uint4*)&h[(size_t)s * HF + c];
        l = l * r + wgt;
        acc[0] = acc[0] * r + wgt * bfl(hv.x);
        acc[1] = acc[1] * r + wgt * bfh(hv.x);
        acc[2] = acc[2] * r + wgt * bfl(hv.y);
        acc[3] = acc[3] * r + wgt * bfh(hv.y);
        acc[4] = acc[4] * r + wgt * bfl(hv.z);
        acc[5] = acc[5] * r + wgt * bfh(hv.z);
        acc[6] = acc[6] * r + wgt * bfl(hv.w);
        acc[7] = acc[7] * r + wgt * bfh(hv.w);
        m = mn;
    }
    float invd = 1.0f / (l + 1e-16f);
    unsigned short th[8];
#pragma unroll
    for (int k = 0; k < 8; ++k) {
        float v = acc[k] * invd;
        v = v > 0.f ? v : (__expf(v) - 1.0f);  // elu
        th[k] = f2bf(v);
    }
    constexpr int NKT = HF / 32;
    int lq = (node & 15) | (((c >> 3) & 3) << 4);
    size_t base = ((size_t)((node >> 4) * NKT + (c >> 5)) * 64 + lq) * 8;
    *(uint4*)&oh[base] = *(uint4*)th;
}

// ---------------- wave-per-node single-pass aggregate (layer 2) ----------------
__global__ __launch_bounds__(256) void aggregate_wpn2(
    const __hip_bfloat16* __restrict__ h, const float* __restrict__ es,
    const float* __restrict__ ed, const unsigned* __restrict__ gmax,
    const int* __restrict__ offsets, const int* __restrict__ ssrc,
    unsigned short* __restrict__ oh, int n) {
    constexpr int HF = 192;
    int wid = (int)((blockIdx.x * (unsigned)blockDim.x + threadIdx.x) >> 6);
    int lane = threadIdx.x & 63;
    if (wid >= n || lane >= 48) return;
    int node = wid;
    int hd = lane >> 3;  // F=32: 8 lanes (32ch) per head
    int c = lane * 4;
    int a = offsets[node], b = offsets[node + 1];
    float edv = ed[node * HHEADS + hd];
    float mv = funkey(gmax[6 + hd]) + edv;
    float m = mv > 0.f ? mv : 0.2f * mv;
    float l = 0.f;
    float acc[4] = {};
    const unsigned short* hbase = (const unsigned short*)h + c;
    int j = a;
    for (; j + 1 < b; j += 2) {
        int s0 = ssrc[j], s1 = ssrc[j + 1];
        float ev0 = es[(size_t)s0 * HHEADS + hd];
        float ev1 = es[(size_t)s1 * HHEADS + hd];
        uint2 h0 = *(const uint2*)(hbase + (size_t)s0 * HF);
        uint2 h1 = *(const uint2*)(hbase + (size_t)s1 * HF);
        float v0 = ev0 + edv;
        v0 = v0 > 0.f ? v0 : 0.2f * v0;
        float v1 = ev1 + edv;
        v1 = v1 > 0.f ? v1 : 0.2f * v1;
        float w0 = __expf(v0 - m);
        float w1 = __expf(v1 - m);
        l += w0;
        acc[0] += w0 * bfl(h0.x);
        acc[1] += w0 * bfh(h0.x);
        acc[2] += w0 * bfl(h0.y);
        acc[3] += w0 * bfh(h0.y);
        l += w1;
        acc[0] += w1 * bfl(h1.x);
        acc[1] += w1 * bfh(h1.x);
        acc[2] += w1 * bfl(h1.y);
        acc[3] += w1 * bfh(h1.y);
    }
    if (j < b) {
        int s0 = ssrc[j];
        float ev0 = es[(size_t)s0 * HHEADS + hd];
        uint2 h0 = *(const uint2*)(hbase + (size_t)s0 * HF);
        float v0 = ev0 + edv;
        v0 = v0 > 0.f ? v0 : 0.2f * v0;
        float w0 = __expf(v0 - m);
        l += w0;
        acc[0] += w0 * bfl(h0.x);
        acc[1] += w0 * bfh(h0.x);
        acc[2] += w0 * bfl(h0.y);
        acc[3] += w0 * bfh(h0.y);
    }
    float invd = 1.0f / (l + 1e-16f);
    unsigned short th[4];
#pragma unroll
    for (int k = 0; k < 4; ++k) {
        float v = acc[k] * invd;
        v = v > 0.f ? v : (__expf(v) - 1.0f);  // elu
        th[k] = f2bf(v);
    }
    int lq = (node & 15) | (((c >> 3) & 3) << 4);
    size_t base = ((size_t)((node >> 4) * (HF / 32) + (c >> 5)) * 64 + lq) * 8 + (c & 7);
    *(uint2*)&oh[base] = *(uint2*)th;
}

// ---------------- wave-per-node single-pass aggregate (layer 3, fp8 h) --------
__global__ __launch_bounds__(256) void aggregate_wpn3(
    const unsigned char* __restrict__ h8, const float* __restrict__ es,
    const float* __restrict__ ed, const unsigned* __restrict__ gmax,
    const int* __restrict__ offsets, const int* __restrict__ ssrc,
    __hip_bfloat16* __restrict__ outb, int n) {
    constexpr int HF = 384;
    int wid = (int)((blockIdx.x * (unsigned)blockDim.x + threadIdx.x) >> 6);
    int lane = threadIdx.x & 63;
    if (wid >= n || lane >= 48) return;
    int node = wid;
    int hd = lane >> 3;  // 8 lanes (64ch) per head
    int c = lane * 8;
    int a = offsets[node], b = offsets[node + 1];
    float edv = ed[node * HHEADS + hd];
    float mv = funkey(gmax[hd]) + edv;
    float m = mv > 0.f ? mv : 0.2f * mv;
    float l = 0.f;
    float acc[8] = {};
    const unsigned char* hbase = h8 + c;
    int j = a;
    for (; j + 1 < b; j += 2) {
        int s0 = ssrc[j], s1 = ssrc[j + 1];
        float ev0 = es[(size_t)s0 * HHEADS + hd];
        float ev1 = es[(size_t)s1 * HHEADS + hd];
        uint2 h0 = *(const uint2*)(hbase + (size_t)s0 * HF);
        uint2 h1 = *(const uint2*)(hbase + (size_t)s1 * HF);
        float v0 = ev0 + edv;
        v0 = v0 > 0.f ? v0 : 0.2f * v0;
        float v1 = ev1 + edv;
        v1 = v1 > 0.f ? v1 : 0.2f * v1;
        float w0 = __expf(v0 - m);
        float w1 = __expf(v1 - m);
        {
            f32x2 p0 = __builtin_amdgcn_cvt_pk_f32_fp8((int)h0.x, false);
            f32x2 p1 = __builtin_amdgcn_cvt_pk_f32_fp8((int)h0.x, true);
            f32x2 p2 = __builtin_amdgcn_cvt_pk_f32_fp8((int)h0.y, false);
            f32x2 p3 = __builtin_amdgcn_cvt_pk_f32_fp8((int)h0.y, true);
            l += w0;
            acc[0] += w0 * p0[0];
            acc[1] += w0 * p0[1];
            acc[2] += w0 * p1[0];
            acc[3] += w0 * p1[1];
            acc[4] += w0 * p2[0];
            acc[5] += w0 * p2[1];
            acc[6] += w0 * p3[0];
            acc[7] += w0 * p3[1];
        }
        {
            f32x2 p0 = __builtin_amdgcn_cvt_pk_f32_fp8((int)h1.x, false);
            f32x2 p1 = __builtin_amdgcn_cvt_pk_f32_fp8((int)h1.x, true);
            f32x2 p2 = __builtin_amdgcn_cvt_pk_f32_fp8((int)h1.y, false);
            f32x2 p3 = __builtin_amdgcn_cvt_pk_f32_fp8((int)h1.y, true);
            l += w1;
            acc[0] += w1 * p0[0];
            acc[1] += w1 * p0[1];
            acc[2] += w1 * p1[0];
            acc[3] += w1 * p1[1];
            acc[4] += w1 * p2[0];
            acc[5] += w1 * p2[1];
            acc[6] += w1 * p3[0];
            acc[7] += w1 * p3[1];
        }
    }
    if (j < b) {
        int s0 = ssrc[j];
        float ev0 = es[(size_t)s0 * HHEADS + hd];
        uint2 h0 = *(const uint2*)(hbase + (size_t)s0 * HF);
        float v0 = ev0 + edv;
        v0 = v0 > 0.f ? v0 : 0.2f * v0;
        float w0 = __expf(v0 - m);
        f32x2 p0 = __builtin_amdgcn_cvt_pk_f32_fp8((int)h0.x, false);
        f32x2 p1 = __builtin_amdgcn_cvt_pk_f32_fp8((int)h0.x, true);
        f32x2 p2 = __builtin_amdgcn_cvt_pk_f32_fp8((int)h0.y, false);
        f32x2 p3 = __builtin_amdgcn_cvt_pk_f32_fp8((int)h0.y, true);
        l += w0;
        acc[0] += w0 * p0[0];
        acc[1] += w0 * p0[1];
        acc[2] += w0 * p1[0];
        acc[3] += w0 * p1[1];
        acc[4] += w0 * p2[0];
        acc[5] += w0 * p2[1];
        acc[6] += w0 * p3[0];
        acc[7] += w0 * p3[1];
    }
    float invd = 1.0f / (l + 1e-16f);
    __hip_bfloat16 tb[8];
#pragma unroll
    for (int k = 0; k < 8; ++k) {
        float v = acc[k] * invd;
        v = v > 0.f ? v : (__expf(v) - 1.0f);  // elu
        tb[k] = __float2bfloat16(v);
    }
    *(uint4*)&outb[(size_t)node * HF + c] = *(uint4*)tb;
}

// ---------------- pooling (bf16 input) + head ----------------
__global__ void pool_kernel(const __hip_bfloat16* __restrict__ out3, float* __restrict__ g,
                            int n) {
    int b = blockIdx.x, t = threadIdx.x;  // blockDim = 192
    int chunk = (n + gridDim.x - 1) / gridDim.x;
    int n0 = b * chunk, n1 = min(n, n0 + chunk);
    float a0 = 0.f, a1 = 0.f;
    const unsigned* p = (const unsigned*)out3;
    for (int node = n0; node < n1; ++node) {
        unsigned u = p[(size_t)node * 192 + t];
        a0 += bfl(u);
        a1 += bfh(u);
    }
    atomicAdd(&g[2 * t], a0);
    atomicAdd(&g[2 * t + 1], a1);
}

__global__ void final_kernel(const float* __restrict__ g, const float* __restrict__ Wd,
                             const float* __restrict__ bd, float* __restrict__ outp) {
    __shared__ float red[384];
    int t = threadIdx.x;  // blockDim = 384
    float v = g[t];
    red[t] = v * v;
    __syncthreads();
    for (int s = 192; s >= 3; s >>= 1) {
        if (t < s) red[t] += red[t + s];
        __syncthreads();
    }
    __shared__ float scale_s;
    if (t == 0) {
        float norm = sqrtf(red[0] + red[1] + red[2]);
        scale_s = 1.0f / fmaxf(norm, 1e-12f);
    }
    __syncthreads();
    float scale = scale_s;
    red[t] = v * scale * Wd[t];
    __syncthreads();
    for (int s = 192; s >= 3; s >>= 1) {
        if (t < s) red[t] += red[t + s];
        __syncthreads();
    }
    if (t == 0) outp[0] = red[0] + red[1] + red[2] + bd[0];
}

// ---------------- host side ----------------
extern "C" void kernel_launch(void* const* d_in, const int* in_sizes, int n_in, void* d_out,
                              int out_size, void* d_ws, size_t ws_size, hipStream_t stream) {
    const float* x = (const float*)d_in[0];
    const int* ei = (const int*)d_in[1];
    const float* W1 = (const float*)d_in[2];
    const float* a1s = (const float*)d_in[3];
    const float* a1d = (const float*)d_in[4];
    const float* W2 = (const float*)d_in[5];
    const float* a2s = (const float*)d_in[6];
    const float* a2d = (const float*)d_in[7];
    const float* W3 = (const float*)d_in[8];
    const float* a3s = (const float*)d_in[9];
    const float* a3d = (const float*)d_in[10];
    const float* Wd = (const float*)d_in[11];
    const float* bd = (const float*)d_in[12];
    float* outp = (float*)d_out;

    const int N = in_sizes[0] / 11;
    const int E = in_sizes[1] / 2;
    const int* src = ei;
    const int* dst = ei + E;

    const int NT16 = ((N + 127) / 128) * 8;  // padded 16-row tiles
    const int NMT = (N + 127) / 128;         // 128-row M-tiles

    char* w = (char*)d_ws;
    size_t off = 0;
    auto A = [&](size_t bytes) {
        size_t o = off;
        off += (bytes + 255) & ~(size_t)255;
        return o;
    };
    __hip_bfloat16* bufH = (__hip_bfloat16*)(w + A((size_t)N * 384 * 2));  // h (bf16 / fp8@L3)
    __hip_bfloat16* bufO = (__hip_bfloat16*)(w + A((size_t)N * 384 * 2));  // layer3 out (bf16)
    unsigned short* apH = (unsigned short*)(w + A((size_t)NT16 * 6 * 512 * 2));  // A-pack
    unsigned short* b2H = (unsigned short*)(w + A((size_t)16 * 3 * 512 * 2));    // W2 pack
    unsigned short* b3H = (unsigned short*)(w + A((size_t)24 * 6 * 512 * 2));    // W3 pack
    float* es = (float*)(w + A((size_t)N * HHEADS * 4));
    float* ed = (float*)(w + A((size_t)N * HHEADS * 4));
    unsigned* gmax = (unsigned*)(w + A(256));
    float* wp = (float*)(w + A((size_t)11 * 96 * 4));  // layer-1 f32 repack
    int* count = (int*)(w + A((size_t)(N + 1) * 4));
    int* cursor = (int*)(w + A((size_t)(N + 1) * 4));
    int* offsets = (int*)(w + A((size_t)(N + 1) * 4));
    int* bsum = (int*)(w + A(64 * 4));
    int* ssrc = (int*)(w + A((size_t)E * 4));
    float* g = (float*)(w + A(384 * 4));

    // one-shot zero of all small scratch (count, cursor, g, gmax, A-pack pads)
    const long t16v = N / 16;
    const long padT = NT16 - t16v;
    zero_misc<<<(N + 255) / 256, 256, 0, stream>>>(count, cursor, g, gmax, apH,
                                                   t16v * 3 * 512, padT * 3 * 512,
                                                   t16v * 6 * 512, padT * 6 * 512, N);

    // CSR build (by dst)
    hist_kernel<<<(E + 255) / 256, 256, 0, stream>>>(dst, count, E);
    int nb = (N + 1023) / 1024;
    scan_block<<<nb, 1024, 0, stream>>>(count, offsets, bsum, N);
    scan_tops<<<1, 64, 0, stream>>>(bsum, nb);
    scan_add<<<nb, 1024, 0, stream>>>(offsets, bsum, N, E);
    scatter_kernel<<<(E + 255) / 256, 256, 0, stream>>>(src, dst, offsets, cursor, ssrc, E);

    // weight packs
    repack_w<<<(11 * 96 + 255) / 256, 256, 0, stream>>>(W1, wp, 11, 16);
    repack_w_mfma<<<(96 * 256 + 255) / 256, 256, 0, stream>>>(W2, b2H, 96, 32, 256);
    repack_w_mfma<<<(192 * 384 + 255) / 256, 256, 0, stream>>>(W3, b3H, 192, 64, 384);

    // ---- layer 1 (FIN=11, F=16): gemm + fused attn terms ----
    {
        dim3 grid((96 + 63) / 64, (N + 63) / 64);
        gemm_small_attn<64, 64, 32><<<grid, 256, 0, stream>>>(x, wp, bufH, a1s, a1d, es, ed, N,
                                                              11, 96);
    }
    {
        long total = (long)N * (96 / 8);
        aggregate_fused<16><<<(total + 255) / 256, 256, 0, stream>>>(bufH, es, ed, offsets,
                                                                     ssrc, apH, N);
    }

    // ---- layer 2 (K=96, N=192 pad 256, F=32): bf16 C + fused gmax(6-11) ----
    {
        dim3 grid(2, (NMT + 3) / 4);
        gemm_attn_mfma<96, 192, 256, 32, 4><<<grid, 256, 0, stream>>>(
            apH, b2H, bufH, (unsigned char*)nullptr, a2s, a2d, es, ed, gmax, N);
    }
    {
        int grid = (N + 3) / 4;  // 4 waves/block, wave-per-node
        aggregate_wpn2<<<grid, 256, 0, stream>>>(bufH, es, ed, gmax, offsets, ssrc, apH, N);
    }

    // ---- layer 3 (K=192, N=384, F=64): fp8 C + fused gmax(0-5) ----
    {
        dim3 grid(3, (NMT + 3) / 4);
        gemm_attn_mfma<192, 384, 384, 64, 4><<<grid, 256, 0, stream>>>(
            apH, b3H, bufH, (unsigned char*)bufH, a3s, a3d, es, ed, gmax, N);
    }
    {
        int grid = (N + 3) / 4;
        aggregate_wpn3<<<grid, 256, 0, stream>>>((const unsigned char*)bufH, es, ed, gmax,
                                                 offsets, ssrc, bufO, N);
    }

    // sum-pool (bf16 in) -> normalize -> dense
    pool_kernel<<<256, 192, 0, stream>>>(bufO, g, N);
    final_kernel<<<1, 384, 0, stream>>>(g, Wd, bd, outp);
}

// Round 10
// 513.338 us; speedup vs baseline: 1.1282x; 1.0261x over previous
//
#include <hip/hip_runtime.h>
#include <hip/hip_bf16.h>

// GAT 3-layer: N=50000 nodes, E=800000 edges, H=6 heads.
// R1-R17: MFMA GEMMs + CSR fused softmax/aggregate ladder (545us).
// R20: L3 aggregate wave-per-node; aggregates pin at bytes-through-L2-miss.
// R21: L3 h -> fp8 e4m3 (absmax 2.4e-4, passed) + L2 wpn agg.
// R22-R25: GEMM store/stage/pipeline/precision ladder -> GEMM invariant;
//      per-block fixed overhead dominates at 1173 tiny blocks.
// R26: MT=4 M-tiles/block, persistent-B LDS: GEMMs out of top-5; 555->527us.
//      agg3 now 69us at VALU 60% / FETCH 154MB = 8 XCDs x fp8 array (near its
//      bytes+VALU roofline).
// R27: same fp8 lever on the two remaining bf16 gathers: L1 h (96B/row) and
//      L2 h (192B/row) stored fp8 by their producing GEMMs, unpacked with
//      cvt_pk_f32_fp8 in the aggregates. es/ed stay exact f32; A-pack bf16;
//      L3 untouched. Revert L1-fp8 first if absmax fails.

#define HHEADS 6

typedef __attribute__((ext_vector_type(8))) short bf16x8;   // 8 bf16 = 4 VGPR
typedef __attribute__((ext_vector_type(4))) float f32x4;    // mfma C/D
typedef __attribute__((ext_vector_type(2))) float f32x2;

typedef __attribute__((address_space(3))) unsigned int lds_uint;
typedef const __attribute__((address_space(1))) unsigned int glb_uint;

__device__ __forceinline__ float bfl(unsigned u) { return __uint_as_float(u << 16); }
__device__ __forceinline__ float bfh(unsigned u) { return __uint_as_float(u & 0xffff0000u); }
__device__ __forceinline__ unsigned short f2bf(float v) {  // RNE f32->bf16
    unsigned u = __float_as_uint(v);
    return (unsigned short)((u + 0x7fffu + ((u >> 16) & 1u)) >> 16);
}
__device__ __forceinline__ float bf2f(unsigned short h) {
    return __uint_as_float((unsigned)h << 16);
}
// monotone float<->uint for atomicMax on floats (memset-0 = -inf identity)
__device__ __forceinline__ unsigned fkey(float f) {
    unsigned u = __float_as_uint(f);
    return (u >> 31) ? ~u : (u | 0x80000000u);
}
__device__ __forceinline__ float funkey(unsigned k) {
    return (k >> 31) ? __uint_as_float(k & 0x7fffffffu) : __uint_as_float(~k);
}

// 4x4 transpose across a 4-lane group (lanes share lane>>2). In: v0..v3 =
// rows 0..3 at this lane's column. Out: v0..v3 = cols 0..3 at row (lane&3).
__device__ __forceinline__ void xpose4(float& v0, float& v1, float& v2, float& v3, int b) {
    bool hi = (b & 2) != 0;
    float s0 = hi ? v0 : v2;
    float s1 = hi ? v1 : v3;
    s0 = __shfl_xor(s0, 2, 64);
    s1 = __shfl_xor(s1, 2, 64);
    v0 = hi ? s0 : v0;
    v1 = hi ? s1 : v1;
    v2 = hi ? v2 : s0;
    v3 = hi ? v3 : s1;
    bool od = (b & 1) != 0;
    float t0 = od ? v0 : v1;
    t0 = __shfl_xor(t0, 1, 64);
    v0 = od ? t0 : v0;
    v1 = od ? v1 : t0;
    float t1 = od ? v2 : v3;
    t1 = __shfl_xor(t1, 1, 64);
    v2 = od ? t1 : v2;
    v3 = od ? v3 : t1;
}

// ---------------- one-shot zero of all small scratch ----------------
__global__ void zero_misc(int* __restrict__ count, int* __restrict__ cursor,
                          float* __restrict__ g, unsigned* __restrict__ gmax,
                          unsigned short* __restrict__ apH,
                          long pad3_off, long pad3_cnt, long pad6_off, long pad6_cnt, int n) {
    long i = (long)blockIdx.x * blockDim.x + threadIdx.x;
    long stride = (long)gridDim.x * blockDim.x;
    for (long j = i; j < n; j += stride) {
        count[j] = 0;
        cursor[j] = 0;
    }
    if (i < 384) g[i] = 0.f;
    if (i < 12) gmax[i] = 0u;  // slots 0-5: L3, 6-11: L2
    for (long j = i; j < pad3_cnt; j += stride) apH[pad3_off + j] = 0;
    for (long j = i; j < pad6_cnt; j += stride) apH[pad6_off + j] = 0;
}

// ---------------- CSR build ----------------
__global__ void hist_kernel(const int* __restrict__ dst, int* __restrict__ count, int E) {
    int e = blockIdx.x * blockDim.x + threadIdx.x;
    if (e >= E) return;
    atomicAdd(&count[dst[e]], 1);
}

__global__ void scan_block(const int* __restrict__ count, int* __restrict__ offsets,
                           int* __restrict__ bsum, int n) {
    __shared__ int s[1024];
    int i = blockIdx.x * 1024 + threadIdx.x;
    int v = (i < n) ? count[i] : 0;
    s[threadIdx.x] = v;
    __syncthreads();
    for (int off = 1; off < 1024; off <<= 1) {
        int t = (threadIdx.x >= (unsigned)off) ? s[threadIdx.x - off] : 0;
        __syncthreads();
        s[threadIdx.x] += t;
        __syncthreads();
    }
    if (i < n) offsets[i] = s[threadIdx.x] - v;
    if (threadIdx.x == 1023) bsum[blockIdx.x] = s[1023];
}

__global__ void scan_tops(int* __restrict__ bsum, int nb) {
    __shared__ int s[64];
    int t = threadIdx.x;
    int v = (t < nb) ? bsum[t] : 0;
    s[t] = v;
    __syncthreads();
    for (int off = 1; off < 64; off <<= 1) {
        int tmp = (t >= off) ? s[t - off] : 0;
        __syncthreads();
        s[t] += tmp;
        __syncthreads();
    }
    if (t < nb) bsum[t] = s[t] - v;
}

__global__ void scan_add(int* __restrict__ offsets, const int* __restrict__ bsum, int n,
                         int total) {
    int i = blockIdx.x * 1024 + threadIdx.x;
    if (i < n) offsets[i] += bsum[blockIdx.x];
    if (i == 0) offsets[n] = total;
}

__global__ void scatter_kernel(const int* __restrict__ src, const int* __restrict__ dst,
                               const int* __restrict__ offsets, int* __restrict__ cursor,
                               int* __restrict__ ssrc, int E) {
    int e = blockIdx.x * blockDim.x + threadIdx.x;
    if (e >= E) return;
    int d = dst[e];
    int pos = offsets[d] + atomicAdd(&cursor[d], 1);
    ssrc[pos] = src[e];
}

// ---------------- weight repacks ----------------
__global__ void repack_w(const float* __restrict__ W, float* __restrict__ Wp, int FIN, int F) {
    int HF = HHEADS * F;
    int i = blockIdx.x * blockDim.x + threadIdx.x;
    if (i >= FIN * HF) return;
    int k = i / HF, c = i % HF;
    int hd = c / F, f = c % F;
    Wp[i] = W[(hd * FIN + k) * F + f];
}

// bf16 pack in MFMA B-fragment layout (B^T: lane n=..&15, k contiguous)
__global__ void repack_w_mfma(const float* __restrict__ W, unsigned short* __restrict__ bh,
                              int FIN, int F, int NPAD) {
    int i = blockIdx.x * blockDim.x + threadIdx.x;
    if (i >= FIN * NPAD) return;
    int k = i / NPAD, n = i % NPAD;
    int NKT = FIN / 32;
    int HF = HHEADS * F;
    float w = 0.f;
    if (n < HF) {
        int hd = n / F, f = n % F;
        w = W[(hd * FIN + k) * F + f];
    }
    size_t e = ((size_t)((n >> 4) * NKT + (k >> 5)) * 64 + ((n & 15) | (((k >> 3) & 3) << 4))) * 8 +
               (k & 7);
    bh[e] = f2bf(w);
}

// ---------------- small GEMM + fused attn (layer 1, K=11, F=16) ----------------
// R27: C written fp8 e4m3 (feeds only aggregate_fused).
template <int BM, int BN, int BK>
__global__ __launch_bounds__(256) void gemm_small_attn(const float* __restrict__ A,
                                                       const float* __restrict__ B,
                                                       unsigned char* __restrict__ C8,
                                                       const float* __restrict__ as_,
                                                       const float* __restrict__ ad_,
                                                       float* __restrict__ es,
                                                       float* __restrict__ ed, int M, int K,
                                                       int N) {
    __shared__ float As[BK][BM + 4];
    __shared__ float Bs[BK][BN];
    int tid = threadIdx.x;
    int tx = tid % 16, ty = tid / 16;
    int m0 = blockIdx.y * BM, n0 = blockIdx.x * BN;
    float acc[4][4] = {};
    for (int kk0 = 0; kk0 < K; kk0 += BK) {
#pragma unroll
        for (int i = 0; i < (BM * BK) / 256; ++i) {
            int idx = tid + i * 256;
            int m = idx / BK, k = idx % BK;
            float v = 0.f;
            if (m0 + m < M && kk0 + k < K) v = A[(size_t)(m0 + m) * K + kk0 + k];
            As[k][m] = v;
        }
#pragma unroll
        for (int i = 0; i < (BK * BN) / 1024; ++i) {
            int idx = tid + i * 256;
            int k = idx / (BN / 4), n4 = idx % (BN / 4);
            float4 v = make_float4(0.f, 0.f, 0.f, 0.f);
            if (kk0 + k < K && n0 + n4 * 4 < N)
                v = *(const float4*)&B[(size_t)(kk0 + k) * N + n0 + n4 * 4];
            *(float4*)&Bs[k][n4 * 4] = v;
        }
        __syncthreads();
#pragma unroll
        for (int k = 0; k < BK; ++k) {
            float4 av = *(const float4*)&As[k][ty * 4];
            float4 bv = *(const float4*)&Bs[k][tx * 4];
            float a[4] = {av.x, av.y, av.z, av.w};
            float b[4] = {bv.x, bv.y, bv.z, bv.w};
#pragma unroll
            for (int i = 0; i < 4; ++i)
#pragma unroll
                for (int j = 0; j < 4; ++j) acc[i][j] += a[i] * b[j];
        }
        __syncthreads();
    }
    bool colok = (n0 + tx * 4) < N;
    float asv[4], adv[4];
#pragma unroll
    for (int j = 0; j < 4; ++j) {
        int col = n0 + tx * 4 + j;
        asv[j] = (col < N) ? as_[col] : 0.f;
        adv[j] = (col < N) ? ad_[col] : 0.f;
    }
#pragma unroll
    for (int i = 0; i < 4; ++i) {
        int m = m0 + ty * 4 + i;
        bool mok = m < M;
        if (mok && colok) {
            int pk = __builtin_amdgcn_cvt_pk_fp8_f32(acc[i][0], acc[i][1], 0, false);
            pk = __builtin_amdgcn_cvt_pk_fp8_f32(acc[i][2], acc[i][3], pk, true);
            *(unsigned*)&C8[(size_t)m * N + n0 + tx * 4] = (unsigned)pk;
        }
        float ps = 0.f, pd = 0.f;
#pragma unroll
        for (int j = 0; j < 4; ++j) {
            ps += acc[i][j] * asv[j];
            pd += acc[i][j] * adv[j];
        }
        ps += __shfl_down(ps, 2, 4);
        ps += __shfl_down(ps, 1, 4);
        pd += __shfl_down(pd, 2, 4);
        pd += __shfl_down(pd, 1, 4);
        if (mok && colok && (tx & 3) == 0) {
            int hd = (n0 + tx * 4) >> 4;  // F=16
            es[(size_t)m * HHEADS + hd] = ps;
            ed[(size_t)m * HHEADS + hd] = pd;
        }
    }
}

// ---------------- MFMA bf16 GEMM + fused attn (layers 2/3) ----------------
// R26: MT M-tiles per block; persistent B in LDS; A double-buffered.
// R27: C always fp8 e4m3 (both layers' h feed only their aggregate).
// F==64: gmax slots 0-5. F==32: gmax slots 6-11.
template <int K, int NREAL, int NPAD, int F, int MT>
__global__ __launch_bounds__(256) void gemm_attn_mfma(
    const unsigned short* __restrict__ Ah, const unsigned short* __restrict__ Bh,
    unsigned char* __restrict__ C8, const float* __restrict__ as_,
    const float* __restrict__ ad_, float* __restrict__ es, float* __restrict__ ed,
    unsigned* __restrict__ gmax, int M) {
    constexpr int NKT = K / 32;
    __shared__ unsigned short sB[NKT * 4096];  // persistent B panel
    __shared__ unsigned short sA[2][4096];     // A double buffer
    int tid = threadIdx.x;
    int lane = tid & 63, wave = tid >> 6;
    int wrow = wave >> 1, wcol = wave & 1;
    int quad = lane >> 4, c16 = lane & 15;

    // XCD-bijective swizzle (m204): co-locate blocks sharing B panels.
    int nwg = gridDim.x * gridDim.y;
    int hh = blockIdx.y * gridDim.x + blockIdx.x;
    int q = nwg >> 3, r = nwg & 7;
    int xcd = hh & 7, pos = hh >> 3;
    int wk = (xcd < r ? xcd * (q + 1) : r * (q + 1) + (xcd - r) * q) + pos;
    int bx = wk % gridDim.x, by = wk / gridDim.x;

    int n0 = bx * 128;
    int bn16 = n0 >> 4;
    int nmt = (M + 127) >> 7;  // number of valid 128-row M-tiles

    // ---- stage entire B panel (once) ----
#pragma unroll
    for (int kt2 = 0; kt2 < NKT; ++kt2) {
#pragma unroll
        for (int rep = 0; rep < 2; ++rep) {
            int chunk = tid + rep * 256;
            int tile = chunk >> 6, e8 = chunk & 63;
            size_t boff = ((size_t)((bn16 + tile) * NKT + kt2) * 64 + e8) * 8;
            __builtin_amdgcn_global_load_lds((glb_uint*)&Bh[boff],
                                             (lds_uint*)&sB[kt2 * 4096 + chunk * 8], 16, 0, 0);
        }
    }
    auto STAGE_A = [&](int mti, int kt2, int buf) {
#pragma unroll
        for (int rep = 0; rep < 2; ++rep) {
            int chunk = tid + rep * 256;
            int tile = chunk >> 6, e8 = chunk & 63;
            size_t aoff = ((size_t)((mti * 8 + tile) * NKT + kt2) * 64 + e8) * 8;
            __builtin_amdgcn_global_load_lds((glb_uint*)&Ah[aoff],
                                             (lds_uint*)&sA[buf][chunk * 8], 16, 0, 0);
        }
    };
    STAGE_A(min(by * MT, nmt - 1), 0, 0);
    asm volatile("s_waitcnt vmcnt(0)" ::: "memory");
    __builtin_amdgcn_s_barrier();

    float asv[4], adv[4];
#pragma unroll
    for (int j = 0; j < 4; ++j) {
        int col = n0 + wcol * 64 + j * 16 + c16;
        bool ok = col < NREAL;
        asv[j] = ok ? as_[col] : 0.f;
        adv[j] = ok ? ad_[col] : 0.f;
    }
    float mx = -1e30f;                 // F==64 per-wave head max (across mts)
    float mxA = -1e30f, mxB = -1e30f;  // F==32 per-wave 2-head max
    bool colvalid = (n0 + wcol * 64) < NREAL;
    int b4 = lane & 3;

    f32x4 acc[4][4] = {};
    const int T = MT * NKT;
    int mt = 0, kt = 0;
    for (int t = 0; t < T; ++t) {
        int cur = t & 1;
        int nkt = kt + 1, nmt2 = mt;
        if (nkt == NKT) {
            nkt = 0;
            nmt2 = mt + 1;
        }
        if (t + 1 < T) STAGE_A(min(by * MT + nmt2, nmt - 1), nkt, cur ^ 1);  // issue-early
        bf16x8 fah[4], fbh[4];
#pragma unroll
        for (int i = 0; i < 4; ++i) {
            fah[i] = *(const bf16x8*)&sA[cur][(wrow * 4 + i) * 512 + lane * 8];
            fbh[i] = *(const bf16x8*)&sB[kt * 4096 + (wcol * 4 + i) * 512 + lane * 8];
        }
        asm volatile("s_waitcnt lgkmcnt(0)" ::: "memory");
        __builtin_amdgcn_sched_barrier(0);  // rule #18
#pragma unroll
        for (int i = 0; i < 4; ++i)
#pragma unroll
            for (int j = 0; j < 4; ++j)
                acc[i][j] = __builtin_amdgcn_mfma_f32_16x16x32_bf16(fah[i], fbh[j], acc[i][j],
                                                                    0, 0, 0);
        if (kt == NKT - 1) {  // M-tile complete: epilogue (uniform branch)
            int m0 = (by * MT + mt) * 128;
            if (m0 < M) {
                // ---- es/ed + gmax partial (fragment layout) ----
#pragma unroll
                for (int i = 0; i < 4; ++i) {
#pragma unroll
                    for (int r2 = 0; r2 < 4; ++r2) {
                        int m = m0 + wrow * 64 + i * 16 + quad * 4 + r2;
                        bool mok = m < M;
                        if (F == 64) {
                            float ps = acc[i][0][r2] * asv[0] + acc[i][1][r2] * asv[1] +
                                       acc[i][2][r2] * asv[2] + acc[i][3][r2] * asv[3];
                            float pd = acc[i][0][r2] * adv[0] + acc[i][1][r2] * adv[1] +
                                       acc[i][2][r2] * adv[2] + acc[i][3][r2] * adv[3];
#pragma unroll
                            for (int off = 8; off > 0; off >>= 1) {
                                ps += __shfl_down(ps, off, 16);
                                pd += __shfl_down(pd, off, 16);
                            }
                            if (mok && c16 == 0) {
                                int hd = (n0 + wcol * 64) / 64;
                                es[(size_t)m * HHEADS + hd] = ps;
                                ed[(size_t)m * HHEADS + hd] = pd;
                                mx = fmaxf(mx, ps);
                            }
                        } else {  // F == 32: two heads per wave-column
                            float psA = acc[i][0][r2] * asv[0] + acc[i][1][r2] * asv[1];
                            float pdA = acc[i][0][r2] * adv[0] + acc[i][1][r2] * adv[1];
                            float psB = acc[i][2][r2] * asv[2] + acc[i][3][r2] * asv[3];
                            float pdB = acc[i][2][r2] * adv[2] + acc[i][3][r2] * adv[3];
#pragma unroll
                            for (int off = 8; off > 0; off >>= 1) {
                                psA += __shfl_down(psA, off, 16);
                                pdA += __shfl_down(pdA, off, 16);
                                psB += __shfl_down(psB, off, 16);
                                pdB += __shfl_down(pdB, off, 16);
                            }
                            if (mok && c16 == 0 && colvalid) {
                                int colbase = n0 + wcol * 64;
                                int hd = colbase / 32;
                                es[(size_t)m * HHEADS + hd] = psA;
                                ed[(size_t)m * HHEADS + hd] = pdA;
                                es[(size_t)m * HHEADS + hd + 1] = psB;
                                ed[(size_t)m * HHEADS + hd + 1] = pdB;
                                mxA = fmaxf(mxA, psA);
                                mxB = fmaxf(mxB, psB);
                            }
                        }
                    }
                }
                // ---- C store (fp8): transpose 16x16 blocks, dword stores ----
#pragma unroll
                for (int i = 0; i < 4; ++i) {
                    int m = m0 + wrow * 64 + i * 16 + quad * 4 + b4;
                    bool mok = m < M;
#pragma unroll
                    for (int j = 0; j < 4; ++j) {
                        float v0 = acc[i][j][0], v1 = acc[i][j][1], v2 = acc[i][j][2],
                              v3 = acc[i][j][3];
                        xpose4(v0, v1, v2, v3, b4);
                        int colb = n0 + wcol * 64 + j * 16 + (c16 & 12);
                        if (mok && (F == 64 || colvalid)) {
                            int pk = __builtin_amdgcn_cvt_pk_fp8_f32(v0, v1, 0, false);
                            pk = __builtin_amdgcn_cvt_pk_fp8_f32(v2, v3, pk, true);
                            *(unsigned*)&C8[(size_t)m * NREAL + colb] = (unsigned)pk;
                        }
                    }
                }
            }
#pragma unroll
            for (int i = 0; i < 4; ++i)
#pragma unroll
                for (int j = 0; j < 4; ++j) acc[i][j] = (f32x4){0.f, 0.f, 0.f, 0.f};
        }
        asm volatile("s_waitcnt vmcnt(0)" ::: "memory");
        __builtin_amdgcn_s_barrier();
        kt = nkt;
        mt = nmt2;
    }

    if (F == 64) {  // per-head global es max, one atomic per wave per block
#pragma unroll
        for (int off = 32; off > 0; off >>= 1) mx = fmaxf(mx, __shfl_xor(mx, off));
        if (lane == 0) atomicMax(&gmax[(n0 + wcol * 64) / 64], fkey(mx));
    } else {
        mxA = fmaxf(mxA, __shfl_xor(mxA, 16));
        mxA = fmaxf(mxA, __shfl_xor(mxA, 32));
        mxB = fmaxf(mxB, __shfl_xor(mxB, 16));
        mxB = fmaxf(mxB, __shfl_xor(mxB, 32));
        if (lane == 0 && colvalid) {
            int hd = (n0 + wcol * 64) / 32;
            atomicMax(&gmax[6 + hd], fkey(mxA));
            atomicMax(&gmax[6 + hd + 1], fkey(mxB));
        }
    }
}

// ---------------- online-rescale softmax-aggregate (layer 1, fp8 h) -----------
// Thread per (node, 8ch); fp8 gather (uint2) + HW unpack; emits bf16 A-plane.
template <int F>
__global__ __launch_bounds__(256) void aggregate_fused(
    const unsigned char* __restrict__ h8, const float* __restrict__ es,
    const float* __restrict__ ed, const int* __restrict__ offsets,
    const int* __restrict__ ssrc, unsigned short* __restrict__ oh, int n) {
    constexpr int HF = HHEADS * F;
    constexpr int C8 = HF / 8;
    int tid = blockIdx.x * blockDim.x + threadIdx.x;
    if (tid >= n * C8) return;
    int node = tid / C8, q = tid % C8;
    int c = q * 8, hd = c / F;
    int a = offsets[node], b = offsets[node + 1];
    float edv = ed[node * HHEADS + hd];
    float m = -1e30f, l = 0.f;
    float acc[8] = {};
    for (int j = a; j < b; ++j) {
        int s = ssrc[j];
        float v = es[s * HHEADS + hd] + edv;
        v = v > 0.f ? v : 0.2f * v;  // leaky relu 0.2
        float mn = fmaxf(m, v);
        float r = __expf(m - mn);
        float wgt = __expf(v - mn);
        uint2 hv = *(const uint2*)&h8[(size_t)s * HF + c];
        f32x2 p0 = __builtin_amdgcn_cvt_pk_f32_fp8((int)hv.x, false);
        f32x2 p1 = __builtin_amdgcn_cvt_pk_f32_fp8((int)hv.x, true);
        f32x2 p2 = __builtin_amdgcn_cvt_pk_f32_fp8((int)hv.y, false);
        f32x2 p3 = __builtin_amdgcn_cvt_pk_f32_fp8((int)hv.y, true);
        l = l * r + wgt;
        acc[0] = acc[0] * r + wgt * p0[0];
        acc[1] = acc[1] * r + wgt * p0[1];
        acc[2] = acc[2] * r + wgt * p1[0];
        acc[3] = acc[3] * r + wgt * p1[1];
        acc[4] = acc[4] * r + wgt * p2[0];
        acc[5] = acc[5] * r + wgt * p2[1];
        acc[6] = acc[6] * r + wgt * p3[0];
        acc[7] = acc[7] * r + wgt * p3[1];
        m = mn;
    }
    float invd = 1.0f / (l + 1e-16f);
    unsigned short th[8];
#pragma unroll
    for (int k = 0; k < 8; ++k) {
        float v = acc[k] * invd;
        v = v > 0.f ? v : (__expf(v) - 1.0f);  // elu
        th[k] = f2bf(v);
    }
    constexpr int NKT = HF / 32;
    int lq = (node & 15) | (((c >> 3) & 3) << 4);
    size_t base = ((size_t)((node >> 4) * NKT + (c >> 5)) * 64 + lq) * 8;
    *(uint4*)&oh[base] = *(uint4*)th;
}

// ---------------- wave-per-node single-pass aggregate (layer 2, fp8 h) --------
// Lanes 0..47 own 4 channels (uint = 4 fp8); fully-coalesced 192B row.
__global__ __launch_bounds__(256) void aggregate_wpn2(
    const unsigned char* __restrict__ h8, const float* __restrict__ es,
    const float* __restrict__ ed, const unsigned* __restrict__ gmax,
    const int* __restrict__ offsets, const int* __restrict__ ssrc,
    unsigned short* __restrict__ oh, int n) {
    constexpr int HF = 192;
    int wid = (int)((blockIdx.x * (unsigned)blockDim.x + threadIdx.x) >> 6);
    int lane = threadIdx.x & 63;
    if (wid >= n || lane >= 48) return;
    int node = wid;
    int hd = lane >> 3;  // F=32: 8 lanes (32ch) per head
    int c = lane * 4;
    int a = offsets[node], b = offsets[node + 1];
    float edv = ed[node * HHEADS + hd];
    float mv = funkey(gmax[6 + hd]) + edv;
    float m = mv > 0.f ? mv : 0.2f * mv;
    float l = 0.f;
    float acc[4] = {};
    const unsigned char* hbase = h8 + c;
    int j = a;
    for (; j + 1 < b; j += 2) {
        int s0 = ssrc[j], s1 = ssrc[j + 1];
        float ev0 = es[(size_t)s0 * HHEADS + hd];
        float ev1 = es[(size_t)s1 * HHEADS + hd];
        unsigned h0 = *(const unsigned*)(hbase + (size_t)s0 * HF);
        unsigned h1 = *(const unsigned*)(hbase + (size_t)s1 * HF);
        float v0 = ev0 + edv;
        v0 = v0 > 0.f ? v0 : 0.2f * v0;
        float v1 = ev1 + edv;
        v1 = v1 > 0.f ? v1 : 0.2f * v1;
        float w0 = __expf(v0 - m);
        float w1 = __expf(v1 - m);
        {
            f32x2 p0 = __builtin_amdgcn_cvt_pk_f32_fp8((int)h0, false);
            f32x2 p1 = __builtin_amdgcn_cvt_pk_f32_fp8((int)h0, true);
            l += w0;
            acc[0] += w0 * p0[0];
            acc[1] += w0 * p0[1];
            acc[2] += w0 * p1[0];
            acc[3] += w0 * p1[1];
        }
        {
            f32x2 p0 = __builtin_amdgcn_cvt_pk_f32_fp8((int)h1, false);
            f32x2 p1 = __builtin_amdgcn_cvt_pk_f32_fp8((int)h1, true);
            l += w1;
            acc[0] += w1 * p0[0];
            acc[1] += w1 * p0[1];
            acc[2] += w1 * p1[0];
            acc[3] += w1 * p1[1];
        }
    }
    if (j < b) {
        int s0 = ssrc[j];
        float ev0 = es[(size_t)s0 * HHEADS + hd];
        unsigned h0 = *(const unsigned*)(hbase + (size_t)s0 * HF);
        float v0 = ev0 + edv;
        v0 = v0 > 0.f ? v0 : 0.2f * v0;
        float w0 = __expf(v0 - m);
        f32x2 p0 = __builtin_amdgcn_cvt_pk_f32_fp8((int)h0, false);
        f32x2 p1 = __builtin_amdgcn_cvt_pk_f32_fp8((int)h0, true);
        l += w0;
        acc[0] += w0 * p0[0];
        acc[1] += w0 * p0[1];
        acc[2] += w0 * p1[0];
        acc[3] += w0 * p1[1];
    }
    float invd = 1.0f / (l + 1e-16f);
    unsigned short th[4];
#pragma unroll
    for (int k = 0; k < 4; ++k) {
        float v = acc[k] * invd;
        v = v > 0.f ? v : (__expf(v) - 1.0f);  // elu
        th[k] = f2bf(v);
    }
    int lq = (node & 15) | (((c >> 3) & 3) << 4);
    size_t base = ((size_t)((node >> 4) * (HF / 32) + (c >> 5)) * 64 + lq) * 8 + (c & 7);
    *(uint2*)&oh[base] = *(uint2*)th;
}

// ---------------- wave-per-node single-pass aggregate (layer 3, fp8 h) --------
__global__ __launch_bounds__(256) void aggregate_wpn3(
    const unsigned char* __restrict__ h8, const float* __restrict__ es,
    const float* __restrict__ ed, const unsigned* __restrict__ gmax,
    const int* __restrict__ offsets, const int* __restrict__ ssrc,
    __hip_bfloat16* __restrict__ outb, int n) {
    constexpr int HF = 384;
    int wid = (int)((blockIdx.x * (unsigned)blockDim.x + threadIdx.x) >> 6);
    int lane = threadIdx.x & 63;
    if (wid >= n || lane >= 48) return;
    int node = wid;
    int hd = lane >> 3;  // 8 lanes (64ch) per head
    int c = lane * 8;
    int a = offsets[node], b = offsets[node + 1];
    float edv = ed[node * HHEADS + hd];
    float mv = funkey(gmax[hd]) + edv;
    float m = mv > 0.f ? mv : 0.2f * mv;
    float l = 0.f;
    float acc[8] = {};
    const unsigned char* hbase = h8 + c;
    int j = a;
    for (; j + 1 < b; j += 2) {
        int s0 = ssrc[j], s1 = ssrc[j + 1];
        float ev0 = es[(size_t)s0 * HHEADS + hd];
        float ev1 = es[(size_t)s1 * HHEADS + hd];
        uint2 h0 = *(const uint2*)(hbase + (size_t)s0 * HF);
        uint2 h1 = *(const uint2*)(hbase + (size_t)s1 * HF);
        float v0 = ev0 + edv;
        v0 = v0 > 0.f ? v0 : 0.2f * v0;
        float v1 = ev1 + edv;
        v1 = v1 > 0.f ? v1 : 0.2f * v1;
        float w0 = __expf(v0 - m);
        float w1 = __expf(v1 - m);
        {
            f32x2 p0 = __builtin_amdgcn_cvt_pk_f32_fp8((int)h0.x, false);
            f32x2 p1 = __builtin_amdgcn_cvt_pk_f32_fp8((int)h0.x, true);
            f32x2 p2 = __builtin_amdgcn_cvt_pk_f32_fp8((int)h0.y, false);
            f32x2 p3 = __builtin_amdgcn_cvt_pk_f32_fp8((int)h0.y, true);
            l += w0;
            acc[0] += w0 * p0[0];
            acc[1] += w0 * p0[1];
            acc[2] += w0 * p1[0];
            acc[3] += w0 * p1[1];
            acc[4] += w0 * p2[0];
            acc[5] += w0 * p2[1];
            acc[6] += w0 * p3[0];
            acc[7] += w0 * p3[1];
        }
        {
            f32x2 p0 = __builtin_amdgcn_cvt_pk_f32_fp8((int)h1.x, false);
            f32x2 p1 = __builtin_amdgcn_cvt_pk_f32_fp8((int)h1.x, true);
            f32x2 p2 = __builtin_amdgcn_cvt_pk_f32_fp8((int)h1.y, false);
            f32x2 p3 = __builtin_amdgcn_cvt_pk_f32_fp8((int)h1.y, true);
            l += w1;
            acc[0] += w1 * p0[0];
            acc[1] += w1 * p0[1];
            acc[2] += w1 * p1[0];
            acc[3] += w1 * p1[1];
            acc[4] += w1 * p2[0];
            acc[5] += w1 * p2[1];
            acc[6] += w1 * p3[0];
            acc[7] += w1 * p3[1];
        }
    }
    if (j < b) {
        int s0 = ssrc[j];
        float ev0 = es[(size_t)s0 * HHEADS + hd];
        uint2 h0 = *(const uint2*)(hbase + (size_t)s0 * HF);
        float v0 = ev0 + edv;
        v0 = v0 > 0.f ? v0 : 0.2f * v0;
        float w0 = __expf(v0 - m);
        f32x2 p0 = __builtin_amdgcn_cvt_pk_f32_fp8((int)h0.x, false);
        f32x2 p1 = __builtin_amdgcn_cvt_pk_f32_fp8((int)h0.x, true);
        f32x2 p2 = __builtin_amdgcn_cvt_pk_f32_fp8((int)h0.y, false);
        f32x2 p3 = __builtin_amdgcn_cvt_pk_f32_fp8((int)h0.y, true);
        l += w0;
        acc[0] += w0 * p0[0];
        acc[1] += w0 * p0[1];
        acc[2] += w0 * p1[0];
        acc[3] += w0 * p1[1];
        acc[4] += w0 * p2[0];
        acc[5] += w0 * p2[1];
        acc[6] += w0 * p3[0];
        acc[7] += w0 * p3[1];
    }
    float invd = 1.0f / (l + 1e-16f);
    __hip_bfloat16 tb[8];
#pragma unroll
    for (int k = 0; k < 8; ++k) {
        float v = acc[k] * invd;
        v = v > 0.f ? v : (__expf(v) - 1.0f);  // elu
        tb[k] = __float2bfloat16(v);
    }
    *(uint4*)&outb[(size_t)node * HF + c] = *(uint4*)tb;
}

// ---------------- pooling (bf16 input) + head ----------------
__global__ void pool_kernel(const __hip_bfloat16* __restrict__ out3, float* __restrict__ g,
                            int n) {
    int b = blockIdx.x, t = threadIdx.x;  // blockDim = 192
    int chunk = (n + gridDim.x - 1) / gridDim.x;
    int n0 = b * chunk, n1 = min(n, n0 + chunk);
    float a0 = 0.f, a1 = 0.f;
    const unsigned* p = (const unsigned*)out3;
    for (int node = n0; node < n1; ++node) {
        unsigned u = p[(size_t)node * 192 + t];
        a0 += bfl(u);
        a1 += bfh(u);
    }
    atomicAdd(&g[2 * t], a0);
    atomicAdd(&g[2 * t + 1], a1);
}

__global__ void final_kernel(const float* __restrict__ g, const float* __restrict__ Wd,
                             const float* __restrict__ bd, float* __restrict__ outp) {
    __shared__ float red[384];
    int t = threadIdx.x;  // blockDim = 384
    float v = g[t];
    red[t] = v * v;
    __syncthreads();
    for (int s = 192; s >= 3; s >>= 1) {
        if (t < s) red[t] += red[t + s];
        __syncthreads();
    }
    __shared__ float scale_s;
    if (t == 0) {
        float norm = sqrtf(red[0] + red[1] + red[2]);
        scale_s = 1.0f / fmaxf(norm, 1e-12f);
    }
    __syncthreads();
    float scale = scale_s;
    red[t] = v * scale * Wd[t];
    __syncthreads();
    for (int s = 192; s >= 3; s >>= 1) {
        if (t < s) red[t] += red[t + s];
        __syncthreads();
    }
    if (t == 0) outp[0] = red[0] + red[1] + red[2] + bd[0];
}

// ---------------- host side ----------------
extern "C" void kernel_launch(void* const* d_in, const int* in_sizes, int n_in, void* d_out,
                              int out_size, void* d_ws, size_t ws_size, hipStream_t stream) {
    const float* x = (const float*)d_in[0];
    const int* ei = (const int*)d_in[1];
    const float* W1 = (const float*)d_in[2];
    const float* a1s = (const float*)d_in[3];
    const float* a1d = (const float*)d_in[4];
    const float* W2 = (const float*)d_in[5];
    const float* a2s = (const float*)d_in[6];
    const float* a2d = (const float*)d_in[7];
    const float* W3 = (const float*)d_in[8];
    const float* a3s = (const float*)d_in[9];
    const float* a3d = (const float*)d_in[10];
    const float* Wd = (const float*)d_in[11];
    const float* bd = (const float*)d_in[12];
    float* outp = (float*)d_out;

    const int N = in_sizes[0] / 11;
    const int E = in_sizes[1] / 2;
    const int* src = ei;
    const int* dst = ei + E;

    const int NT16 = ((N + 127) / 128) * 8;  // padded 16-row tiles
    const int NMT = (N + 127) / 128;         // 128-row M-tiles

    char* w = (char*)d_ws;
    size_t off = 0;
    auto A = [&](size_t bytes) {
        size_t o = off;
        off += (bytes + 255) & ~(size_t)255;
        return o;
    };
    unsigned char* bufH = (unsigned char*)(w + A((size_t)N * 384 * 2));   // h (fp8 all layers)
    __hip_bfloat16* bufO = (__hip_bfloat16*)(w + A((size_t)N * 384 * 2));  // layer3 out (bf16)
    unsigned short* apH = (unsigned short*)(w + A((size_t)NT16 * 6 * 512 * 2));  // A-pack
    unsigned short* b2H = (unsigned short*)(w + A((size_t)16 * 3 * 512 * 2));    // W2 pack
    unsigned short* b3H = (unsigned short*)(w + A((size_t)24 * 6 * 512 * 2));    // W3 pack
    float* es = (float*)(w + A((size_t)N * HHEADS * 4));
    float* ed = (float*)(w + A((size_t)N * HHEADS * 4));
    unsigned* gmax = (unsigned*)(w + A(256));
    float* wp = (float*)(w + A((size_t)11 * 96 * 4));  // layer-1 f32 repack
    int* count = (int*)(w + A((size_t)(N + 1) * 4));
    int* cursor = (int*)(w + A((size_t)(N + 1) * 4));
    int* offsets = (int*)(w + A((size_t)(N + 1) * 4));
    int* bsum = (int*)(w + A(64 * 4));
    int* ssrc = (int*)(w + A((size_t)E * 4));
    float* g = (float*)(w + A(384 * 4));

    // one-shot zero of all small scratch (count, cursor, g, gmax, A-pack pads)
    const long t16v = N / 16;
    const long padT = NT16 - t16v;
    zero_misc<<<(N + 255) / 256, 256, 0, stream>>>(count, cursor, g, gmax, apH,
                                                   t16v * 3 * 512, padT * 3 * 512,
                                                   t16v * 6 * 512, padT * 6 * 512, N);

    // CSR build (by dst)
    hist_kernel<<<(E + 255) / 256, 256, 0, stream>>>(dst, count, E);
    int nb = (N + 1023) / 1024;
    scan_block<<<nb, 1024, 0, stream>>>(count, offsets, bsum, N);
    scan_tops<<<1, 64, 0, stream>>>(bsum, nb);
    scan_add<<<nb, 1024, 0, stream>>>(offsets, bsum, N, E);
    scatter_kernel<<<(E + 255) / 256, 256, 0, stream>>>(src, dst, offsets, cursor, ssrc, E);

    // weight packs
    repack_w<<<(11 * 96 + 255) / 256, 256, 0, stream>>>(W1, wp, 11, 16);
    repack_w_mfma<<<(96 * 256 + 255) / 256, 256, 0, stream>>>(W2, b2H, 96, 32, 256);
    repack_w_mfma<<<(192 * 384 + 255) / 256, 256, 0, stream>>>(W3, b3H, 192, 64, 384);

    // ---- layer 1 (FIN=11, F=16): gemm (fp8 C) + fused attn terms ----
    {
        dim3 grid((96 + 63) / 64, (N + 63) / 64);
        gemm_small_attn<64, 64, 32><<<grid, 256, 0, stream>>>(x, wp, bufH, a1s, a1d, es, ed, N,
                                                              11, 96);
    }
    {
        long total = (long)N * (96 / 8);
        aggregate_fused<16><<<(total + 255) / 256, 256, 0, stream>>>(bufH, es, ed, offsets,
                                                                     ssrc, apH, N);
    }

    // ---- layer 2 (K=96, N=192 pad 256, F=32): fp8 C + fused gmax(6-11) ----
    {
        dim3 grid(2, (NMT + 3) / 4);
        gemm_attn_mfma<96, 192, 256, 32, 4><<<grid, 256, 0, stream>>>(apH, b2H, bufH, a2s,
                                                                      a2d, es, ed, gmax, N);
    }
    {
        int grid = (N + 3) / 4;  // 4 waves/block, wave-per-node
        aggregate_wpn2<<<grid, 256, 0, stream>>>(bufH, es, ed, gmax, offsets, ssrc, apH, N);
    }

    // ---- layer 3 (K=192, N=384, F=64): fp8 C + fused gmax(0-5) ----
    {
        dim3 grid(3, (NMT + 3) / 4);
        gemm_attn_mfma<192, 384, 384, 64, 4><<<grid, 256, 0, stream>>>(apH, b3H, bufH, a3s,
                                                                       a3d, es, ed, gmax, N);
    }
    {
        int grid = (N + 3) / 4;
        aggregate_wpn3<<<grid, 256, 0, stream>>>(bufH, es, ed, gmax, offsets, ssrc, bufO, N);
    }

    // sum-pool (bf16 in) -> normalize -> dense
    pool_kernel<<<256, 192, 0, stream>>>(bufO, g, N);
    final_kernel<<<1, 384, 0, stream>>>(g, Wd, bd, outp);
}